// Round 1
// baseline (3919.102 us; speedup 1.0000x reference)
//
#include <hip/hip_runtime.h>
#include <math.h>

#define NN 50000
#define NH 50000
#define NI 800000
#define NL 20000

// ---------------- degree count: deg[0..NN) = deg over nsrc, deg[NN..NN+NH) over hdst
__global__ void k_count_deg(const int* __restrict__ ei, float* __restrict__ deg) {
    int t = blockIdx.x * blockDim.x + threadIdx.x;
    if (t < NI) {
        atomicAdd(&deg[ei[t]], 1.0f);            // row 0: nsrc
    } else if (t < 2 * NI) {
        atomicAdd(&deg[NN + ei[t]], 1.0f);       // row 1: hdst
    }
}

__global__ void k_invert(float* __restrict__ a, int n) {
    int i = blockIdx.x * blockDim.x + threadIdx.x;
    if (i < n) a[i] = a[i] > 0.0f ? 1.0f / a[i] : 0.0f;
}

// ---------------- Y[row][t] = sum_k X[row][k] * W[k][t]; block = m threads, one row per block
__global__ void k_gemm_row(const float* __restrict__ X, const float* __restrict__ W,
                           float* __restrict__ Y, int k, int m) {
    extern __shared__ float xrow[];
    int row = blockIdx.x;
    const float* xr = X + (size_t)row * k;
    for (int i = threadIdx.x; i < k; i += blockDim.x) xrow[i] = xr[i];
    __syncthreads();
    int t = threadIdx.x;
    float acc = 0.0f;
#pragma unroll 8
    for (int kk = 0; kk < k; kk++) acc = fmaf(xrow[kk], W[(size_t)kk * m + t], acc);
    Y[(size_t)row * m + t] = acc;
}

// ---------------- he[didx[e]][f] += xw[sidx[e]][f]
__global__ void k_scatterA(const float* __restrict__ xw, const int* __restrict__ sidx,
                           const int* __restrict__ didx, float* __restrict__ he, int shift) {
    unsigned t = blockIdx.x * blockDim.x + threadIdx.x;
    unsigned total = (unsigned)NI << shift;
    if (t >= total) return;
    unsigned e = t >> shift;
    unsigned f = t & ((1u << shift) - 1u);
    atomicAdd(&he[((size_t)didx[e] << shift) + f], xw[((size_t)sidx[e] << shift) + f]);
}

// ---------------- out[sidx[e]][f] += he[didx[e]][f] * binv[didx[e]]
__global__ void k_scatterB(const float* __restrict__ he, const float* __restrict__ binv,
                           const int* __restrict__ sidx, const int* __restrict__ didx,
                           float* __restrict__ out, int shift) {
    unsigned t = blockIdx.x * blockDim.x + threadIdx.x;
    unsigned total = (unsigned)NI << shift;
    if (t >= total) return;
    unsigned e = t >> shift;
    unsigned f = t & ((1u << shift) - 1u);
    int dd = didx[e];
    atomicAdd(&out[((size_t)sidx[e] << shift) + f],
              he[((size_t)dd << shift) + f] * binv[dd]);
}

// ---------------- y = relu(y * dinv[row] + b[f])
__global__ void k_finalize(float* __restrict__ y, const float* __restrict__ dinv,
                           const float* __restrict__ b, int n, int shift) {
    unsigned t = blockIdx.x * blockDim.x + threadIdx.x;
    if (t >= ((unsigned)n << shift)) return;
    unsigned i = t >> shift;
    unsigned f = t & ((1u << shift) - 1u);
    y[t] = fmaxf(fmaf(y[t], dinv[i], b[f]), 0.0f);
}

// ---------------- fused feature assembly + MLP + log_softmax; 8 links per block
#define LB 8
__global__ void k_final_mlp(const float* __restrict__ h1, const float* __restrict__ h2,
                            const float* __restrict__ h3, const float* __restrict__ g1,
                            const float* __restrict__ g2, const float* __restrict__ g3,
                            const int* __restrict__ marks, const int* __restrict__ emarks,
                            const float* __restrict__ W1, const float* __restrict__ b1,
                            const float* __restrict__ W2, const float* __restrict__ b2,
                            float* __restrict__ out) {
    __shared__ float feat[LB][768];
    __shared__ float hid[LB][256];
    __shared__ float lg[LB][2];
    int base = blockIdx.x * LB;
    int t = threadIdx.x;
    for (int i = 0; i < LB; i++) {
        int l = base + i;
        int m = marks[l];
        int ea = emarks[l];
        for (int f = t; f < 192; f += 256) {
            const float* g; int off;
            if (f < 64)       { g = g1; off = f; }
            else if (f < 128) { g = g2; off = f - 64; }
            else              { g = g3; off = f - 128; }
            float av = g[(size_t)ea * 64 + off];
            float bv = g[(size_t)(ea + 1) * 64 + off];
            feat[i][f]       = fminf(av, bv);
            feat[i][192 + f] = fmaxf(av, bv);
        }
        for (int f = t; f < 384; f += 256) {
            const float* h; int off;
            if (f < 128)      { h = h1; off = f; }
            else if (f < 256) { h = h2; off = f - 128; }
            else              { h = h3; off = f - 256; }
            feat[i][384 + f] = h[(size_t)m * 128 + off];
        }
    }
    __syncthreads();
    float acc[LB];
#pragma unroll
    for (int i = 0; i < LB; i++) acc[i] = b1[t];
    for (int k = 0; k < 768; k++) {
        float w = W1[(size_t)k * 256 + t];
#pragma unroll
        for (int i = 0; i < LB; i++) acc[i] = fmaf(feat[i][k], w, acc[i]);
    }
#pragma unroll
    for (int i = 0; i < LB; i++) hid[i][t] = fmaxf(acc[i], 0.0f);
    __syncthreads();
    if (t < LB * 2) {
        int i = t >> 1, c = t & 1;
        float s = b2[c];
        for (int k = 0; k < 256; k++) s = fmaf(hid[i][k], W2[(size_t)k * 2 + c], s);
        lg[i][c] = s;
    }
    __syncthreads();
    if (t < LB) {
        float l0 = lg[t][0], l1 = lg[t][1];
        float mx = fmaxf(l0, l1);
        float lse = mx + logf(expf(l0 - mx) + expf(l1 - mx));
        out[(size_t)(base + t) * 2 + 0] = l0 - lse;
        out[(size_t)(base + t) * 2 + 1] = l1 - lse;
    }
}

extern "C" void kernel_launch(void* const* d_in, const int* in_sizes, int n_in,
                              void* d_out, int out_size, void* d_ws, size_t ws_size,
                              hipStream_t stream) {
    const float* x      = (const float*)d_in[0];
    const float* ex     = (const float*)d_in[1];
    const int*   ei     = (const int*)d_in[2];
    const int*   nsrc   = ei;
    const int*   hdst   = ei + NI;
    const int*   marks  = (const int*)d_in[3];
    const int*   emarks = (const int*)d_in[4];
    // setup_inputs dict order: Wn0,bn0,We0,be0,Wn1,bn1,We1,be1,Wn2,bn2,We2,be2,W1,b1,W2,b2
    const float* Wn[3] = {(const float*)d_in[5],  (const float*)d_in[9],  (const float*)d_in[13]};
    const float* bn[3] = {(const float*)d_in[6],  (const float*)d_in[10], (const float*)d_in[14]};
    const float* We[3] = {(const float*)d_in[7],  (const float*)d_in[11], (const float*)d_in[15]};
    const float* be[3] = {(const float*)d_in[8],  (const float*)d_in[12], (const float*)d_in[16]};
    const float* W1 = (const float*)d_in[17];
    const float* b1 = (const float*)d_in[18];
    const float* W2 = (const float*)d_in[19];
    const float* b2 = (const float*)d_in[20];

    float* p    = (float*)d_ws;
    float* invn = p;                 // NN
    float* invh = p + NN;            // NH
    float* xw   = p + 100000;        // up to NN*128
    float* he   = xw + 6400000;      // up to NN*128
    float* h[3] = {he + 6400000, he + 12800000, he + 19200000};      // NN*128 each
    float* g[3] = {he + 25600000, he + 28800000, he + 32000000};     // NH*64 each

    // degrees (shared by all layers)
    hipMemsetAsync(p, 0, (size_t)100000 * 4, stream);
    k_count_deg<<<(2 * NI + 255) / 256, 256, 0, stream>>>(ei, p);
    k_invert<<<(100000 + 255) / 256, 256, 0, stream>>>(p, 100000);

    // ---- node convs: src=nsrc, dst=hdst, d_out=128
    const float* cur = x;
    int k = 256;
    for (int i = 0; i < 3; i++) {
        k_gemm_row<<<NN, 128, k * 4, stream>>>(cur, Wn[i], xw, k, 128);
        hipMemsetAsync(he, 0, (size_t)NH * 128 * 4, stream);
        k_scatterA<<<((unsigned)NI * 128 + 255) / 256, 256, 0, stream>>>(xw, nsrc, hdst, he, 7);
        hipMemsetAsync(h[i], 0, (size_t)NN * 128 * 4, stream);
        k_scatterB<<<((unsigned)NI * 128 + 255) / 256, 256, 0, stream>>>(he, invh, nsrc, hdst, h[i], 7);
        k_finalize<<<((unsigned)NN * 128 + 255) / 256, 256, 0, stream>>>(h[i], invn, bn[i], NN, 7);
        cur = h[i];
        k = 128;
    }

    // ---- edge convs: src=hdst, dst=nsrc, d_out=64
    cur = ex;
    k = 128;
    for (int i = 0; i < 3; i++) {
        k_gemm_row<<<NH, 64, k * 4, stream>>>(cur, We[i], xw, k, 64);
        hipMemsetAsync(he, 0, (size_t)NN * 64 * 4, stream);
        k_scatterA<<<((unsigned)NI * 64 + 255) / 256, 256, 0, stream>>>(xw, hdst, nsrc, he, 6);
        hipMemsetAsync(g[i], 0, (size_t)NH * 64 * 4, stream);
        k_scatterB<<<((unsigned)NI * 64 + 255) / 256, 256, 0, stream>>>(he, invn, hdst, nsrc, g[i], 6);
        k_finalize<<<((unsigned)NH * 64 + 255) / 256, 256, 0, stream>>>(g[i], invh, be[i], NH, 6);
        cur = g[i];
        k = 64;
    }

    // ---- final fused MLP + log_softmax
    k_final_mlp<<<NL / LB, 256, 0, stream>>>(h[0], h[1], h[2], g[0], g[1], g[2],
                                             marks, emarks, W1, b1, W2, b2, (float*)d_out);
}

// Round 2
// 1591.398 us; speedup vs baseline: 2.4627x; 2.4627x over previous
//
#include <hip/hip_runtime.h>
#include <math.h>

#define NN 50000
#define NH 50000
#define NI 800000
#define NL 20000

// ================= CSR build =================
__global__ void k_hist(const int* __restrict__ ei, int* __restrict__ cnt_n,
                       int* __restrict__ cnt_h) {
    int t = blockIdx.x * blockDim.x + threadIdx.x;
    if (t < NI) atomicAdd(&cnt_n[ei[t]], 1);            // nsrc
    else if (t < 2 * NI) atomicAdd(&cnt_h[ei[t]], 1);   // hdst
}

// one-block exclusive scan of n (~50k) counts -> off[0..n], off[n]=total
__global__ void k_scan(const int* __restrict__ cnt, int* __restrict__ off, int n) {
    __shared__ int part[1024];
    int t = threadIdx.x;
    int chunk = (n + 1023) >> 10;
    int lo = t * chunk, hi = min(lo + chunk, n);
    int s = 0;
    for (int i = lo; i < hi; i++) s += cnt[i];
    part[t] = s;
    __syncthreads();
    for (int d = 1; d < 1024; d <<= 1) {
        int v = (t >= d) ? part[t - d] : 0;
        __syncthreads();
        part[t] += v;
        __syncthreads();
    }
    int run = (t == 0) ? 0 : part[t - 1];
    for (int i = lo; i < hi; i++) { off[i] = run; run += cnt[i]; }
    if (hi == n) off[n] = run;
}

__global__ void k_fill(const int* __restrict__ ei, const int* __restrict__ off_n,
                       const int* __restrict__ off_h, int* __restrict__ cur_n,
                       int* __restrict__ cur_h, int* __restrict__ adj_n,
                       int* __restrict__ adj_h) {
    int t = blockIdx.x * blockDim.x + threadIdx.x;
    if (t < NI) {
        int s = ei[t], d = ei[t + NI];
        int p = atomicAdd(&cur_h[d], 1);
        adj_h[off_h[d] + p] = s;                 // CSR by hyperedge -> node ids
    } else if (t < 2 * NI) {
        int e = t - NI;
        int s = ei[e], d = ei[e + NI];
        int p = atomicAdd(&cur_n[s], 1);
        adj_n[off_n[s] + p] = d;                 // CSR by node -> hyperedge ids
    }
}

__global__ void k_invdeg(const int* __restrict__ off, float* __restrict__ inv, int n) {
    int i = blockIdx.x * blockDim.x + threadIdx.x;
    if (i < n) {
        int d = off[i + 1] - off[i];
        inv[i] = d > 0 ? 1.0f / (float)d : 0.0f;
    }
}

// ================= dense row GEMM (unchanged) =================
__global__ void k_gemm_row(const float* __restrict__ X, const float* __restrict__ W,
                           float* __restrict__ Y, int k, int m) {
    extern __shared__ float xrow[];
    int row = blockIdx.x;
    const float* xr = X + (size_t)row * k;
    for (int i = threadIdx.x; i < k; i += blockDim.x) xrow[i] = xr[i];
    __syncthreads();
    int t = threadIdx.x;
    float acc = 0.0f;
#pragma unroll 8
    for (int kk = 0; kk < k; kk++) acc = fmaf(xrow[kk], W[(size_t)kk * m + t], acc);
    Y[(size_t)row * m + t] = acc;
}

// ================= pull aggregation =================
// out[r][:] = scale[r] * sum_{j in off[r]..off[r+1]} in[adj[j]][:]   (+bias, relu)
template <int F, bool RELU>
__global__ void k_pull(const float* __restrict__ in, const int* __restrict__ off,
                       const int* __restrict__ adj, const float* __restrict__ scale,
                       const float* __restrict__ bias, float* __restrict__ out,
                       int nrows) {
    constexpr int TPR = F / 4;            // threads per row (float4 lanes)
    constexpr int RPB = 256 / TPR;        // rows per block
    int r = blockIdx.x * RPB + threadIdx.x / TPR;
    int lane = threadIdx.x % TPR;
    if (r >= nrows) return;
    int lo = off[r], hi = off[r + 1];
    const float4* in4 = (const float4*)in;
    float4 a0 = {0.f, 0.f, 0.f, 0.f}, a1 = {0.f, 0.f, 0.f, 0.f};
    int j = lo;
    for (; j + 1 < hi; j += 2) {
        int c0 = adj[j], c1 = adj[j + 1];
        float4 v0 = in4[(size_t)c0 * TPR + lane];
        float4 v1 = in4[(size_t)c1 * TPR + lane];
        a0.x += v0.x; a0.y += v0.y; a0.z += v0.z; a0.w += v0.w;
        a1.x += v1.x; a1.y += v1.y; a1.z += v1.z; a1.w += v1.w;
    }
    if (j < hi) {
        int c0 = adj[j];
        float4 v0 = in4[(size_t)c0 * TPR + lane];
        a0.x += v0.x; a0.y += v0.y; a0.z += v0.z; a0.w += v0.w;
    }
    a0.x += a1.x; a0.y += a1.y; a0.z += a1.z; a0.w += a1.w;
    float sc = scale[r];
    if (RELU) {
        float4 b = ((const float4*)bias)[lane];
        a0.x = fmaxf(fmaf(a0.x, sc, b.x), 0.f);
        a0.y = fmaxf(fmaf(a0.y, sc, b.y), 0.f);
        a0.z = fmaxf(fmaf(a0.z, sc, b.z), 0.f);
        a0.w = fmaxf(fmaf(a0.w, sc, b.w), 0.f);
    } else {
        a0.x *= sc; a0.y *= sc; a0.z *= sc; a0.w *= sc;
    }
    ((float4*)out)[(size_t)r * TPR + lane] = a0;
}

// ================= fused feature assembly + MLP + log_softmax =================
#define LB 8
__global__ void k_final_mlp(const float* __restrict__ h1, const float* __restrict__ h2,
                            const float* __restrict__ h3, const float* __restrict__ g1,
                            const float* __restrict__ g2, const float* __restrict__ g3,
                            const int* __restrict__ marks, const int* __restrict__ emarks,
                            const float* __restrict__ W1, const float* __restrict__ b1,
                            const float* __restrict__ W2, const float* __restrict__ b2,
                            float* __restrict__ out) {
    __shared__ float feat[LB][768];
    __shared__ float hid[LB][256];
    __shared__ float lg[LB][2];
    int base = blockIdx.x * LB;
    int t = threadIdx.x;
    for (int i = 0; i < LB; i++) {
        int l = base + i;
        int m = marks[l];
        int ea = emarks[l];
        for (int f = t; f < 192; f += 256) {
            const float* g; int off;
            if (f < 64)       { g = g1; off = f; }
            else if (f < 128) { g = g2; off = f - 64; }
            else              { g = g3; off = f - 128; }
            float av = g[(size_t)ea * 64 + off];
            float bv = g[(size_t)(ea + 1) * 64 + off];
            feat[i][f]       = fminf(av, bv);
            feat[i][192 + f] = fmaxf(av, bv);
        }
        for (int f = t; f < 384; f += 256) {
            const float* h; int off;
            if (f < 128)      { h = h1; off = f; }
            else if (f < 256) { h = h2; off = f - 128; }
            else              { h = h3; off = f - 256; }
            feat[i][384 + f] = h[(size_t)m * 128 + off];
        }
    }
    __syncthreads();
    float acc[LB];
#pragma unroll
    for (int i = 0; i < LB; i++) acc[i] = b1[t];
    for (int k = 0; k < 768; k++) {
        float w = W1[(size_t)k * 256 + t];
#pragma unroll
        for (int i = 0; i < LB; i++) acc[i] = fmaf(feat[i][k], w, acc[i]);
    }
#pragma unroll
    for (int i = 0; i < LB; i++) hid[i][t] = fmaxf(acc[i], 0.0f);
    __syncthreads();
    if (t < LB * 2) {
        int i = t >> 1, c = t & 1;
        float s = b2[c];
        for (int k = 0; k < 256; k++) s = fmaf(hid[i][k], W2[(size_t)k * 2 + c], s);
        lg[i][c] = s;
    }
    __syncthreads();
    if (t < LB) {
        float l0 = lg[t][0], l1 = lg[t][1];
        float mx = fmaxf(l0, l1);
        float lse = mx + logf(expf(l0 - mx) + expf(l1 - mx));
        out[(size_t)(base + t) * 2 + 0] = l0 - lse;
        out[(size_t)(base + t) * 2 + 1] = l1 - lse;
    }
}

extern "C" void kernel_launch(void* const* d_in, const int* in_sizes, int n_in,
                              void* d_out, int out_size, void* d_ws, size_t ws_size,
                              hipStream_t stream) {
    const float* x      = (const float*)d_in[0];
    const float* ex     = (const float*)d_in[1];
    const int*   ei     = (const int*)d_in[2];
    const int*   marks  = (const int*)d_in[3];
    const int*   emarks = (const int*)d_in[4];
    const float* Wn[3] = {(const float*)d_in[5],  (const float*)d_in[9],  (const float*)d_in[13]};
    const float* bn[3] = {(const float*)d_in[6],  (const float*)d_in[10], (const float*)d_in[14]};
    const float* We[3] = {(const float*)d_in[7],  (const float*)d_in[11], (const float*)d_in[15]};
    const float* be[3] = {(const float*)d_in[8],  (const float*)d_in[12], (const float*)d_in[16]};
    const float* W1 = (const float*)d_in[17];
    const float* b1 = (const float*)d_in[18];
    const float* W2 = (const float*)d_in[19];
    const float* b2 = (const float*)d_in[20];

    // ---- workspace layout ----
    int*   off_n = (int*)d_ws;                 // 50004
    int*   off_h = off_n + 50004;              // 50004
    int*   adj_n = off_h + 50004;              // 800000
    int*   adj_h = adj_n + 800000;             // 800000
    int*   cnt   = adj_h + 800000;             // 100000 (counts, then cursors)
    float* invn  = (float*)(cnt + 100000);     // 50000
    float* invh  = invn + 50000;               // 50000
    float* xw    = invh + 50000;               // 6.4M
    float* heb   = xw + 6400000;               // 6.4M
    float* h[3]  = {heb + 6400000, heb + 12800000, heb + 19200000};   // NN*128 each
    float* g[3]  = {heb + 25600000, heb + 28800000, heb + 32000000};  // NH*64 each

    int* cnt_n = cnt;
    int* cnt_h = cnt + 50000;

    // ---- CSR build ----
    hipMemsetAsync(cnt, 0, 100000 * sizeof(int), stream);
    k_hist<<<(2 * NI + 255) / 256, 256, 0, stream>>>(ei, cnt_n, cnt_h);
    k_scan<<<1, 1024, 0, stream>>>(cnt_n, off_n, NN);
    k_scan<<<1, 1024, 0, stream>>>(cnt_h, off_h, NH);
    hipMemsetAsync(cnt, 0, 100000 * sizeof(int), stream);
    k_fill<<<(2 * NI + 255) / 256, 256, 0, stream>>>(ei, off_n, off_h, cnt_n, cnt_h, adj_n, adj_h);
    k_invdeg<<<(NN + 255) / 256, 256, 0, stream>>>(off_n, invn, NN);
    k_invdeg<<<(NH + 255) / 256, 256, 0, stream>>>(off_h, invh, NH);

    // ---- node convs: pass A groups by hdst (CSR_h), pass B groups by nsrc (CSR_n)
    const float* cur = x;
    int k = 256;
    for (int i = 0; i < 3; i++) {
        k_gemm_row<<<NN, 128, k * 4, stream>>>(cur, Wn[i], xw, k, 128);
        k_pull<128, false><<<(NH + 7) / 8, 256, 0, stream>>>(xw, off_h, adj_h, invh, nullptr, heb, NH);
        k_pull<128, true><<<(NN + 7) / 8, 256, 0, stream>>>(heb, off_n, adj_n, invn, bn[i], h[i], NN);
        cur = h[i];
        k = 128;
    }

    // ---- edge convs (flipped): pass A groups by nsrc (CSR_n), pass B groups by hdst (CSR_h)
    cur = ex;
    k = 128;
    for (int i = 0; i < 3; i++) {
        k_gemm_row<<<NH, 64, k * 4, stream>>>(cur, We[i], xw, k, 64);
        k_pull<64, false><<<(NN + 15) / 16, 256, 0, stream>>>(xw, off_n, adj_n, invn, nullptr, heb, NN);
        k_pull<64, true><<<(NH + 15) / 16, 256, 0, stream>>>(heb, off_h, adj_h, invh, be[i], g[i], NH);
        cur = g[i];
        k = 64;
    }

    // ---- final fused MLP + log_softmax
    k_final_mlp<<<NL / LB, 256, 0, stream>>>(h[0], h[1], h[2], g[0], g[1], g[2],
                                             marks, emarks, W1, b1, W2, b2, (float*)d_out);
}

// Round 3
// 1296.420 us; speedup vs baseline: 3.0230x; 1.2275x over previous
//
#include <hip/hip_runtime.h>
#include <math.h>

#define NN 50000
#define NH 50000
#define NI 800000
#define NL 20000

// ================= CSR build =================
__global__ void k_hist(const int* __restrict__ ei, int* __restrict__ cnt_n,
                       int* __restrict__ cnt_h) {
    int t = blockIdx.x * blockDim.x + threadIdx.x;
    if (t < NI) atomicAdd(&cnt_n[ei[t]], 1);            // nsrc
    else if (t < 2 * NI) atomicAdd(&cnt_h[ei[t]], 1);   // hdst
}

// one-block exclusive scan of n (~50k) counts -> off[0..n], off[n]=total
__global__ void k_scan(const int* __restrict__ cnt, int* __restrict__ off, int n) {
    __shared__ int part[1024];
    int t = threadIdx.x;
    int chunk = (n + 1023) >> 10;
    int lo = t * chunk, hi = min(lo + chunk, n);
    int s = 0;
    for (int i = lo; i < hi; i++) s += cnt[i];
    part[t] = s;
    __syncthreads();
    for (int d = 1; d < 1024; d <<= 1) {
        int v = (t >= d) ? part[t - d] : 0;
        __syncthreads();
        part[t] += v;
        __syncthreads();
    }
    int run = (t == 0) ? 0 : part[t - 1];
    for (int i = lo; i < hi; i++) { off[i] = run; run += cnt[i]; }
    if (hi == n) off[n] = run;
}

__global__ void k_fill(const int* __restrict__ ei, const int* __restrict__ off_n,
                       const int* __restrict__ off_h, int* __restrict__ cur_n,
                       int* __restrict__ cur_h, int* __restrict__ adj_n,
                       int* __restrict__ adj_h) {
    int t = blockIdx.x * blockDim.x + threadIdx.x;
    if (t < NI) {
        int s = ei[t], d = ei[t + NI];
        int p = atomicAdd(&cur_h[d], 1);
        adj_h[off_h[d] + p] = s;                 // CSR by hyperedge -> node ids
    } else if (t < 2 * NI) {
        int e = t - NI;
        int s = ei[e], d = ei[e + NI];
        int p = atomicAdd(&cur_n[s], 1);
        adj_n[off_n[s] + p] = d;                 // CSR by node -> hyperedge ids
    }
}

__global__ void k_invdeg(const int* __restrict__ off, float* __restrict__ inv, int n) {
    int i = blockIdx.x * blockDim.x + threadIdx.x;
    if (i < n) {
        int d = off[i + 1] - off[i];
        inv[i] = d > 0 ? 1.0f / (float)d : 0.0f;
    }
}

// ================= register-tiled GEMM: Y[M][BN] = X[M][K] @ W[K][BN] =================
// block = 256 threads; per-thread TM x TN register tile; K staged in BK slices.
template <int BM, int BN, int BK, int TM, int TN>
__global__ void k_gemm_t(const float* __restrict__ X, const float* __restrict__ W,
                         float* __restrict__ Y, int M, int K) {
    constexpr int TX = BN / TN;        // threads across columns
    __shared__ float Xs[BM][BK + 4];   // +4: keeps float4 staging aligned, spreads banks
    __shared__ float Ws[BK][BN];
    int t = threadIdx.x;
    int tx = t % TX, ty = t / TX;
    int bm0 = blockIdx.x * BM;
    float acc[TM][TN] = {};
    for (int k0 = 0; k0 < K; k0 += BK) {
        constexpr int XF4 = BM * BK / 4;
        for (int q = t; q < XF4; q += 256) {
            int r = q / (BK / 4), c = q % (BK / 4);
            int rg = bm0 + r; if (rg >= M) rg = M - 1;
            *(float4*)&Xs[r][c * 4] = *(const float4*)&X[(size_t)rg * K + k0 + c * 4];
        }
        constexpr int WF4 = BK * BN / 4;
        for (int q = t; q < WF4; q += 256) {
            int r = q / (BN / 4), c = q % (BN / 4);
            *(float4*)&Ws[r][c * 4] = *(const float4*)&W[(size_t)(k0 + r) * BN + c * 4];
        }
        __syncthreads();
#pragma unroll 8
        for (int kk = 0; kk < BK; kk++) {
            float a[TM];
#pragma unroll
            for (int i = 0; i < TM; i++) a[i] = Xs[ty * TM + i][kk];
            float4 wv = *(float4*)&Ws[kk][tx * TN];
#pragma unroll
            for (int i = 0; i < TM; i++) {
                acc[i][0] = fmaf(a[i], wv.x, acc[i][0]);
                acc[i][1] = fmaf(a[i], wv.y, acc[i][1]);
                acc[i][2] = fmaf(a[i], wv.z, acc[i][2]);
                acc[i][3] = fmaf(a[i], wv.w, acc[i][3]);
            }
        }
        __syncthreads();
    }
#pragma unroll
    for (int i = 0; i < TM; i++) {
        int rg = bm0 + ty * TM + i;
        if (rg < M)
            *(float4*)&Y[(size_t)rg * BN + tx * TN] =
                make_float4(acc[i][0], acc[i][1], acc[i][2], acc[i][3]);
    }
}

// ================= pull aggregation =================
// out[r][:] = scale[r] * sum_{j in off[r]..off[r+1]} in[adj[j]][:]   (+bias, relu)
template <int F, bool RELU>
__global__ void k_pull(const float* __restrict__ in, const int* __restrict__ off,
                       const int* __restrict__ adj, const float* __restrict__ scale,
                       const float* __restrict__ bias, float* __restrict__ out,
                       int nrows) {
    constexpr int TPR = F / 4;            // threads per row (float4 lanes)
    constexpr int RPB = 256 / TPR;        // rows per block
    int r = blockIdx.x * RPB + threadIdx.x / TPR;
    int lane = threadIdx.x % TPR;
    if (r >= nrows) return;
    int lo = off[r], hi = off[r + 1];
    const float4* in4 = (const float4*)in;
    float4 a0 = {0.f, 0.f, 0.f, 0.f}, a1 = {0.f, 0.f, 0.f, 0.f};
    int j = lo;
    for (; j + 1 < hi; j += 2) {
        int c0 = adj[j], c1 = adj[j + 1];
        float4 v0 = in4[(size_t)c0 * TPR + lane];
        float4 v1 = in4[(size_t)c1 * TPR + lane];
        a0.x += v0.x; a0.y += v0.y; a0.z += v0.z; a0.w += v0.w;
        a1.x += v1.x; a1.y += v1.y; a1.z += v1.z; a1.w += v1.w;
    }
    if (j < hi) {
        int c0 = adj[j];
        float4 v0 = in4[(size_t)c0 * TPR + lane];
        a0.x += v0.x; a0.y += v0.y; a0.z += v0.z; a0.w += v0.w;
    }
    a0.x += a1.x; a0.y += a1.y; a0.z += a1.z; a0.w += a1.w;
    float sc = scale[r];
    if (RELU) {
        float4 b = ((const float4*)bias)[lane];
        a0.x = fmaxf(fmaf(a0.x, sc, b.x), 0.f);
        a0.y = fmaxf(fmaf(a0.y, sc, b.y), 0.f);
        a0.z = fmaxf(fmaf(a0.z, sc, b.z), 0.f);
        a0.w = fmaxf(fmaf(a0.w, sc, b.w), 0.f);
    } else {
        a0.x *= sc; a0.y *= sc; a0.z *= sc; a0.w *= sc;
    }
    ((float4*)out)[(size_t)r * TPR + lane] = a0;
}

// ================= fused feature assembly + MLP + log_softmax =================
#define LB 8
__global__ void k_final_mlp(const float* __restrict__ h1, const float* __restrict__ h2,
                            const float* __restrict__ h3, const float* __restrict__ g1,
                            const float* __restrict__ g2, const float* __restrict__ g3,
                            const int* __restrict__ marks, const int* __restrict__ emarks,
                            const float* __restrict__ W1, const float* __restrict__ b1,
                            const float* __restrict__ W2, const float* __restrict__ b2,
                            float* __restrict__ out) {
    __shared__ float feat[LB][768];
    __shared__ float hid[LB][256];
    __shared__ float lg[LB][2];
    int base = blockIdx.x * LB;
    int t = threadIdx.x;
    for (int i = 0; i < LB; i++) {
        int l = base + i;
        int m = marks[l];
        int ea = emarks[l];
        for (int f = t; f < 192; f += 256) {
            const float* g; int off;
            if (f < 64)       { g = g1; off = f; }
            else if (f < 128) { g = g2; off = f - 64; }
            else              { g = g3; off = f - 128; }
            float av = g[(size_t)ea * 64 + off];
            float bv = g[(size_t)(ea + 1) * 64 + off];
            feat[i][f]       = fminf(av, bv);
            feat[i][192 + f] = fmaxf(av, bv);
        }
        for (int f = t; f < 384; f += 256) {
            const float* h; int off;
            if (f < 128)      { h = h1; off = f; }
            else if (f < 256) { h = h2; off = f - 128; }
            else              { h = h3; off = f - 256; }
            feat[i][384 + f] = h[(size_t)m * 128 + off];
        }
    }
    __syncthreads();
    float acc[LB];
#pragma unroll
    for (int i = 0; i < LB; i++) acc[i] = b1[t];
    for (int k = 0; k < 768; k++) {
        float w = W1[(size_t)k * 256 + t];
#pragma unroll
        for (int i = 0; i < LB; i++) acc[i] = fmaf(feat[i][k], w, acc[i]);
    }
#pragma unroll
    for (int i = 0; i < LB; i++) hid[i][t] = fmaxf(acc[i], 0.0f);
    __syncthreads();
    if (t < LB * 2) {
        int i = t >> 1, c = t & 1;
        float s = b2[c];
        for (int k = 0; k < 256; k++) s = fmaf(hid[i][k], W2[(size_t)k * 2 + c], s);
        lg[i][c] = s;
    }
    __syncthreads();
    if (t < LB) {
        float l0 = lg[t][0], l1 = lg[t][1];
        float mx = fmaxf(l0, l1);
        float lse = mx + logf(expf(l0 - mx) + expf(l1 - mx));
        out[(size_t)(base + t) * 2 + 0] = l0 - lse;
        out[(size_t)(base + t) * 2 + 1] = l1 - lse;
    }
}

extern "C" void kernel_launch(void* const* d_in, const int* in_sizes, int n_in,
                              void* d_out, int out_size, void* d_ws, size_t ws_size,
                              hipStream_t stream) {
    const float* x      = (const float*)d_in[0];
    const float* ex     = (const float*)d_in[1];
    const int*   ei     = (const int*)d_in[2];
    const int*   marks  = (const int*)d_in[3];
    const int*   emarks = (const int*)d_in[4];
    const float* Wn[3] = {(const float*)d_in[5],  (const float*)d_in[9],  (const float*)d_in[13]};
    const float* bn[3] = {(const float*)d_in[6],  (const float*)d_in[10], (const float*)d_in[14]};
    const float* We[3] = {(const float*)d_in[7],  (const float*)d_in[11], (const float*)d_in[15]};
    const float* be[3] = {(const float*)d_in[8],  (const float*)d_in[12], (const float*)d_in[16]};
    const float* W1 = (const float*)d_in[17];
    const float* b1 = (const float*)d_in[18];
    const float* W2 = (const float*)d_in[19];
    const float* b2 = (const float*)d_in[20];

    // ---- workspace layout ----
    int*   off_n = (int*)d_ws;                 // 50004
    int*   off_h = off_n + 50004;              // 50004
    int*   adj_n = off_h + 50004;              // 800000
    int*   adj_h = adj_n + 800000;             // 800000
    int*   cnt   = adj_h + 800000;             // 100000 (counts, then cursors)
    float* invn  = (float*)(cnt + 100000);     // 50000
    float* invh  = invn + 50000;               // 50000
    float* xw    = invh + 50000;               // 6.4M
    float* heb   = xw + 6400000;               // 6.4M
    float* h[3]  = {heb + 6400000, heb + 12800000, heb + 19200000};   // NN*128 each
    float* g[3]  = {heb + 25600000, heb + 28800000, heb + 32000000};  // NH*64 each

    int* cnt_n = cnt;
    int* cnt_h = cnt + 50000;

    // ---- CSR build ----
    hipMemsetAsync(cnt, 0, 100000 * sizeof(int), stream);
    k_hist<<<(2 * NI + 255) / 256, 256, 0, stream>>>(ei, cnt_n, cnt_h);
    k_scan<<<1, 1024, 0, stream>>>(cnt_n, off_n, NN);
    k_scan<<<1, 1024, 0, stream>>>(cnt_h, off_h, NH);
    hipMemsetAsync(cnt, 0, 100000 * sizeof(int), stream);
    k_fill<<<(2 * NI + 255) / 256, 256, 0, stream>>>(ei, off_n, off_h, cnt_n, cnt_h, adj_n, adj_h);
    k_invdeg<<<(NN + 255) / 256, 256, 0, stream>>>(off_n, invn, NN);
    k_invdeg<<<(NH + 255) / 256, 256, 0, stream>>>(off_h, invh, NH);

    // ---- node convs: pass A groups by hdst (CSR_h), pass B groups by nsrc (CSR_n)
    const float* cur = x;
    int k = 256;
    for (int i = 0; i < 3; i++) {
        k_gemm_t<64, 128, 64, 8, 4><<<(NN + 63) / 64, 256, 0, stream>>>(cur, Wn[i], xw, NN, k);
        k_pull<128, false><<<(NH + 7) / 8, 256, 0, stream>>>(xw, off_h, adj_h, invh, nullptr, heb, NH);
        k_pull<128, true><<<(NN + 7) / 8, 256, 0, stream>>>(heb, off_n, adj_n, invn, bn[i], h[i], NN);
        cur = h[i];
        k = 128;
    }

    // ---- edge convs (flipped): pass A groups by nsrc (CSR_n), pass B groups by hdst (CSR_h)
    cur = ex;
    k = 128;
    for (int i = 0; i < 3; i++) {
        k_gemm_t<64, 64, 64, 4, 4><<<(NH + 63) / 64, 256, 0, stream>>>(cur, We[i], xw, NH, k);
        k_pull<64, false><<<(NN + 15) / 16, 256, 0, stream>>>(xw, off_n, adj_n, invn, nullptr, heb, NN);
        k_pull<64, true><<<(NH + 15) / 16, 256, 0, stream>>>(heb, off_h, adj_h, invh, be[i], g[i], NH);
        cur = g[i];
        k = 64;
    }

    // ---- final fused MLP + log_softmax
    k_final_mlp<<<NL / LB, 256, 0, stream>>>(h[0], h[1], h[2], g[0], g[1], g[2],
                                             marks, emarks, W1, b1, W2, b2, (float*)d_out);
}

// Round 4
// 1271.950 us; speedup vs baseline: 3.0812x; 1.0192x over previous
//
#include <hip/hip_runtime.h>
#include <math.h>

#define NN 50000
#define NH 50000
#define NI 800000
#define NL 20000

// ================= CSR build =================
__global__ void k_hist(const int* __restrict__ ei, int* __restrict__ cnt_n,
                       int* __restrict__ cnt_h) {
    int t = blockIdx.x * blockDim.x + threadIdx.x;
    if (t < NI) atomicAdd(&cnt_n[ei[t]], 1);            // nsrc
    else if (t < 2 * NI) atomicAdd(&cnt_h[ei[t]], 1);   // hdst
}

// one-block exclusive scan of n (~50k) counts -> off[0..n], off[n]=total
__global__ void k_scan(const int* __restrict__ cnt, int* __restrict__ off, int n) {
    __shared__ int part[1024];
    int t = threadIdx.x;
    int chunk = (n + 1023) >> 10;
    int lo = t * chunk, hi = min(lo + chunk, n);
    int s = 0;
    for (int i = lo; i < hi; i++) s += cnt[i];
    part[t] = s;
    __syncthreads();
    for (int d = 1; d < 1024; d <<= 1) {
        int v = (t >= d) ? part[t - d] : 0;
        __syncthreads();
        part[t] += v;
        __syncthreads();
    }
    int run = (t == 0) ? 0 : part[t - 1];
    for (int i = lo; i < hi; i++) { off[i] = run; run += cnt[i]; }
    if (hi == n) off[n] = run;
}

__global__ void k_fill(const int* __restrict__ ei, const int* __restrict__ off_n,
                       const int* __restrict__ off_h, int* __restrict__ cur_n,
                       int* __restrict__ cur_h, int* __restrict__ adj_n,
                       int* __restrict__ adj_h) {
    int t = blockIdx.x * blockDim.x + threadIdx.x;
    if (t < NI) {
        int s = ei[t], d = ei[t + NI];
        int p = atomicAdd(&cur_h[d], 1);
        adj_h[off_h[d] + p] = s;                 // CSR by hyperedge -> node ids
    } else if (t < 2 * NI) {
        int e = t - NI;
        int s = ei[e], d = ei[e + NI];
        int p = atomicAdd(&cur_n[s], 1);
        adj_n[off_n[s] + p] = d;                 // CSR by node -> hyperedge ids
    }
}

__global__ void k_invdeg(const int* __restrict__ off, float* __restrict__ inv, int n) {
    int i = blockIdx.x * blockDim.x + threadIdx.x;
    if (i < n) {
        int d = off[i + 1] - off[i];
        inv[i] = d > 0 ? 1.0f / (float)d : 0.0f;
    }
}

// ================= register-tiled GEMM: Y[M][BN] = X[M][K] @ W[K][BN] =================
template <int BM, int BN, int BK, int TM, int TN>
__global__ void k_gemm_t(const float* __restrict__ X, const float* __restrict__ W,
                         float* __restrict__ Y, int M, int K) {
    constexpr int TX = BN / TN;
    __shared__ float Xs[BM][BK + 4];
    __shared__ float Ws[BK][BN];
    int t = threadIdx.x;
    int tx = t % TX, ty = t / TX;
    int bm0 = blockIdx.x * BM;
    float acc[TM][TN] = {};
    for (int k0 = 0; k0 < K; k0 += BK) {
        constexpr int XF4 = BM * BK / 4;
        for (int q = t; q < XF4; q += 256) {
            int r = q / (BK / 4), c = q % (BK / 4);
            int rg = bm0 + r; if (rg >= M) rg = M - 1;
            *(float4*)&Xs[r][c * 4] = *(const float4*)&X[(size_t)rg * K + k0 + c * 4];
        }
        constexpr int WF4 = BK * BN / 4;
        for (int q = t; q < WF4; q += 256) {
            int r = q / (BN / 4), c = q % (BN / 4);
            *(float4*)&Ws[r][c * 4] = *(const float4*)&W[(size_t)(k0 + r) * BN + c * 4];
        }
        __syncthreads();
#pragma unroll 8
        for (int kk = 0; kk < BK; kk++) {
            float a[TM];
#pragma unroll
            for (int i = 0; i < TM; i++) a[i] = Xs[ty * TM + i][kk];
            float4 wv = *(float4*)&Ws[kk][tx * TN];
#pragma unroll
            for (int i = 0; i < TM; i++) {
                acc[i][0] = fmaf(a[i], wv.x, acc[i][0]);
                acc[i][1] = fmaf(a[i], wv.y, acc[i][1]);
                acc[i][2] = fmaf(a[i], wv.z, acc[i][2]);
                acc[i][3] = fmaf(a[i], wv.w, acc[i][3]);
            }
        }
        __syncthreads();
    }
#pragma unroll
    for (int i = 0; i < TM; i++) {
        int rg = bm0 + ty * TM + i;
        if (rg < M)
            *(float4*)&Y[(size_t)rg * BN + tx * TN] =
                make_float4(acc[i][0], acc[i][1], acc[i][2], acc[i][3]);
    }
}

// ================= pull aggregation (4-way unrolled) =================
template <int F, bool RELU>
__global__ void k_pull(const float* __restrict__ in, const int* __restrict__ off,
                       const int* __restrict__ adj, const float* __restrict__ scale,
                       const float* __restrict__ bias, float* __restrict__ out,
                       int nrows) {
    constexpr int TPR = F / 4;
    constexpr int RPB = 256 / TPR;
    int r = blockIdx.x * RPB + threadIdx.x / TPR;
    int lane = threadIdx.x % TPR;
    if (r >= nrows) return;
    int lo = off[r], hi = off[r + 1];
    const float4* in4 = (const float4*)in;
    float4 a0 = {0.f, 0.f, 0.f, 0.f}, a1 = {0.f, 0.f, 0.f, 0.f};
    float4 a2 = {0.f, 0.f, 0.f, 0.f}, a3 = {0.f, 0.f, 0.f, 0.f};
    int j = lo;
    for (; j + 3 < hi; j += 4) {
        int c0 = adj[j], c1 = adj[j + 1], c2 = adj[j + 2], c3 = adj[j + 3];
        float4 v0 = in4[(size_t)c0 * TPR + lane];
        float4 v1 = in4[(size_t)c1 * TPR + lane];
        float4 v2 = in4[(size_t)c2 * TPR + lane];
        float4 v3 = in4[(size_t)c3 * TPR + lane];
        a0.x += v0.x; a0.y += v0.y; a0.z += v0.z; a0.w += v0.w;
        a1.x += v1.x; a1.y += v1.y; a1.z += v1.z; a1.w += v1.w;
        a2.x += v2.x; a2.y += v2.y; a2.z += v2.z; a2.w += v2.w;
        a3.x += v3.x; a3.y += v3.y; a3.z += v3.z; a3.w += v3.w;
    }
    for (; j < hi; j++) {
        int c0 = adj[j];
        float4 v0 = in4[(size_t)c0 * TPR + lane];
        a0.x += v0.x; a0.y += v0.y; a0.z += v0.z; a0.w += v0.w;
    }
    a0.x += a1.x + a2.x + a3.x; a0.y += a1.y + a2.y + a3.y;
    a0.z += a1.z + a2.z + a3.z; a0.w += a1.w + a2.w + a3.w;
    float sc = scale[r];
    if (RELU) {
        float4 b = ((const float4*)bias)[lane];
        a0.x = fmaxf(fmaf(a0.x, sc, b.x), 0.f);
        a0.y = fmaxf(fmaf(a0.y, sc, b.y), 0.f);
        a0.z = fmaxf(fmaf(a0.z, sc, b.z), 0.f);
        a0.w = fmaxf(fmaf(a0.w, sc, b.w), 0.f);
    } else {
        a0.x *= sc; a0.y *= sc; a0.z *= sc; a0.w *= sc;
    }
    ((float4*)out)[(size_t)r * TPR + lane] = a0;
}

// ================= fused final MLP: feat-gather + GEMM(768x256) + W2 head + log_softmax
// BM=64 links, BN=256 hidden, BK=32; 256 threads: TX=64 (lane), TY=4; TM=16, TN=4.
__global__ void __launch_bounds__(256)
k_mlp_gemm(const float* __restrict__ hx1, const float* __restrict__ hx2,
           const float* __restrict__ hx3, const float* __restrict__ gx1,
           const float* __restrict__ gx2, const float* __restrict__ gx3,
           const int* __restrict__ marks, const int* __restrict__ emarks,
           const float* __restrict__ W1, const float* __restrict__ b1,
           const float* __restrict__ W2, const float* __restrict__ b2,
           float* __restrict__ out) {
    constexpr int BM = 64, BN = 256, BK = 32, TM = 16, TN = 4, TX = 64;
    __shared__ float Xs[BM][BK + 4];
    __shared__ float Ws[BK][BN];
    int t = threadIdx.x;
    int tx = t % TX, ty = t / TX;          // tx == lane within wave
    int bm0 = blockIdx.x * BM;
    // each thread stages rows r_a = t/8 and r_b = r_a+32, float4 col-group c4 = t%8
    int r_a = t / 8, r_b = r_a + 32, c4 = t % 8;
    int l_a = bm0 + r_a; if (l_a >= NL) l_a = NL - 1;
    int l_b = bm0 + r_b; if (l_b >= NL) l_b = NL - 1;
    int m_a = marks[l_a], e_a = emarks[l_a];
    int m_b = marks[l_b], e_b = emarks[l_b];

    float acc[TM][TN] = {};
    for (int k0 = 0; k0 < 768; k0 += BK) {
        // ---- stage feat slice (block-uniform slice type) ----
        if (k0 < 192) {
            int f = k0 + c4 * 4;
            const float* g = f < 64 ? gx1 : (f < 128 ? gx2 : gx3);
            int off = f & 63;
            float4 av = *(const float4*)&g[(size_t)e_a * 64 + off];
            float4 bv = *(const float4*)&g[(size_t)(e_a + 1) * 64 + off];
            *(float4*)&Xs[r_a][c4 * 4] = make_float4(fminf(av.x, bv.x), fminf(av.y, bv.y),
                                                     fminf(av.z, bv.z), fminf(av.w, bv.w));
            av = *(const float4*)&g[(size_t)e_b * 64 + off];
            bv = *(const float4*)&g[(size_t)(e_b + 1) * 64 + off];
            *(float4*)&Xs[r_b][c4 * 4] = make_float4(fminf(av.x, bv.x), fminf(av.y, bv.y),
                                                     fminf(av.z, bv.z), fminf(av.w, bv.w));
        } else if (k0 < 384) {
            int f = (k0 - 192) + c4 * 4;
            const float* g = f < 64 ? gx1 : (f < 128 ? gx2 : gx3);
            int off = f & 63;
            float4 av = *(const float4*)&g[(size_t)e_a * 64 + off];
            float4 bv = *(const float4*)&g[(size_t)(e_a + 1) * 64 + off];
            *(float4*)&Xs[r_a][c4 * 4] = make_float4(fmaxf(av.x, bv.x), fmaxf(av.y, bv.y),
                                                     fmaxf(av.z, bv.z), fmaxf(av.w, bv.w));
            av = *(const float4*)&g[(size_t)e_b * 64 + off];
            bv = *(const float4*)&g[(size_t)(e_b + 1) * 64 + off];
            *(float4*)&Xs[r_b][c4 * 4] = make_float4(fmaxf(av.x, bv.x), fmaxf(av.y, bv.y),
                                                     fmaxf(av.z, bv.z), fmaxf(av.w, bv.w));
        } else {
            int f = (k0 - 384) + c4 * 4;
            const float* h = f < 128 ? hx1 : (f < 256 ? hx2 : hx3);
            int off = f & 127;
            *(float4*)&Xs[r_a][c4 * 4] = *(const float4*)&h[(size_t)m_a * 128 + off];
            *(float4*)&Xs[r_b][c4 * 4] = *(const float4*)&h[(size_t)m_b * 128 + off];
        }
        // ---- stage W1 slice ----
        constexpr int WF4 = BK * BN / 4;
        for (int q = t; q < WF4; q += 256) {
            int r = q / (BN / 4), c = q % (BN / 4);
            *(float4*)&Ws[r][c * 4] = *(const float4*)&W1[(size_t)(k0 + r) * BN + c * 4];
        }
        __syncthreads();
#pragma unroll 8
        for (int kk = 0; kk < BK; kk++) {
            float a[TM];
#pragma unroll
            for (int i = 0; i < TM; i++) a[i] = Xs[ty * TM + i][kk];
            float4 wv = *(float4*)&Ws[kk][tx * TN];
#pragma unroll
            for (int i = 0; i < TM; i++) {
                acc[i][0] = fmaf(a[i], wv.x, acc[i][0]);
                acc[i][1] = fmaf(a[i], wv.y, acc[i][1]);
                acc[i][2] = fmaf(a[i], wv.z, acc[i][2]);
                acc[i][3] = fmaf(a[i], wv.w, acc[i][3]);
            }
        }
        __syncthreads();
    }
    // ---- epilogue: bias + relu + W2 head + wave reduce + log_softmax ----
    float4 b1v = *(const float4*)&b1[tx * TN];
    float w20[TN], w21[TN];
#pragma unroll
    for (int j = 0; j < TN; j++) {
        w20[j] = W2[(size_t)(tx * TN + j) * 2 + 0];
        w21[j] = W2[(size_t)(tx * TN + j) * 2 + 1];
    }
    float bb0 = b2[0], bb1 = b2[1];
#pragma unroll
    for (int i = 0; i < TM; i++) {
        float h0 = fmaxf(acc[i][0] + b1v.x, 0.f);
        float h1 = fmaxf(acc[i][1] + b1v.y, 0.f);
        float h2 = fmaxf(acc[i][2] + b1v.z, 0.f);
        float h3 = fmaxf(acc[i][3] + b1v.w, 0.f);
        float p0 = h0 * w20[0] + h1 * w20[1] + h2 * w20[2] + h3 * w20[3];
        float p1 = h0 * w21[0] + h1 * w21[1] + h2 * w21[2] + h3 * w21[3];
#pragma unroll
        for (int d = 32; d > 0; d >>= 1) {
            p0 += __shfl_down(p0, d);
            p1 += __shfl_down(p1, d);
        }
        if (tx == 0) {
            int l = bm0 + ty * TM + i;
            if (l < NL) {
                float l0 = p0 + bb0, l1 = p1 + bb1;
                float mx = fmaxf(l0, l1);
                float lse = mx + logf(expf(l0 - mx) + expf(l1 - mx));
                out[(size_t)l * 2 + 0] = l0 - lse;
                out[(size_t)l * 2 + 1] = l1 - lse;
            }
        }
    }
}

extern "C" void kernel_launch(void* const* d_in, const int* in_sizes, int n_in,
                              void* d_out, int out_size, void* d_ws, size_t ws_size,
                              hipStream_t stream) {
    const float* x      = (const float*)d_in[0];
    const float* ex     = (const float*)d_in[1];
    const int*   ei     = (const int*)d_in[2];
    const int*   marks  = (const int*)d_in[3];
    const int*   emarks = (const int*)d_in[4];
    const float* Wn[3] = {(const float*)d_in[5],  (const float*)d_in[9],  (const float*)d_in[13]};
    const float* bn[3] = {(const float*)d_in[6],  (const float*)d_in[10], (const float*)d_in[14]};
    const float* We[3] = {(const float*)d_in[7],  (const float*)d_in[11], (const float*)d_in[15]};
    const float* be[3] = {(const float*)d_in[8],  (const float*)d_in[12], (const float*)d_in[16]};
    const float* W1 = (const float*)d_in[17];
    const float* b1 = (const float*)d_in[18];
    const float* W2 = (const float*)d_in[19];
    const float* b2 = (const float*)d_in[20];

    // ---- workspace layout ----
    int*   off_n = (int*)d_ws;                 // 50004
    int*   off_h = off_n + 50004;              // 50004
    int*   adj_n = off_h + 50004;              // 800000
    int*   adj_h = adj_n + 800000;             // 800000
    int*   cnt   = adj_h + 800000;             // 100000 (counts, then cursors)
    float* invn  = (float*)(cnt + 100000);     // 50000
    float* invh  = invn + 50000;               // 50000
    float* xw    = invh + 50000;               // 6.4M
    float* heb   = xw + 6400000;               // 6.4M
    float* h[3]  = {heb + 6400000, heb + 12800000, heb + 19200000};   // NN*128 each
    float* g[3]  = {heb + 25600000, heb + 28800000, heb + 32000000};  // NH*64 each

    int* cnt_n = cnt;
    int* cnt_h = cnt + 50000;

    // ---- CSR build ----
    hipMemsetAsync(cnt, 0, 100000 * sizeof(int), stream);
    k_hist<<<(2 * NI + 255) / 256, 256, 0, stream>>>(ei, cnt_n, cnt_h);
    k_scan<<<1, 1024, 0, stream>>>(cnt_n, off_n, NN);
    k_scan<<<1, 1024, 0, stream>>>(cnt_h, off_h, NH);
    hipMemsetAsync(cnt, 0, 100000 * sizeof(int), stream);
    k_fill<<<(2 * NI + 255) / 256, 256, 0, stream>>>(ei, off_n, off_h, cnt_n, cnt_h, adj_n, adj_h);
    k_invdeg<<<(NN + 255) / 256, 256, 0, stream>>>(off_n, invn, NN);
    k_invdeg<<<(NH + 255) / 256, 256, 0, stream>>>(off_h, invh, NH);

    // ---- node convs ----
    const float* cur = x;
    int k = 256;
    for (int i = 0; i < 3; i++) {
        k_gemm_t<64, 128, 64, 8, 4><<<(NN + 63) / 64, 256, 0, stream>>>(cur, Wn[i], xw, NN, k);
        k_pull<128, false><<<(NH + 7) / 8, 256, 0, stream>>>(xw, off_h, adj_h, invh, nullptr, heb, NH);
        k_pull<128, true><<<(NN + 7) / 8, 256, 0, stream>>>(heb, off_n, adj_n, invn, bn[i], h[i], NN);
        cur = h[i];
        k = 128;
    }

    // ---- edge convs (flipped) ----
    cur = ex;
    k = 128;
    for (int i = 0; i < 3; i++) {
        k_gemm_t<64, 64, 64, 4, 4><<<(NH + 63) / 64, 256, 0, stream>>>(cur, We[i], xw, NH, k);
        k_pull<64, false><<<(NN + 15) / 16, 256, 0, stream>>>(xw, off_n, adj_n, invn, nullptr, heb, NN);
        k_pull<64, true><<<(NH + 15) / 16, 256, 0, stream>>>(heb, off_h, adj_h, invh, be[i], g[i], NH);
        cur = g[i];
        k = 64;
    }

    // ---- fused final MLP + head + log_softmax ----
    k_mlp_gemm<<<(NL + 63) / 64, 256, 0, stream>>>(h[0], h[1], h[2], g[0], g[1], g[2],
                                                   marks, emarks, W1, b1, W2, b2, (float*)d_out);
}

// Round 5
// 1253.792 us; speedup vs baseline: 3.1258x; 1.0145x over previous
//
#include <hip/hip_runtime.h>
#include <math.h>

#define NN 50000
#define NH 50000
#define NI 800000
#define NL 20000

// ================= CSR build =================
__global__ void k_hist(const int* __restrict__ ei, int* __restrict__ cnt_n,
                       int* __restrict__ cnt_h) {
    int t = blockIdx.x * blockDim.x + threadIdx.x;
    if (t < NI) atomicAdd(&cnt_n[ei[t]], 1);            // nsrc
    else if (t < 2 * NI) atomicAdd(&cnt_h[ei[t]], 1);   // hdst
}

// one-block exclusive scan of n (~50k) counts -> off[0..n], off[n]=total
__global__ void k_scan(const int* __restrict__ cnt, int* __restrict__ off, int n) {
    __shared__ int part[1024];
    int t = threadIdx.x;
    int chunk = (n + 1023) >> 10;
    int lo = t * chunk, hi = min(lo + chunk, n);
    int s = 0;
    for (int i = lo; i < hi; i++) s += cnt[i];
    part[t] = s;
    __syncthreads();
    for (int d = 1; d < 1024; d <<= 1) {
        int v = (t >= d) ? part[t - d] : 0;
        __syncthreads();
        part[t] += v;
        __syncthreads();
    }
    int run = (t == 0) ? 0 : part[t - 1];
    for (int i = lo; i < hi; i++) { off[i] = run; run += cnt[i]; }
    if (hi == n) off[n] = run;
}

__global__ void k_fill(const int* __restrict__ ei, const int* __restrict__ off_n,
                       const int* __restrict__ off_h, int* __restrict__ cur_n,
                       int* __restrict__ cur_h, int* __restrict__ adj_n,
                       int* __restrict__ adj_h) {
    int t = blockIdx.x * blockDim.x + threadIdx.x;
    if (t < NI) {
        int s = ei[t], d = ei[t + NI];
        int p = atomicAdd(&cur_h[d], 1);
        adj_h[off_h[d] + p] = s;                 // CSR by hyperedge -> node ids
    } else if (t < 2 * NI) {
        int e = t - NI;
        int s = ei[e], d = ei[e + NI];
        int p = atomicAdd(&cur_n[s], 1);
        adj_n[off_n[s] + p] = d;                 // CSR by node -> hyperedge ids
    }
}

__global__ void k_invdeg(const int* __restrict__ off, float* __restrict__ inv, int n) {
    int i = blockIdx.x * blockDim.x + threadIdx.x;
    if (i < n) {
        int d = off[i + 1] - off[i];
        inv[i] = d > 0 ? 1.0f / (float)d : 0.0f;
    }
}

// ================= register-tiled GEMM: Y[M][BN] = X[M][K] @ W[K][BN] =================
template <int BM, int BN, int BK, int TM, int TN>
__global__ void k_gemm_t(const float* __restrict__ X, const float* __restrict__ W,
                         float* __restrict__ Y, int M, int K) {
    constexpr int TX = BN / TN;
    __shared__ float Xs[BM][BK + 4];
    __shared__ float Ws[BK][BN];
    int t = threadIdx.x;
    int tx = t % TX, ty = t / TX;
    int bm0 = blockIdx.x * BM;
    float acc[TM][TN] = {};
    for (int k0 = 0; k0 < K; k0 += BK) {
        constexpr int XF4 = BM * BK / 4;
        for (int q = t; q < XF4; q += 256) {
            int r = q / (BK / 4), c = q % (BK / 4);
            int rg = bm0 + r; if (rg >= M) rg = M - 1;
            *(float4*)&Xs[r][c * 4] = *(const float4*)&X[(size_t)rg * K + k0 + c * 4];
        }
        constexpr int WF4 = BK * BN / 4;
        for (int q = t; q < WF4; q += 256) {
            int r = q / (BN / 4), c = q % (BN / 4);
            *(float4*)&Ws[r][c * 4] = *(const float4*)&W[(size_t)(k0 + r) * BN + c * 4];
        }
        __syncthreads();
#pragma unroll 8
        for (int kk = 0; kk < BK; kk++) {
            float a[TM];
#pragma unroll
            for (int i = 0; i < TM; i++) a[i] = Xs[ty * TM + i][kk];
            float4 wv = *(float4*)&Ws[kk][tx * TN];
#pragma unroll
            for (int i = 0; i < TM; i++) {
                acc[i][0] = fmaf(a[i], wv.x, acc[i][0]);
                acc[i][1] = fmaf(a[i], wv.y, acc[i][1]);
                acc[i][2] = fmaf(a[i], wv.z, acc[i][2]);
                acc[i][3] = fmaf(a[i], wv.w, acc[i][3]);
            }
        }
        __syncthreads();
    }
#pragma unroll
    for (int i = 0; i < TM; i++) {
        int rg = bm0 + ty * TM + i;
        if (rg < M)
            *(float4*)&Y[(size_t)rg * BN + tx * TN] =
                make_float4(acc[i][0], acc[i][1], acc[i][2], acc[i][3]);
    }
}

// ================= pull aggregation (8-way unrolled) =================
template <int F, bool RELU>
__global__ void k_pull(const float* __restrict__ in, const int* __restrict__ off,
                       const int* __restrict__ adj, const float* __restrict__ scale,
                       const float* __restrict__ bias, float* __restrict__ out,
                       int nrows) {
    constexpr int TPR = F / 4;
    constexpr int RPB = 256 / TPR;
    int r = blockIdx.x * RPB + threadIdx.x / TPR;
    int lane = threadIdx.x % TPR;
    if (r >= nrows) return;
    int lo = off[r], hi = off[r + 1];
    const float4* in4 = (const float4*)in;
    float4 a0 = {0.f, 0.f, 0.f, 0.f}, a1 = {0.f, 0.f, 0.f, 0.f};
    float4 a2 = {0.f, 0.f, 0.f, 0.f}, a3 = {0.f, 0.f, 0.f, 0.f};
    int j = lo;
    for (; j + 7 < hi; j += 8) {
        int c0 = adj[j], c1 = adj[j + 1], c2 = adj[j + 2], c3 = adj[j + 3];
        int c4 = adj[j + 4], c5 = adj[j + 5], c6 = adj[j + 6], c7 = adj[j + 7];
        float4 v0 = in4[(size_t)c0 * TPR + lane];
        float4 v1 = in4[(size_t)c1 * TPR + lane];
        float4 v2 = in4[(size_t)c2 * TPR + lane];
        float4 v3 = in4[(size_t)c3 * TPR + lane];
        float4 v4 = in4[(size_t)c4 * TPR + lane];
        float4 v5 = in4[(size_t)c5 * TPR + lane];
        float4 v6 = in4[(size_t)c6 * TPR + lane];
        float4 v7 = in4[(size_t)c7 * TPR + lane];
        a0.x += v0.x; a0.y += v0.y; a0.z += v0.z; a0.w += v0.w;
        a1.x += v1.x; a1.y += v1.y; a1.z += v1.z; a1.w += v1.w;
        a2.x += v2.x; a2.y += v2.y; a2.z += v2.z; a2.w += v2.w;
        a3.x += v3.x; a3.y += v3.y; a3.z += v3.z; a3.w += v3.w;
        a0.x += v4.x; a0.y += v4.y; a0.z += v4.z; a0.w += v4.w;
        a1.x += v5.x; a1.y += v5.y; a1.z += v5.z; a1.w += v5.w;
        a2.x += v6.x; a2.y += v6.y; a2.z += v6.z; a2.w += v6.w;
        a3.x += v7.x; a3.y += v7.y; a3.z += v7.z; a3.w += v7.w;
    }
    for (; j + 1 < hi; j += 2) {
        int c0 = adj[j], c1 = adj[j + 1];
        float4 v0 = in4[(size_t)c0 * TPR + lane];
        float4 v1 = in4[(size_t)c1 * TPR + lane];
        a0.x += v0.x; a0.y += v0.y; a0.z += v0.z; a0.w += v0.w;
        a1.x += v1.x; a1.y += v1.y; a1.z += v1.z; a1.w += v1.w;
    }
    if (j < hi) {
        int c0 = adj[j];
        float4 v0 = in4[(size_t)c0 * TPR + lane];
        a0.x += v0.x; a0.y += v0.y; a0.z += v0.z; a0.w += v0.w;
    }
    a0.x += a1.x + a2.x + a3.x; a0.y += a1.y + a2.y + a3.y;
    a0.z += a1.z + a2.z + a3.z; a0.w += a1.w + a2.w + a3.w;
    float sc = scale[r];
    if (RELU) {
        float4 b = ((const float4*)bias)[lane];
        a0.x = fmaxf(fmaf(a0.x, sc, b.x), 0.f);
        a0.y = fmaxf(fmaf(a0.y, sc, b.y), 0.f);
        a0.z = fmaxf(fmaf(a0.z, sc, b.z), 0.f);
        a0.w = fmaxf(fmaf(a0.w, sc, b.w), 0.f);
    } else {
        a0.x *= sc; a0.y *= sc; a0.z *= sc; a0.w *= sc;
    }
    ((float4*)out)[(size_t)r * TPR + lane] = a0;
}

// ================= fused final MLP: feat-gather + GEMM(768x256) + W2 head + log_softmax
// BM=16 links, BN=256 hidden, BK=32; 256 threads: TX=64 (lane), TY=4; TM=4, TN=4.
__global__ void __launch_bounds__(256)
k_mlp_gemm(const float* __restrict__ hx1, const float* __restrict__ hx2,
           const float* __restrict__ hx3, const float* __restrict__ gx1,
           const float* __restrict__ gx2, const float* __restrict__ gx3,
           const int* __restrict__ marks, const int* __restrict__ emarks,
           const float* __restrict__ W1, const float* __restrict__ b1,
           const float* __restrict__ W2, const float* __restrict__ b2,
           float* __restrict__ out) {
    constexpr int BM = 16, BN = 256, BK = 32, TM = 4, TN = 4, TX = 64;
    __shared__ float Xs[BM][BK + 4];
    __shared__ float Ws[BK][BN];
    int t = threadIdx.x;
    int tx = t % TX, ty = t / TX;          // ty uniform within a wave
    int bm0 = blockIdx.x * BM;
    // staging thread map: t<128 -> row r = t/8, float4 col-group c4 = t%8
    int r_s = t >> 3, c4 = t & 7;
    int l_s = bm0 + r_s; if (l_s >= NL) l_s = NL - 1;
    int m_s = 0, e_s = 0;
    if (t < 128) { m_s = marks[l_s]; e_s = emarks[l_s]; }

    float acc[TM][TN] = {};
    for (int k0 = 0; k0 < 768; k0 += BK) {
        if (t < 128) {
            if (k0 < 192) {
                int f = k0 + c4 * 4;
                const float* g = f < 64 ? gx1 : (f < 128 ? gx2 : gx3);
                int off = f & 63;
                float4 av = *(const float4*)&g[(size_t)e_s * 64 + off];
                float4 bv = *(const float4*)&g[(size_t)(e_s + 1) * 64 + off];
                *(float4*)&Xs[r_s][c4 * 4] = make_float4(fminf(av.x, bv.x), fminf(av.y, bv.y),
                                                         fminf(av.z, bv.z), fminf(av.w, bv.w));
            } else if (k0 < 384) {
                int f = (k0 - 192) + c4 * 4;
                const float* g = f < 64 ? gx1 : (f < 128 ? gx2 : gx3);
                int off = f & 63;
                float4 av = *(const float4*)&g[(size_t)e_s * 64 + off];
                float4 bv = *(const float4*)&g[(size_t)(e_s + 1) * 64 + off];
                *(float4*)&Xs[r_s][c4 * 4] = make_float4(fmaxf(av.x, bv.x), fmaxf(av.y, bv.y),
                                                         fmaxf(av.z, bv.z), fmaxf(av.w, bv.w));
            } else {
                int f = (k0 - 384) + c4 * 4;
                const float* h = f < 128 ? hx1 : (f < 256 ? hx2 : hx3);
                int off = f & 127;
                *(float4*)&Xs[r_s][c4 * 4] = *(const float4*)&h[(size_t)m_s * 128 + off];
            }
        }
        constexpr int WF4 = BK * BN / 4;
        for (int q = t; q < WF4; q += 256) {
            int r = q >> 6, c = q & 63;
            *(float4*)&Ws[r][c * 4] = *(const float4*)&W1[(size_t)(k0 + r) * BN + c * 4];
        }
        __syncthreads();
#pragma unroll 8
        for (int kk = 0; kk < BK; kk++) {
            float a[TM];
#pragma unroll
            for (int i = 0; i < TM; i++) a[i] = Xs[ty * TM + i][kk];   // wave-uniform broadcast
            float4 wv = *(float4*)&Ws[kk][tx * TN];
#pragma unroll
            for (int i = 0; i < TM; i++) {
                acc[i][0] = fmaf(a[i], wv.x, acc[i][0]);
                acc[i][1] = fmaf(a[i], wv.y, acc[i][1]);
                acc[i][2] = fmaf(a[i], wv.z, acc[i][2]);
                acc[i][3] = fmaf(a[i], wv.w, acc[i][3]);
            }
        }
        __syncthreads();
    }
    // ---- epilogue: bias + relu + W2 head + wave reduce + log_softmax ----
    float4 b1v = *(const float4*)&b1[tx * TN];
    float w20[TN], w21[TN];
#pragma unroll
    for (int j = 0; j < TN; j++) {
        w20[j] = W2[(size_t)(tx * TN + j) * 2 + 0];
        w21[j] = W2[(size_t)(tx * TN + j) * 2 + 1];
    }
    float bb0 = b2[0], bb1 = b2[1];
#pragma unroll
    for (int i = 0; i < TM; i++) {
        float h0 = fmaxf(acc[i][0] + b1v.x, 0.f);
        float h1 = fmaxf(acc[i][1] + b1v.y, 0.f);
        float h2 = fmaxf(acc[i][2] + b1v.z, 0.f);
        float h3 = fmaxf(acc[i][3] + b1v.w, 0.f);
        float p0 = h0 * w20[0] + h1 * w20[1] + h2 * w20[2] + h3 * w20[3];
        float p1 = h0 * w21[0] + h1 * w21[1] + h2 * w21[2] + h3 * w21[3];
#pragma unroll
        for (int d = 32; d > 0; d >>= 1) {
            p0 += __shfl_down(p0, d);
            p1 += __shfl_down(p1, d);
        }
        if (tx == 0) {
            int l = bm0 + ty * TM + i;
            if (l < NL) {
                float l0 = p0 + bb0, l1 = p1 + bb1;
                float mx = fmaxf(l0, l1);
                float lse = mx + logf(expf(l0 - mx) + expf(l1 - mx));
                out[(size_t)l * 2 + 0] = l0 - lse;
                out[(size_t)l * 2 + 1] = l1 - lse;
            }
        }
    }
}

extern "C" void kernel_launch(void* const* d_in, const int* in_sizes, int n_in,
                              void* d_out, int out_size, void* d_ws, size_t ws_size,
                              hipStream_t stream) {
    const float* x      = (const float*)d_in[0];
    const float* ex     = (const float*)d_in[1];
    const int*   ei     = (const int*)d_in[2];
    const int*   marks  = (const int*)d_in[3];
    const int*   emarks = (const int*)d_in[4];
    const float* Wn[3] = {(const float*)d_in[5],  (const float*)d_in[9],  (const float*)d_in[13]};
    const float* bn[3] = {(const float*)d_in[6],  (const float*)d_in[10], (const float*)d_in[14]};
    const float* We[3] = {(const float*)d_in[7],  (const float*)d_in[11], (const float*)d_in[15]};
    const float* be[3] = {(const float*)d_in[8],  (const float*)d_in[12], (const float*)d_in[16]};
    const float* W1 = (const float*)d_in[17];
    const float* b1 = (const float*)d_in[18];
    const float* W2 = (const float*)d_in[19];
    const float* b2 = (const float*)d_in[20];

    // ---- workspace layout ----
    int*   off_n = (int*)d_ws;                 // 50004
    int*   off_h = off_n + 50004;              // 50004
    int*   adj_n = off_h + 50004;              // 800000
    int*   adj_h = adj_n + 800000;             // 800000
    int*   cnt   = adj_h + 800000;             // 100000 (counts, then cursors)
    float* invn  = (float*)(cnt + 100000);     // 50000
    float* invh  = invn + 50000;               // 50000
    float* xw    = invh + 50000;               // 6.4M
    float* heb   = xw + 6400000;               // 6.4M
    float* h[3]  = {heb + 6400000, heb + 12800000, heb + 19200000};   // NN*128 each
    float* g[3]  = {heb + 25600000, heb + 28800000, heb + 32000000};  // NH*64 each

    int* cnt_n = cnt;
    int* cnt_h = cnt + 50000;

    // ---- CSR build ----
    hipMemsetAsync(cnt, 0, 100000 * sizeof(int), stream);
    k_hist<<<(2 * NI + 255) / 256, 256, 0, stream>>>(ei, cnt_n, cnt_h);
    k_scan<<<1, 1024, 0, stream>>>(cnt_n, off_n, NN);
    k_scan<<<1, 1024, 0, stream>>>(cnt_h, off_h, NH);
    hipMemsetAsync(cnt, 0, 100000 * sizeof(int), stream);
    k_fill<<<(2 * NI + 255) / 256, 256, 0, stream>>>(ei, off_n, off_h, cnt_n, cnt_h, adj_n, adj_h);
    k_invdeg<<<(NN + 255) / 256, 256, 0, stream>>>(off_n, invn, NN);
    k_invdeg<<<(NH + 255) / 256, 256, 0, stream>>>(off_h, invh, NH);

    // ---- node convs ----
    const float* cur = x;
    int k = 256;
    for (int i = 0; i < 3; i++) {
        k_gemm_t<64, 128, 64, 8, 4><<<(NN + 63) / 64, 256, 0, stream>>>(cur, Wn[i], xw, NN, k);
        k_pull<128, false><<<(NH + 7) / 8, 256, 0, stream>>>(xw, off_h, adj_h, invh, nullptr, heb, NH);
        k_pull<128, true><<<(NN + 7) / 8, 256, 0, stream>>>(heb, off_n, adj_n, invn, bn[i], h[i], NN);
        cur = h[i];
        k = 128;
    }

    // ---- edge convs (flipped) ----
    cur = ex;
    k = 128;
    for (int i = 0; i < 3; i++) {
        k_gemm_t<64, 64, 64, 4, 4><<<(NH + 63) / 64, 256, 0, stream>>>(cur, We[i], xw, NH, k);
        k_pull<64, false><<<(NN + 15) / 16, 256, 0, stream>>>(xw, off_n, adj_n, invn, nullptr, heb, NN);
        k_pull<64, true><<<(NH + 15) / 16, 256, 0, stream>>>(heb, off_h, adj_h, invh, be[i], g[i], NH);
        cur = g[i];
        k = 64;
    }

    // ---- fused final MLP + head + log_softmax ----
    k_mlp_gemm<<<(NL + 15) / 16, 256, 0, stream>>>(h[0], h[1], h[2], g[0], g[1], g[2],
                                                   marks, emarks, W1, b1, W2, b2, (float*)d_out);
}

// Round 6
// 1052.988 us; speedup vs baseline: 3.7219x; 1.1907x over previous
//
#include <hip/hip_runtime.h>
#include <hip/hip_fp16.h>
#include <math.h>

#define NN 50000
#define NH 50000
#define NI 800000
#define NL 20000

// ================= helpers =================
static __device__ __forceinline__ void acc_h4(float4& a, float2 raw) {
    float2 lo = __half22float2(*(__half2*)&raw.x);
    float2 hi = __half22float2(*(__half2*)&raw.y);
    a.x += lo.x; a.y += lo.y; a.z += hi.x; a.w += hi.y;
}
static __device__ __forceinline__ float2 pack_h4(float4 v) {
    float2 st;
    *(__half2*)&st.x = __float22half2_rn(make_float2(v.x, v.y));
    *(__half2*)&st.y = __float22half2_rn(make_float2(v.z, v.w));
    return st;
}
static __device__ __forceinline__ float4 unpack_h4(float2 raw) {
    float2 lo = __half22float2(*(__half2*)&raw.x);
    float2 hi = __half22float2(*(__half2*)&raw.y);
    return make_float4(lo.x, lo.y, hi.x, hi.y);
}

// ================= fp32 -> fp16 conversion (n4 = n/4 quads) =================
__global__ void k_f2h(const float* __restrict__ in, __half* __restrict__ out, int n4) {
    int i = blockIdx.x * blockDim.x + threadIdx.x;
    if (i >= n4) return;
    float4 v = ((const float4*)in)[i];
    ((float2*)out)[i] = pack_h4(v);
}

// ================= CSR build =================
__global__ void k_hist(const int* __restrict__ ei, int* __restrict__ cnt_n,
                       int* __restrict__ cnt_h) {
    int t = blockIdx.x * blockDim.x + threadIdx.x;
    if (t < NI) atomicAdd(&cnt_n[ei[t]], 1);
    else if (t < 2 * NI) atomicAdd(&cnt_h[ei[t]], 1);
}

__global__ void k_scan(const int* __restrict__ cnt, int* __restrict__ off, int n) {
    __shared__ int part[1024];
    int t = threadIdx.x;
    int chunk = (n + 1023) >> 10;
    int lo = t * chunk, hi = min(lo + chunk, n);
    int s = 0;
    for (int i = lo; i < hi; i++) s += cnt[i];
    part[t] = s;
    __syncthreads();
    for (int d = 1; d < 1024; d <<= 1) {
        int v = (t >= d) ? part[t - d] : 0;
        __syncthreads();
        part[t] += v;
        __syncthreads();
    }
    int run = (t == 0) ? 0 : part[t - 1];
    for (int i = lo; i < hi; i++) { off[i] = run; run += cnt[i]; }
    if (hi == n) off[n] = run;
}

__global__ void k_fill(const int* __restrict__ ei, const int* __restrict__ off_n,
                       const int* __restrict__ off_h, int* __restrict__ cur_n,
                       int* __restrict__ cur_h, int* __restrict__ adj_n,
                       int* __restrict__ adj_h) {
    int t = blockIdx.x * blockDim.x + threadIdx.x;
    if (t < NI) {
        int s = ei[t], d = ei[t + NI];
        int p = atomicAdd(&cur_h[d], 1);
        adj_h[off_h[d] + p] = s;
    } else if (t < 2 * NI) {
        int e = t - NI;
        int s = ei[e], d = ei[e + NI];
        int p = atomicAdd(&cur_n[s], 1);
        adj_n[off_n[s] + p] = d;
    }
}

__global__ void k_invdeg(const int* __restrict__ off, float* __restrict__ inv, int n) {
    int i = blockIdx.x * blockDim.x + threadIdx.x;
    if (i < n) {
        int d = off[i + 1] - off[i];
        inv[i] = d > 0 ? 1.0f / (float)d : 0.0f;
    }
}

// ================= GEMM: Y[M][BN](fp16) = X[M][K](fp16) @ W[K][BN](fp32) ========
// Transposed LDS A-tile: XsT[BK][BM+4] so A-reads are broadcast ds_read_b128.
template <int BM, int BN, int BK, int TM, int TN>
__global__ void k_gemm_h(const __half* __restrict__ X, const float* __restrict__ W,
                         __half* __restrict__ Y, int M, int K) {
    constexpr int TX = BN / TN;
    __shared__ float XsT[BK][BM + 4];
    __shared__ float Ws[BK][BN];
    int t = threadIdx.x;
    int tx = t % TX, ty = t / TX;
    int bm0 = blockIdx.x * BM;
    float4 acc4[TM];
#pragma unroll
    for (int i = 0; i < TM; i++) acc4[i] = make_float4(0.f, 0.f, 0.f, 0.f);

    for (int k0 = 0; k0 < K; k0 += BK) {
        // stage X (fp16 -> fp32, transposed)
        constexpr int XQ = BM * BK / 4;           // 4-half quads
        for (int q = t; q < XQ; q += 256) {
            int r = q / (BK / 4), c = q % (BK / 4);
            int rg = bm0 + r; if (rg >= M) rg = M - 1;
            float2 raw = *(const float2*)&X[(size_t)rg * K + k0 + c * 4];
            float4 f = unpack_h4(raw);
            XsT[c * 4 + 0][r] = f.x;
            XsT[c * 4 + 1][r] = f.y;
            XsT[c * 4 + 2][r] = f.z;
            XsT[c * 4 + 3][r] = f.w;
        }
        // stage W (fp32)
        constexpr int WF4 = BK * BN / 4;
        for (int q = t; q < WF4; q += 256) {
            int r = q / (BN / 4), c = q % (BN / 4);
            *(float4*)&Ws[r][c * 4] = *(const float4*)&W[(size_t)(k0 + r) * BN + c * 4];
        }
        __syncthreads();
#pragma unroll 8
        for (int kk = 0; kk < BK; kk++) {
            float4 wv = *(float4*)&Ws[kk][tx * TN];
#pragma unroll
            for (int i4 = 0; i4 < TM / 4; i4++) {
                float4 av = *(float4*)&XsT[kk][ty * TM + i4 * 4];
                acc4[i4 * 4 + 0].x = fmaf(av.x, wv.x, acc4[i4 * 4 + 0].x);
                acc4[i4 * 4 + 0].y = fmaf(av.x, wv.y, acc4[i4 * 4 + 0].y);
                acc4[i4 * 4 + 0].z = fmaf(av.x, wv.z, acc4[i4 * 4 + 0].z);
                acc4[i4 * 4 + 0].w = fmaf(av.x, wv.w, acc4[i4 * 4 + 0].w);
                acc4[i4 * 4 + 1].x = fmaf(av.y, wv.x, acc4[i4 * 4 + 1].x);
                acc4[i4 * 4 + 1].y = fmaf(av.y, wv.y, acc4[i4 * 4 + 1].y);
                acc4[i4 * 4 + 1].z = fmaf(av.y, wv.z, acc4[i4 * 4 + 1].z);
                acc4[i4 * 4 + 1].w = fmaf(av.y, wv.w, acc4[i4 * 4 + 1].w);
                acc4[i4 * 4 + 2].x = fmaf(av.z, wv.x, acc4[i4 * 4 + 2].x);
                acc4[i4 * 4 + 2].y = fmaf(av.z, wv.y, acc4[i4 * 4 + 2].y);
                acc4[i4 * 4 + 2].z = fmaf(av.z, wv.z, acc4[i4 * 4 + 2].z);
                acc4[i4 * 4 + 2].w = fmaf(av.z, wv.w, acc4[i4 * 4 + 2].w);
                acc4[i4 * 4 + 3].x = fmaf(av.w, wv.x, acc4[i4 * 4 + 3].x);
                acc4[i4 * 4 + 3].y = fmaf(av.w, wv.y, acc4[i4 * 4 + 3].y);
                acc4[i4 * 4 + 3].z = fmaf(av.w, wv.z, acc4[i4 * 4 + 3].z);
                acc4[i4 * 4 + 3].w = fmaf(av.w, wv.w, acc4[i4 * 4 + 3].w);
            }
        }
        __syncthreads();
    }
#pragma unroll
    for (int i = 0; i < TM; i++) {
        int rg = bm0 + ty * TM + i;
        if (rg < M)
            *(float2*)&Y[(size_t)rg * BN + tx * TN] = pack_h4(acc4[i]);
    }
}

// ================= pull aggregation over fp16 tables (8-way unrolled) ========
// out[r][:] = scale[r] * sum_j in[adj[j]][:]   (+bias, relu); 8B (4 halfs) per lane
template <int F, bool RELU>
__global__ void k_pull_h(const __half* __restrict__ in, const int* __restrict__ off,
                         const int* __restrict__ adj, const float* __restrict__ scale,
                         const float* __restrict__ bias, __half* __restrict__ out,
                         int nrows) {
    constexpr int TPR = F / 4;
    constexpr int RPB = 256 / TPR;
    int r = blockIdx.x * RPB + threadIdx.x / TPR;
    int lane = threadIdx.x % TPR;
    if (r >= nrows) return;
    int lo = off[r], hi = off[r + 1];
    const float2* in2 = (const float2*)in;
    float4 a0 = {0.f, 0.f, 0.f, 0.f}, a1 = {0.f, 0.f, 0.f, 0.f};
    float4 a2 = {0.f, 0.f, 0.f, 0.f}, a3 = {0.f, 0.f, 0.f, 0.f};
    int j = lo;
    for (; j + 7 < hi; j += 8) {
        int c0 = adj[j], c1 = adj[j + 1], c2 = adj[j + 2], c3 = adj[j + 3];
        int c4 = adj[j + 4], c5 = adj[j + 5], c6 = adj[j + 6], c7 = adj[j + 7];
        float2 v0 = in2[(size_t)c0 * TPR + lane];
        float2 v1 = in2[(size_t)c1 * TPR + lane];
        float2 v2 = in2[(size_t)c2 * TPR + lane];
        float2 v3 = in2[(size_t)c3 * TPR + lane];
        float2 v4 = in2[(size_t)c4 * TPR + lane];
        float2 v5 = in2[(size_t)c5 * TPR + lane];
        float2 v6 = in2[(size_t)c6 * TPR + lane];
        float2 v7 = in2[(size_t)c7 * TPR + lane];
        acc_h4(a0, v0); acc_h4(a1, v1); acc_h4(a2, v2); acc_h4(a3, v3);
        acc_h4(a0, v4); acc_h4(a1, v5); acc_h4(a2, v6); acc_h4(a3, v7);
    }
    for (; j + 1 < hi; j += 2) {
        int c0 = adj[j], c1 = adj[j + 1];
        float2 v0 = in2[(size_t)c0 * TPR + lane];
        float2 v1 = in2[(size_t)c1 * TPR + lane];
        acc_h4(a0, v0); acc_h4(a1, v1);
    }
    if (j < hi) {
        float2 v0 = in2[(size_t)adj[j] * TPR + lane];
        acc_h4(a0, v0);
    }
    a0.x += a1.x + a2.x + a3.x; a0.y += a1.y + a2.y + a3.y;
    a0.z += a1.z + a2.z + a3.z; a0.w += a1.w + a2.w + a3.w;
    float sc = scale[r];
    if (RELU) {
        float4 b = ((const float4*)bias)[lane];
        a0.x = fmaxf(fmaf(a0.x, sc, b.x), 0.f);
        a0.y = fmaxf(fmaf(a0.y, sc, b.y), 0.f);
        a0.z = fmaxf(fmaf(a0.z, sc, b.z), 0.f);
        a0.w = fmaxf(fmaf(a0.w, sc, b.w), 0.f);
    } else {
        a0.x *= sc; a0.y *= sc; a0.z *= sc; a0.w *= sc;
    }
    ((float2*)out)[(size_t)r * TPR + lane] = pack_h4(a0);
}

// ================= fused final MLP (fp16 feat/W1, fp32 math) ==================
// BM=16 links, BN=256, BK=32; 256 threads: TX=64 (lane), TY=4 waves; TM=4, TN=4.
__global__ void __launch_bounds__(256)
k_mlp_gemm(const __half* __restrict__ hx1, const __half* __restrict__ hx2,
           const __half* __restrict__ hx3, const __half* __restrict__ gx1,
           const __half* __restrict__ gx2, const __half* __restrict__ gx3,
           const int* __restrict__ marks, const int* __restrict__ emarks,
           const __half* __restrict__ W1h, const float* __restrict__ b1,
           const float* __restrict__ W2, const float* __restrict__ b2,
           float* __restrict__ out) {
    constexpr int BM = 16, BN = 256, BK = 32, TM = 4, TN = 4, TX = 64;
    __shared__ float XsT[BK][BM + 4];
    __shared__ float Ws[BK][BN];
    int t = threadIdx.x;
    int tx = t % TX, ty = t / TX;          // ty = wave id (uniform)
    int bm0 = blockIdx.x * BM;
    int r_s = t >> 3, c4 = t & 7;
    int l_s = bm0 + r_s; if (l_s >= NL) l_s = NL - 1;
    int m_s = 0, e_s = 0;
    if (t < 128) { m_s = marks[l_s]; e_s = emarks[l_s]; }

    float4 acc4[TM];
#pragma unroll
    for (int i = 0; i < TM; i++) acc4[i] = make_float4(0.f, 0.f, 0.f, 0.f);

    for (int k0 = 0; k0 < 768; k0 += BK) {
        if (t < 128) {
            float4 f;
            if (k0 < 384) {
                int fbase = (k0 < 192 ? k0 : k0 - 192) + c4 * 4;
                const __half* g = fbase < 64 ? gx1 : (fbase < 128 ? gx2 : gx3);
                int off = fbase & 63;
                float4 av = unpack_h4(*(const float2*)&g[(size_t)e_s * 64 + off]);
                float4 bv = unpack_h4(*(const float2*)&g[(size_t)(e_s + 1) * 64 + off]);
                if (k0 < 192)
                    f = make_float4(fminf(av.x, bv.x), fminf(av.y, bv.y),
                                    fminf(av.z, bv.z), fminf(av.w, bv.w));
                else
                    f = make_float4(fmaxf(av.x, bv.x), fmaxf(av.y, bv.y),
                                    fmaxf(av.z, bv.z), fmaxf(av.w, bv.w));
            } else {
                int fbase = (k0 - 384) + c4 * 4;
                const __half* h = fbase < 128 ? hx1 : (fbase < 256 ? hx2 : hx3);
                int off = fbase & 127;
                f = unpack_h4(*(const float2*)&h[(size_t)m_s * 128 + off]);
            }
            XsT[c4 * 4 + 0][r_s] = f.x;
            XsT[c4 * 4 + 1][r_s] = f.y;
            XsT[c4 * 4 + 2][r_s] = f.z;
            XsT[c4 * 4 + 3][r_s] = f.w;
        }
        // stage W1 (fp16 -> fp32)
        constexpr int WQ = BK * BN / 4;
        for (int q = t; q < WQ; q += 256) {
            int r = q >> 6, c = q & 63;
            float4 f = unpack_h4(*(const float2*)&W1h[(size_t)(k0 + r) * 256 + c * 4]);
            *(float4*)&Ws[r][c * 4] = f;
        }
        __syncthreads();
#pragma unroll 8
        for (int kk = 0; kk < BK; kk++) {
            float4 av = *(float4*)&XsT[kk][ty * TM];     // wave-uniform broadcast b128
            float4 wv = *(float4*)&Ws[kk][tx * TN];
            acc4[0].x = fmaf(av.x, wv.x, acc4[0].x);
            acc4[0].y = fmaf(av.x, wv.y, acc4[0].y);
            acc4[0].z = fmaf(av.x, wv.z, acc4[0].z);
            acc4[0].w = fmaf(av.x, wv.w, acc4[0].w);
            acc4[1].x = fmaf(av.y, wv.x, acc4[1].x);
            acc4[1].y = fmaf(av.y, wv.y, acc4[1].y);
            acc4[1].z = fmaf(av.y, wv.z, acc4[1].z);
            acc4[1].w = fmaf(av.y, wv.w, acc4[1].w);
            acc4[2].x = fmaf(av.z, wv.x, acc4[2].x);
            acc4[2].y = fmaf(av.z, wv.y, acc4[2].y);
            acc4[2].z = fmaf(av.z, wv.z, acc4[2].z);
            acc4[2].w = fmaf(av.z, wv.w, acc4[2].w);
            acc4[3].x = fmaf(av.w, wv.x, acc4[3].x);
            acc4[3].y = fmaf(av.w, wv.y, acc4[3].y);
            acc4[3].z = fmaf(av.w, wv.z, acc4[3].z);
            acc4[3].w = fmaf(av.w, wv.w, acc4[3].w);
        }
        __syncthreads();
    }
    // ---- epilogue: bias + relu + W2 head + wave reduce + log_softmax ----
    float4 b1v = *(const float4*)&b1[tx * TN];
    float w20[TN], w21[TN];
#pragma unroll
    for (int jj = 0; jj < TN; jj++) {
        w20[jj] = W2[(size_t)(tx * TN + jj) * 2 + 0];
        w21[jj] = W2[(size_t)(tx * TN + jj) * 2 + 1];
    }
    float bb0 = b2[0], bb1 = b2[1];
#pragma unroll
    for (int i = 0; i < TM; i++) {
        float h0 = fmaxf(acc4[i].x + b1v.x, 0.f);
        float h1 = fmaxf(acc4[i].y + b1v.y, 0.f);
        float h2 = fmaxf(acc4[i].z + b1v.z, 0.f);
        float h3 = fmaxf(acc4[i].w + b1v.w, 0.f);
        float p0 = h0 * w20[0] + h1 * w20[1] + h2 * w20[2] + h3 * w20[3];
        float p1 = h0 * w21[0] + h1 * w21[1] + h2 * w21[2] + h3 * w21[3];
#pragma unroll
        for (int d = 32; d > 0; d >>= 1) {
            p0 += __shfl_down(p0, d);
            p1 += __shfl_down(p1, d);
        }
        if (tx == 0) {
            int l = bm0 + ty * TM + i;
            if (l < NL) {
                float l0 = p0 + bb0, l1 = p1 + bb1;
                float mx = fmaxf(l0, l1);
                float lse = mx + logf(expf(l0 - mx) + expf(l1 - mx));
                out[(size_t)l * 2 + 0] = l0 - lse;
                out[(size_t)l * 2 + 1] = l1 - lse;
            }
        }
    }
}

extern "C" void kernel_launch(void* const* d_in, const int* in_sizes, int n_in,
                              void* d_out, int out_size, void* d_ws, size_t ws_size,
                              hipStream_t stream) {
    const float* x      = (const float*)d_in[0];
    const float* ex     = (const float*)d_in[1];
    const int*   ei     = (const int*)d_in[2];
    const int*   marks  = (const int*)d_in[3];
    const int*   emarks = (const int*)d_in[4];
    const float* Wn[3] = {(const float*)d_in[5],  (const float*)d_in[9],  (const float*)d_in[13]};
    const float* bn[3] = {(const float*)d_in[6],  (const float*)d_in[10], (const float*)d_in[14]};
    const float* We[3] = {(const float*)d_in[7],  (const float*)d_in[11], (const float*)d_in[15]};
    const float* be[3] = {(const float*)d_in[8],  (const float*)d_in[12], (const float*)d_in[16]};
    const float* W1 = (const float*)d_in[17];
    const float* b1 = (const float*)d_in[18];
    const float* W2 = (const float*)d_in[19];
    const float* b2 = (const float*)d_in[20];

    // ---- workspace layout ----
    int*    off_n = (int*)d_ws;                // 50004
    int*    off_h = off_n + 50004;             // 50004
    int*    adj_n = off_h + 50004;             // 800000
    int*    adj_h = adj_n + 800000;            // 800000
    int*    cnt   = adj_h + 800000;            // 100000
    float*  invn  = (float*)(cnt + 100000);    // 50000
    float*  invh  = invn + 50000;              // 50000
    __half* xh    = (__half*)(invh + 50000);   // 12.8M halfs
    __half* exh   = xh + 12800000;             // 6.4M
    __half* W1h   = exh + 6400000;             // 196608
    __half* xwb   = W1h + 196608;              // 6.4M
    __half* heb   = xwb + 6400000;             // 6.4M
    __half* h[3]  = {heb + 6400000, heb + 12800000, heb + 19200000};  // 6.4M each
    __half* g[3]  = {h[2] + 6400000, h[2] + 9600000, h[2] + 12800000}; // 3.2M each

    int* cnt_n = cnt;
    int* cnt_h = cnt + 50000;

    // ---- fp16 conversions ----
    k_f2h<<<(3200000 + 255) / 256, 256, 0, stream>>>(x, xh, 3200000);
    k_f2h<<<(1600000 + 255) / 256, 256, 0, stream>>>(ex, exh, 1600000);
    k_f2h<<<(49152 + 255) / 256, 256, 0, stream>>>(W1, W1h, 49152);

    // ---- CSR build ----
    hipMemsetAsync(cnt, 0, 100000 * sizeof(int), stream);
    k_hist<<<(2 * NI + 255) / 256, 256, 0, stream>>>(ei, cnt_n, cnt_h);
    k_scan<<<1, 1024, 0, stream>>>(cnt_n, off_n, NN);
    k_scan<<<1, 1024, 0, stream>>>(cnt_h, off_h, NH);
    hipMemsetAsync(cnt, 0, 100000 * sizeof(int), stream);
    k_fill<<<(2 * NI + 255) / 256, 256, 0, stream>>>(ei, off_n, off_h, cnt_n, cnt_h, adj_n, adj_h);
    k_invdeg<<<(NN + 255) / 256, 256, 0, stream>>>(off_n, invn, NN);
    k_invdeg<<<(NH + 255) / 256, 256, 0, stream>>>(off_h, invh, NH);

    // ---- node convs ----
    const __half* cur = xh;
    int k = 256;
    for (int i = 0; i < 3; i++) {
        k_gemm_h<64, 128, 64, 8, 4><<<(NN + 63) / 64, 256, 0, stream>>>(cur, Wn[i], xwb, NN, k);
        k_pull_h<128, false><<<(NH + 7) / 8, 256, 0, stream>>>(xwb, off_h, adj_h, invh, nullptr, heb, NH);
        k_pull_h<128, true><<<(NN + 7) / 8, 256, 0, stream>>>(heb, off_n, adj_n, invn, bn[i], h[i], NN);
        cur = h[i];
        k = 128;
    }

    // ---- edge convs (flipped) ----
    cur = exh;
    k = 128;
    for (int i = 0; i < 3; i++) {
        k_gemm_h<64, 64, 64, 4, 4><<<(NH + 63) / 64, 256, 0, stream>>>(cur, We[i], xwb, NH, k);
        k_pull_h<64, false><<<(NN + 15) / 16, 256, 0, stream>>>(xwb, off_n, adj_n, invn, nullptr, heb, NN);
        k_pull_h<64, true><<<(NH + 15) / 16, 256, 0, stream>>>(heb, off_h, adj_h, invh, be[i], g[i], NH);
        cur = g[i];
        k = 64;
    }

    // ---- fused final MLP + head + log_softmax ----
    k_mlp_gemm<<<(NL + 15) / 16, 256, 0, stream>>>(h[0], h[1], h[2], g[0], g[1], g[2],
                                                   marks, emarks, W1h, b1, W2, b2, (float*)d_out);
}

// Round 7
// 793.013 us; speedup vs baseline: 4.9420x; 1.3278x over previous
//
#include <hip/hip_runtime.h>
#include <hip/hip_fp16.h>
#include <math.h>

#define NN 50000
#define NH 50000
#define NI 800000
#define NL 20000

using half8 = __attribute__((ext_vector_type(8))) _Float16;
using f32x4 = __attribute__((ext_vector_type(4))) float;

// ================= helpers =================
static __device__ __forceinline__ void acc_h4(float4& a, float2 raw) {
    float2 lo = __half22float2(*(__half2*)&raw.x);
    float2 hi = __half22float2(*(__half2*)&raw.y);
    a.x += lo.x; a.y += lo.y; a.z += hi.x; a.w += hi.y;
}
static __device__ __forceinline__ float2 pack_h4(float4 v) {
    float2 st;
    *(__half2*)&st.x = __float22half2_rn(make_float2(v.x, v.y));
    *(__half2*)&st.y = __float22half2_rn(make_float2(v.z, v.w));
    return st;
}

// ================= fp32 -> fp16 (n4 quads) =================
__global__ void k_f2h(const float* __restrict__ in, __half* __restrict__ out, int n4) {
    int i = blockIdx.x * blockDim.x + threadIdx.x;
    if (i >= n4) return;
    float4 v = ((const float4*)in)[i];
    ((float2*)out)[i] = pack_h4(v);
}

// ================= W[K][N] fp32 -> Wt[N][K] fp16 =================
__global__ void k_wt(const float* __restrict__ W, __half* __restrict__ Wt, int K, int N) {
    int t = blockIdx.x * blockDim.x + threadIdx.x;
    if (t >= K * N) return;
    int n = t / K, k = t % K;
    Wt[(size_t)n * K + k] = __float2half(W[(size_t)k * N + n]);
}

// ================= CSR build =================
__global__ void k_hist(const int* __restrict__ ei, int* __restrict__ cnt_n,
                       int* __restrict__ cnt_h) {
    int t = blockIdx.x * blockDim.x + threadIdx.x;
    if (t < NI) atomicAdd(&cnt_n[ei[t]], 1);
    else if (t < 2 * NI) atomicAdd(&cnt_h[ei[t]], 1);
}

__global__ void k_scan(const int* __restrict__ cnt, int* __restrict__ off, int n) {
    __shared__ int part[1024];
    int t = threadIdx.x;
    int chunk = (n + 1023) >> 10;
    int lo = t * chunk, hi = min(lo + chunk, n);
    int s = 0;
    for (int i = lo; i < hi; i++) s += cnt[i];
    part[t] = s;
    __syncthreads();
    for (int d = 1; d < 1024; d <<= 1) {
        int v = (t >= d) ? part[t - d] : 0;
        __syncthreads();
        part[t] += v;
        __syncthreads();
    }
    int run = (t == 0) ? 0 : part[t - 1];
    for (int i = lo; i < hi; i++) { off[i] = run; run += cnt[i]; }
    if (hi == n) off[n] = run;
}

__global__ void k_fill(const int* __restrict__ ei, const int* __restrict__ off_n,
                       const int* __restrict__ off_h, int* __restrict__ cur_n,
                       int* __restrict__ cur_h, int* __restrict__ adj_n,
                       int* __restrict__ adj_h) {
    int t = blockIdx.x * blockDim.x + threadIdx.x;
    if (t < NI) {
        int s = ei[t], d = ei[t + NI];
        int p = atomicAdd(&cur_h[d], 1);
        adj_h[off_h[d] + p] = s;
    } else if (t < 2 * NI) {
        int e = t - NI;
        int s = ei[e], d = ei[e + NI];
        int p = atomicAdd(&cur_n[s], 1);
        adj_n[off_n[s] + p] = d;
    }
}

__global__ void k_invdeg(const int* __restrict__ off, float* __restrict__ inv, int n) {
    int i = blockIdx.x * blockDim.x + threadIdx.x;
    if (i < n) {
        int d = off[i + 1] - off[i];
        inv[i] = d > 0 ? 1.0f / (float)d : 0.0f;
    }
}

// ================= MFMA GEMM: Y[M][BN](h) = X[M][K](h) @ Wt[BN][K](h) =============
// 4 waves; rows shared, cols split 4 ways. 16x16x32 f16 MFMA, fp32 acc.
// LDS rows padded to 56 halves (112B) -> frag reads <=2-way bank alias (free).
template <int BM, int BN, int FM, int FN>
__global__ void k_gemm_mfma(const __half* __restrict__ X, const __half* __restrict__ Wt,
                            __half* __restrict__ Y, int M, int K) {
    constexpr int LDK = 56;
    constexpr int WN = BN / 4;
    __shared__ __align__(16) __half Xs[BM * LDK];
    __shared__ __align__(16) __half Ws[BN * LDK];
    int t = threadIdx.x;
    int wave = t >> 6, lane = t & 63;
    int g = lane >> 4, lr = lane & 15;
    int bm0 = blockIdx.x * BM;
    f32x4 acc[FM][FN] = {};

    for (int k0 = 0; k0 < K; k0 += 32) {
        for (int u = t; u < BM * 4; u += 256) {
            int r = u >> 2, q = u & 3;
            int rg = bm0 + r; if (rg >= M) rg = M - 1;
            *(float4*)&Xs[r * LDK + q * 8] = *(const float4*)&X[(size_t)rg * K + k0 + q * 8];
        }
        for (int u = t; u < BN * 4; u += 256) {
            int r = u >> 2, q = u & 3;
            *(float4*)&Ws[r * LDK + q * 8] = *(const float4*)&Wt[(size_t)r * K + k0 + q * 8];
        }
        __syncthreads();
        half8 a[FM], b[FN];
#pragma unroll
        for (int fm = 0; fm < FM; fm++)
            a[fm] = *(const half8*)&Xs[(fm * 16 + lr) * LDK + g * 8];
#pragma unroll
        for (int fn = 0; fn < FN; fn++)
            b[fn] = *(const half8*)&Ws[(wave * WN + fn * 16 + lr) * LDK + g * 8];
#pragma unroll
        for (int fm = 0; fm < FM; fm++)
#pragma unroll
            for (int fn = 0; fn < FN; fn++)
                acc[fm][fn] = __builtin_amdgcn_mfma_f32_16x16x32_f16(a[fm], b[fn], acc[fm][fn], 0, 0, 0);
        __syncthreads();
    }
    // C/D: col = lane&15, row = (lane>>4)*4 + reg   [HW-verified]
#pragma unroll
    for (int fm = 0; fm < FM; fm++) {
#pragma unroll
        for (int fn = 0; fn < FN; fn++) {
            int cg = wave * WN + fn * 16 + lr;
#pragma unroll
            for (int reg = 0; reg < 4; reg++) {
                int rg = bm0 + fm * 16 + g * 4 + reg;
                if (rg < M) Y[(size_t)rg * BN + cg] = __float2half(acc[fm][fn][reg]);
            }
        }
    }
}

// ================= pull aggregation over fp16 tables (8-way unrolled) ========
template <int F, bool RELU>
__global__ void k_pull_h(const __half* __restrict__ in, const int* __restrict__ off,
                         const int* __restrict__ adj, const float* __restrict__ scale,
                         const float* __restrict__ bias, __half* __restrict__ out,
                         int nrows) {
    constexpr int TPR = F / 4;
    constexpr int RPB = 256 / TPR;
    int r = blockIdx.x * RPB + threadIdx.x / TPR;
    int lane = threadIdx.x % TPR;
    if (r >= nrows) return;
    int lo = off[r], hi = off[r + 1];
    const float2* in2 = (const float2*)in;
    float4 a0 = {0.f, 0.f, 0.f, 0.f}, a1 = {0.f, 0.f, 0.f, 0.f};
    float4 a2 = {0.f, 0.f, 0.f, 0.f}, a3 = {0.f, 0.f, 0.f, 0.f};
    int j = lo;
    for (; j + 7 < hi; j += 8) {
        int c0 = adj[j], c1 = adj[j + 1], c2 = adj[j + 2], c3 = adj[j + 3];
        int c4 = adj[j + 4], c5 = adj[j + 5], c6 = adj[j + 6], c7 = adj[j + 7];
        float2 v0 = in2[(size_t)c0 * TPR + lane];
        float2 v1 = in2[(size_t)c1 * TPR + lane];
        float2 v2 = in2[(size_t)c2 * TPR + lane];
        float2 v3 = in2[(size_t)c3 * TPR + lane];
        float2 v4 = in2[(size_t)c4 * TPR + lane];
        float2 v5 = in2[(size_t)c5 * TPR + lane];
        float2 v6 = in2[(size_t)c6 * TPR + lane];
        float2 v7 = in2[(size_t)c7 * TPR + lane];
        acc_h4(a0, v0); acc_h4(a1, v1); acc_h4(a2, v2); acc_h4(a3, v3);
        acc_h4(a0, v4); acc_h4(a1, v5); acc_h4(a2, v6); acc_h4(a3, v7);
    }
    for (; j + 1 < hi; j += 2) {
        int c0 = adj[j], c1 = adj[j + 1];
        float2 v0 = in2[(size_t)c0 * TPR + lane];
        float2 v1 = in2[(size_t)c1 * TPR + lane];
        acc_h4(a0, v0); acc_h4(a1, v1);
    }
    if (j < hi) {
        float2 v0 = in2[(size_t)adj[j] * TPR + lane];
        acc_h4(a0, v0);
    }
    a0.x += a1.x + a2.x + a3.x; a0.y += a1.y + a2.y + a3.y;
    a0.z += a1.z + a2.z + a3.z; a0.w += a1.w + a2.w + a3.w;
    float sc = scale[r];
    if (RELU) {
        float4 b = ((const float4*)bias)[lane];
        a0.x = fmaxf(fmaf(a0.x, sc, b.x), 0.f);
        a0.y = fmaxf(fmaf(a0.y, sc, b.y), 0.f);
        a0.z = fmaxf(fmaf(a0.z, sc, b.z), 0.f);
        a0.w = fmaxf(fmaf(a0.w, sc, b.w), 0.f);
    } else {
        a0.x *= sc; a0.y *= sc; a0.z *= sc; a0.w *= sc;
    }
    ((float2*)out)[(size_t)r * TPR + lane] = pack_h4(a0);
}

// ================= fused final MLP via MFMA ==================================
// BM=32 links, BN=256 hidden, K=768. 4 waves split cols (64 each); FM=2, FN=4.
// Feature gather fused into Xs staging; W2 head + log_softmax in epilogue.
__global__ void __launch_bounds__(256)
k_mlp_mfma(const __half* __restrict__ hx1, const __half* __restrict__ hx2,
           const __half* __restrict__ hx3, const __half* __restrict__ gx1,
           const __half* __restrict__ gx2, const __half* __restrict__ gx3,
           const int* __restrict__ marks, const int* __restrict__ emarks,
           const __half* __restrict__ W1t, const float* __restrict__ b1,
           const float* __restrict__ W2, const float* __restrict__ b2,
           float* __restrict__ out) {
    constexpr int LDK = 56;
    __shared__ __align__(16) __half Xs[32 * LDK];
    __shared__ __align__(16) __half Ws[256 * LDK];
    __shared__ float part[4][32][2];
    int t = threadIdx.x;
    int wave = t >> 6, lane = t & 63;
    int g = lane >> 4, lr = lane & 15;
    int bm0 = blockIdx.x * 32;
    int r_s = t >> 2, q_s = t & 3;
    int m_s = 0, e_s = 0;
    if (t < 128) {
        int l = bm0 + r_s; if (l >= NL) l = NL - 1;
        m_s = marks[l]; e_s = emarks[l];
    }
    f32x4 acc[2][4] = {};

    for (int k0 = 0; k0 < 768; k0 += 32) {
        if (t < 128) {
            if (k0 < 384) {
                int fb = (k0 < 192 ? k0 : k0 - 192) + q_s * 8;
                const __half* gs = fb < 64 ? gx1 : (fb < 128 ? gx2 : gx3);
                int off = fb & 63;
                half8 va = *(const half8*)&gs[(size_t)e_s * 64 + off];
                half8 vb = *(const half8*)&gs[(size_t)(e_s + 1) * 64 + off];
                half8 rv;
                if (k0 < 192) {
#pragma unroll
                    for (int j = 0; j < 8; j++)
                        rv[j] = (_Float16)fminf((float)va[j], (float)vb[j]);
                } else {
#pragma unroll
                    for (int j = 0; j < 8; j++)
                        rv[j] = (_Float16)fmaxf((float)va[j], (float)vb[j]);
                }
                *(half8*)&Xs[r_s * LDK + q_s * 8] = rv;
            } else {
                int fb = (k0 - 384) + q_s * 8;
                const __half* hs = fb < 128 ? hx1 : (fb < 256 ? hx2 : hx3);
                int off = fb & 127;
                *(float4*)&Xs[r_s * LDK + q_s * 8] = *(const float4*)&hs[(size_t)m_s * 128 + off];
            }
        }
        for (int u = t; u < 1024; u += 256) {
            int r = u >> 2, q = u & 3;
            *(float4*)&Ws[r * LDK + q * 8] = *(const float4*)&W1t[(size_t)r * 768 + k0 + q * 8];
        }
        __syncthreads();
        half8 a[2], b[4];
#pragma unroll
        for (int fm = 0; fm < 2; fm++)
            a[fm] = *(const half8*)&Xs[(fm * 16 + lr) * LDK + g * 8];
#pragma unroll
        for (int fn = 0; fn < 4; fn++)
            b[fn] = *(const half8*)&Ws[(wave * 64 + fn * 16 + lr) * LDK + g * 8];
#pragma unroll
        for (int fm = 0; fm < 2; fm++)
#pragma unroll
            for (int fn = 0; fn < 4; fn++)
                acc[fm][fn] = __builtin_amdgcn_mfma_f32_16x16x32_f16(a[fm], b[fn], acc[fm][fn], 0, 0, 0);
        __syncthreads();
    }
    // epilogue: bias+relu, W2 head over this lane's 4 cols, reduce 16 lanes, cross-wave
    float b1c[4], w20[4], w21[4];
#pragma unroll
    for (int fn = 0; fn < 4; fn++) {
        int col = wave * 64 + fn * 16 + lr;
        b1c[fn] = b1[col];
        w20[fn] = W2[(size_t)col * 2 + 0];
        w21[fn] = W2[(size_t)col * 2 + 1];
    }
    float p0[2][4], p1[2][4];
#pragma unroll
    for (int fm = 0; fm < 2; fm++) {
#pragma unroll
        for (int reg = 0; reg < 4; reg++) {
            float s0 = 0.f, s1 = 0.f;
#pragma unroll
            for (int fn = 0; fn < 4; fn++) {
                float hh = fmaxf(acc[fm][fn][reg] + b1c[fn], 0.f);
                s0 = fmaf(hh, w20[fn], s0);
                s1 = fmaf(hh, w21[fn], s1);
            }
            p0[fm][reg] = s0; p1[fm][reg] = s1;
        }
    }
#pragma unroll
    for (int mask = 1; mask < 16; mask <<= 1) {
#pragma unroll
        for (int fm = 0; fm < 2; fm++)
#pragma unroll
            for (int reg = 0; reg < 4; reg++) {
                p0[fm][reg] += __shfl_xor(p0[fm][reg], mask);
                p1[fm][reg] += __shfl_xor(p1[fm][reg], mask);
            }
    }
    if (lr == 0) {
#pragma unroll
        for (int fm = 0; fm < 2; fm++)
#pragma unroll
            for (int reg = 0; reg < 4; reg++) {
                int row = fm * 16 + g * 4 + reg;
                part[wave][row][0] = p0[fm][reg];
                part[wave][row][1] = p1[fm][reg];
            }
    }
    __syncthreads();
    if (t < 32) {
        int l = bm0 + t;
        if (l < NL) {
            float l0 = part[0][t][0] + part[1][t][0] + part[2][t][0] + part[3][t][0] + b2[0];
            float l1 = part[0][t][1] + part[1][t][1] + part[2][t][1] + part[3][t][1] + b2[1];
            float mx = fmaxf(l0, l1);
            float lse = mx + logf(expf(l0 - mx) + expf(l1 - mx));
            out[(size_t)l * 2 + 0] = l0 - lse;
            out[(size_t)l * 2 + 1] = l1 - lse;
        }
    }
}

extern "C" void kernel_launch(void* const* d_in, const int* in_sizes, int n_in,
                              void* d_out, int out_size, void* d_ws, size_t ws_size,
                              hipStream_t stream) {
    const float* x      = (const float*)d_in[0];
    const float* ex     = (const float*)d_in[1];
    const int*   ei     = (const int*)d_in[2];
    const int*   marks  = (const int*)d_in[3];
    const int*   emarks = (const int*)d_in[4];
    const float* Wn[3] = {(const float*)d_in[5],  (const float*)d_in[9],  (const float*)d_in[13]};
    const float* bn[3] = {(const float*)d_in[6],  (const float*)d_in[10], (const float*)d_in[14]};
    const float* We[3] = {(const float*)d_in[7],  (const float*)d_in[11], (const float*)d_in[15]};
    const float* be[3] = {(const float*)d_in[8],  (const float*)d_in[12], (const float*)d_in[16]};
    const float* W1 = (const float*)d_in[17];
    const float* b1 = (const float*)d_in[18];
    const float* W2 = (const float*)d_in[19];
    const float* b2 = (const float*)d_in[20];

    // ---- workspace layout ----
    int*    off_n = (int*)d_ws;                // 50004
    int*    off_h = off_n + 50004;             // 50004
    int*    adj_n = off_h + 50004;             // 800000
    int*    adj_h = adj_n + 800000;            // 800000
    int*    cnt   = adj_h + 800000;            // 100000 (+8 pad)
    float*  invn  = (float*)(cnt + 100008);    // 50000
    float*  invh  = invn + 50000;              // 50000
    __half* xh    = (__half*)(invh + 50000);   // 12.8M
    __half* exh   = xh + 12800000;             // 6.4M
    __half* xwb   = exh + 6400000;             // 6.4M
    __half* heb   = xwb + 6400000;             // 6.4M
    __half* h[3]  = {heb + 6400000, heb + 12800000, heb + 19200000};   // 6.4M each
    __half* g[3]  = {h[2] + 6400000, h[2] + 9600000, h[2] + 12800000}; // 3.2M each
    __half* Wnt[3] = {g[2] + 3200000, g[2] + 3232768, g[2] + 3249152}; // 32768,16384,16384
    __half* Wet[3] = {g[2] + 3265536, g[2] + 3273728, g[2] + 3277824}; // 8192,4096,4096
    __half* W1t    = g[2] + 3281920;                                   // 196608

    int* cnt_n = cnt;
    int* cnt_h = cnt + 50000;

    // ---- fp16 conversions + weight transposes ----
    k_f2h<<<(3200000 + 255) / 256, 256, 0, stream>>>(x, xh, 3200000);
    k_f2h<<<(1600000 + 255) / 256, 256, 0, stream>>>(ex, exh, 1600000);
    k_wt<<<(256 * 128 + 255) / 256, 256, 0, stream>>>(Wn[0], Wnt[0], 256, 128);
    k_wt<<<(128 * 128 + 255) / 256, 256, 0, stream>>>(Wn[1], Wnt[1], 128, 128);
    k_wt<<<(128 * 128 + 255) / 256, 256, 0, stream>>>(Wn[2], Wnt[2], 128, 128);
    k_wt<<<(128 * 64 + 255) / 256, 256, 0, stream>>>(We[0], Wet[0], 128, 64);
    k_wt<<<(64 * 64 + 255) / 256, 256, 0, stream>>>(We[1], Wet[1], 64, 64);
    k_wt<<<(64 * 64 + 255) / 256, 256, 0, stream>>>(We[2], Wet[2], 64, 64);
    k_wt<<<(768 * 256 + 255) / 256, 256, 0, stream>>>(W1, W1t, 768, 256);

    // ---- CSR build ----
    hipMemsetAsync(cnt, 0, 100000 * sizeof(int), stream);
    k_hist<<<(2 * NI + 255) / 256, 256, 0, stream>>>(ei, cnt_n, cnt_h);
    k_scan<<<1, 1024, 0, stream>>>(cnt_n, off_n, NN);
    k_scan<<<1, 1024, 0, stream>>>(cnt_h, off_h, NH);
    hipMemsetAsync(cnt, 0, 100000 * sizeof(int), stream);
    k_fill<<<(2 * NI + 255) / 256, 256, 0, stream>>>(ei, off_n, off_h, cnt_n, cnt_h, adj_n, adj_h);
    k_invdeg<<<(NN + 255) / 256, 256, 0, stream>>>(off_n, invn, NN);
    k_invdeg<<<(NH + 255) / 256, 256, 0, stream>>>(off_h, invh, NH);

    // ---- node convs: GEMM (MFMA) + 2 pulls ----
    const __half* cur = xh;
    int k = 256;
    for (int i = 0; i < 3; i++) {
        k_gemm_mfma<64, 128, 4, 2><<<(NN + 63) / 64, 256, 0, stream>>>(cur, Wnt[i], xwb, NN, k);
        k_pull_h<128, false><<<(NH + 7) / 8, 256, 0, stream>>>(xwb, off_h, adj_h, invh, nullptr, heb, NH);
        k_pull_h<128, true><<<(NN + 7) / 8, 256, 0, stream>>>(heb, off_n, adj_n, invn, bn[i], h[i], NN);
        cur = h[i];
        k = 128;
    }

    // ---- edge convs (flipped) ----
    cur = exh;
    k = 128;
    for (int i = 0; i < 3; i++) {
        k_gemm_mfma<64, 64, 4, 1><<<(NH + 63) / 64, 256, 0, stream>>>(cur, Wet[i], xwb, NH, k);
        k_pull_h<64, false><<<(NN + 15) / 16, 256, 0, stream>>>(xwb, off_n, adj_n, invn, nullptr, heb, NN);
        k_pull_h<64, true><<<(NH + 15) / 16, 256, 0, stream>>>(heb, off_h, adj_h, invh, be[i], g[i], NH);
        cur = g[i];
        k = 64;
    }

    // ---- fused final MLP (MFMA) + head + log_softmax ----
    k_mlp_mfma<<<(NL + 31) / 32, 256, 0, stream>>>(h[0], h[1], h[2], g[0], g[1], g[2],
                                                   marks, emarks, W1t, b1, W2, b2, (float*)d_out);
}

// Round 8
// 734.928 us; speedup vs baseline: 5.3326x; 1.0790x over previous
//
#include <hip/hip_runtime.h>
#include <hip/hip_fp16.h>
#include <math.h>

#define NN 50000
#define NH 50000
#define NI 800000
#define NL 20000

using half8 = __attribute__((ext_vector_type(8))) _Float16;
using f32x4 = __attribute__((ext_vector_type(4))) float;

// ================= helpers =================
static __device__ __forceinline__ float2 pack_h4(float4 v) {
    float2 st;
    *(__half2*)&st.x = __float22half2_rn(make_float2(v.x, v.y));
    *(__half2*)&st.y = __float22half2_rn(make_float2(v.z, v.w));
    return st;
}
static __device__ __forceinline__ void acc_h8(float4& a, float4& b, float4 raw) {
    const __half2* hp = (const __half2*)&raw;
    float2 f0 = __half22float2(hp[0]);
    float2 f1 = __half22float2(hp[1]);
    float2 f2 = __half22float2(hp[2]);
    float2 f3 = __half22float2(hp[3]);
    a.x += f0.x; a.y += f0.y; a.z += f1.x; a.w += f1.y;
    b.x += f2.x; b.y += f2.y; b.z += f3.x; b.w += f3.y;
}
static __device__ __forceinline__ float4 pack_h8(float4 a, float4 b) {
    float4 st;
    ((__half2*)&st)[0] = __float22half2_rn(make_float2(a.x, a.y));
    ((__half2*)&st)[1] = __float22half2_rn(make_float2(a.z, a.w));
    ((__half2*)&st)[2] = __float22half2_rn(make_float2(b.x, b.y));
    ((__half2*)&st)[3] = __float22half2_rn(make_float2(b.z, b.w));
    return st;
}

// ================= fused prep: f2h(x), f2h(ex), 7 weight transposes, histogram ==
#define PB_X   12500          // 3.2M x-quads
#define PB_EX  18750          // +1.6M ex-quads
#define PB_WT  19838          // +278528 wt elements
#define PB_H   22963          // +800000 incidences
__global__ void k_prep(const float* __restrict__ x, __half* __restrict__ xh,
                       const float* __restrict__ ex, __half* __restrict__ exh,
                       const float* __restrict__ Wn0, const float* __restrict__ Wn1,
                       const float* __restrict__ Wn2, const float* __restrict__ We0,
                       const float* __restrict__ We1, const float* __restrict__ We2,
                       const float* __restrict__ W1,
                       __half* __restrict__ Wnt0, __half* __restrict__ Wnt1,
                       __half* __restrict__ Wnt2, __half* __restrict__ Wet0,
                       __half* __restrict__ Wet1, __half* __restrict__ Wet2,
                       __half* __restrict__ W1t,
                       const int* __restrict__ ei, int* __restrict__ cnt_n,
                       int* __restrict__ cnt_h) {
    int b = blockIdx.x, t = threadIdx.x;
    if (b < PB_X) {
        int i = b * 256 + t;
        float4 v = ((const float4*)x)[i];
        ((float2*)xh)[i] = pack_h4(v);
    } else if (b < PB_EX) {
        int i = (b - PB_X) * 256 + t;
        float4 v = ((const float4*)ex)[i];
        ((float2*)exh)[i] = pack_h4(v);
    } else if (b < PB_WT) {
        int u = (b - PB_EX) * 256 + t;
        if (u < 278528) {
            const float* S; __half* D; int K, N;
            if (u < 32768)      { S = Wn0; D = Wnt0; K = 256; N = 128; }
            else if (u < 49152) { S = Wn1; D = Wnt1; K = 128; N = 128; u -= 32768; }
            else if (u < 65536) { S = Wn2; D = Wnt2; K = 128; N = 128; u -= 49152; }
            else if (u < 73728) { S = We0; D = Wet0; K = 128; N = 64;  u -= 65536; }
            else if (u < 77824) { S = We1; D = Wet1; K = 64;  N = 64;  u -= 73728; }
            else if (u < 81920) { S = We2; D = Wet2; K = 64;  N = 64;  u -= 77824; }
            else                { S = W1;  D = W1t;  K = 768; N = 256; u -= 81920; }
            int n = u / K, k = u % K;
            D[(size_t)n * K + k] = __float2half(S[(size_t)k * N + n]);
        }
    } else {
        int e = (b - PB_WT) * 256 + t;
        if (e < NI) {
            atomicAdd(&cnt_n[ei[e]], 1);
            atomicAdd(&cnt_h[ei[e + NI]], 1);
        }
    }
}

// ================= fused dual scan + inverse degree (2 blocks) =================
__global__ void k_scan2(const int* __restrict__ cnt_n, const int* __restrict__ cnt_h,
                        int* __restrict__ off_n, int* __restrict__ off_h,
                        float* __restrict__ invn, float* __restrict__ invh) {
    const int* cnt = blockIdx.x ? cnt_h : cnt_n;
    int* off = blockIdx.x ? off_h : off_n;
    float* inv = blockIdx.x ? invh : invn;
    const int n = 50000;
    __shared__ int part[1024];
    int t = threadIdx.x;
    int chunk = (n + 1023) >> 10;
    int lo = t * chunk, hi = min(lo + chunk, n);
    int s = 0;
    for (int i = lo; i < hi; i++) s += cnt[i];
    part[t] = s;
    __syncthreads();
    for (int d = 1; d < 1024; d <<= 1) {
        int v = (t >= d) ? part[t - d] : 0;
        __syncthreads();
        part[t] += v;
        __syncthreads();
    }
    int run = (t == 0) ? 0 : part[t - 1];
    for (int i = lo; i < hi; i++) {
        off[i] = run;
        int c = cnt[i];
        inv[i] = c > 0 ? 1.0f / (float)c : 0.0f;
        run += c;
    }
    if (hi == n) off[n] = run;
}

// ================= fill both CSRs in one pass =================
__global__ void k_fill(const int* __restrict__ ei, const int* __restrict__ off_n,
                       const int* __restrict__ off_h, int* __restrict__ cur_n,
                       int* __restrict__ cur_h, int* __restrict__ adj_n,
                       int* __restrict__ adj_h) {
    int e = blockIdx.x * blockDim.x + threadIdx.x;
    if (e >= NI) return;
    int s = ei[e], d = ei[e + NI];
    int p = atomicAdd(&cur_h[d], 1);
    adj_h[off_h[d] + p] = s;
    int q = atomicAdd(&cur_n[s], 1);
    adj_n[off_n[s] + q] = d;
}

// ================= MFMA GEMM: Y[M][BN](h) = X[M][K](h) @ Wt[BN][K](h) =============
template <int BM, int BN, int FM, int FN>
__global__ void k_gemm_mfma(const __half* __restrict__ X, const __half* __restrict__ Wt,
                            __half* __restrict__ Y, int M, int K) {
    constexpr int LDK = 56;
    constexpr int WN = BN / 4;
    __shared__ __align__(16) __half Xs[BM * LDK];
    __shared__ __align__(16) __half Ws[BN * LDK];
    int t = threadIdx.x;
    int wave = t >> 6, lane = t & 63;
    int g = lane >> 4, lr = lane & 15;
    int bm0 = blockIdx.x * BM;
    f32x4 acc[FM][FN] = {};

    for (int k0 = 0; k0 < K; k0 += 32) {
        for (int u = t; u < BM * 4; u += 256) {
            int r = u >> 2, q = u & 3;
            int rg = bm0 + r; if (rg >= M) rg = M - 1;
            *(float4*)&Xs[r * LDK + q * 8] = *(const float4*)&X[(size_t)rg * K + k0 + q * 8];
        }
        for (int u = t; u < BN * 4; u += 256) {
            int r = u >> 2, q = u & 3;
            *(float4*)&Ws[r * LDK + q * 8] = *(const float4*)&Wt[(size_t)r * K + k0 + q * 8];
        }
        __syncthreads();
        half8 a[FM], b[FN];
#pragma unroll
        for (int fm = 0; fm < FM; fm++)
            a[fm] = *(const half8*)&Xs[(fm * 16 + lr) * LDK + g * 8];
#pragma unroll
        for (int fn = 0; fn < FN; fn++)
            b[fn] = *(const half8*)&Ws[(wave * WN + fn * 16 + lr) * LDK + g * 8];
#pragma unroll
        for (int fm = 0; fm < FM; fm++)
#pragma unroll
            for (int fn = 0; fn < FN; fn++)
                acc[fm][fn] = __builtin_amdgcn_mfma_f32_16x16x32_f16(a[fm], b[fn], acc[fm][fn], 0, 0, 0);
        __syncthreads();
    }
#pragma unroll
    for (int fm = 0; fm < FM; fm++) {
#pragma unroll
        for (int fn = 0; fn < FN; fn++) {
            int cg = wave * WN + fn * 16 + lr;
#pragma unroll
            for (int reg = 0; reg < 4; reg++) {
                int rg = bm0 + fm * 16 + g * 4 + reg;
                if (rg < M) Y[(size_t)rg * BN + cg] = __float2half(acc[fm][fn][reg]);
            }
        }
    }
}

// ================= pull aggregation: 16B gathers, 8-way unrolled ========
template <int F, bool RELU>
__global__ void k_pull_h(const __half* __restrict__ in, const int* __restrict__ off,
                         const int* __restrict__ adj, const float* __restrict__ scale,
                         const float* __restrict__ bias, __half* __restrict__ out,
                         int nrows) {
    constexpr int TPR = F / 8;            // lanes per row, 16B (8 halfs) each
    constexpr int RPB = 256 / TPR;
    int r = blockIdx.x * RPB + threadIdx.x / TPR;
    int lane = threadIdx.x % TPR;
    if (r >= nrows) return;
    int lo = off[r], hi = off[r + 1];
    const float4* in4 = (const float4*)in;
    float4 a0 = {0,0,0,0}, b0 = {0,0,0,0}, a1 = {0,0,0,0}, b1v = {0,0,0,0};
    float4 a2 = {0,0,0,0}, b2v = {0,0,0,0}, a3 = {0,0,0,0}, b3 = {0,0,0,0};
    int j = lo;
    for (; j + 7 < hi; j += 8) {
        int c0 = adj[j], c1 = adj[j + 1], c2 = adj[j + 2], c3 = adj[j + 3];
        int c4 = adj[j + 4], c5 = adj[j + 5], c6 = adj[j + 6], c7 = adj[j + 7];
        float4 v0 = in4[(size_t)c0 * TPR + lane];
        float4 v1 = in4[(size_t)c1 * TPR + lane];
        float4 v2 = in4[(size_t)c2 * TPR + lane];
        float4 v3 = in4[(size_t)c3 * TPR + lane];
        float4 v4 = in4[(size_t)c4 * TPR + lane];
        float4 v5 = in4[(size_t)c5 * TPR + lane];
        float4 v6 = in4[(size_t)c6 * TPR + lane];
        float4 v7 = in4[(size_t)c7 * TPR + lane];
        acc_h8(a0, b0, v0); acc_h8(a1, b1v, v1); acc_h8(a2, b2v, v2); acc_h8(a3, b3, v3);
        acc_h8(a0, b0, v4); acc_h8(a1, b1v, v5); acc_h8(a2, b2v, v6); acc_h8(a3, b3, v7);
    }
    for (; j + 1 < hi; j += 2) {
        int c0 = adj[j], c1 = adj[j + 1];
        float4 v0 = in4[(size_t)c0 * TPR + lane];
        float4 v1 = in4[(size_t)c1 * TPR + lane];
        acc_h8(a0, b0, v0); acc_h8(a1, b1v, v1);
    }
    if (j < hi) {
        float4 v0 = in4[(size_t)adj[j] * TPR + lane];
        acc_h8(a0, b0, v0);
    }
    a0.x += a1.x + a2.x + a3.x; a0.y += a1.y + a2.y + a3.y;
    a0.z += a1.z + a2.z + a3.z; a0.w += a1.w + a2.w + a3.w;
    b0.x += b1v.x + b2v.x + b3.x; b0.y += b1v.y + b2v.y + b3.y;
    b0.z += b1v.z + b2v.z + b3.z; b0.w += b1v.w + b2v.w + b3.w;
    float sc = scale[r];
    if (RELU) {
        float4 ba = ((const float4*)bias)[lane * 2];
        float4 bb = ((const float4*)bias)[lane * 2 + 1];
        a0.x = fmaxf(fmaf(a0.x, sc, ba.x), 0.f);
        a0.y = fmaxf(fmaf(a0.y, sc, ba.y), 0.f);
        a0.z = fmaxf(fmaf(a0.z, sc, ba.z), 0.f);
        a0.w = fmaxf(fmaf(a0.w, sc, ba.w), 0.f);
        b0.x = fmaxf(fmaf(b0.x, sc, bb.x), 0.f);
        b0.y = fmaxf(fmaf(b0.y, sc, bb.y), 0.f);
        b0.z = fmaxf(fmaf(b0.z, sc, bb.z), 0.f);
        b0.w = fmaxf(fmaf(b0.w, sc, bb.w), 0.f);
    } else {
        a0.x *= sc; a0.y *= sc; a0.z *= sc; a0.w *= sc;
        b0.x *= sc; b0.y *= sc; b0.z *= sc; b0.w *= sc;
    }
    ((float4*)out)[(size_t)r * TPR + lane] = pack_h8(a0, b0);
}

// ================= fused final MLP via MFMA ==================================
__global__ void __launch_bounds__(256)
k_mlp_mfma(const __half* __restrict__ hx1, const __half* __restrict__ hx2,
           const __half* __restrict__ hx3, const __half* __restrict__ gx1,
           const __half* __restrict__ gx2, const __half* __restrict__ gx3,
           const int* __restrict__ marks, const int* __restrict__ emarks,
           const __half* __restrict__ W1t, const float* __restrict__ b1,
           const float* __restrict__ W2, const float* __restrict__ b2,
           float* __restrict__ out) {
    constexpr int LDK = 56;
    __shared__ __align__(16) __half Xs[32 * LDK];
    __shared__ __align__(16) __half Ws[256 * LDK];
    __shared__ float part[4][32][2];
    int t = threadIdx.x;
    int wave = t >> 6, lane = t & 63;
    int g = lane >> 4, lr = lane & 15;
    int bm0 = blockIdx.x * 32;
    int r_s = t >> 2, q_s = t & 3;
    int m_s = 0, e_s = 0;
    if (t < 128) {
        int l = bm0 + r_s; if (l >= NL) l = NL - 1;
        m_s = marks[l]; e_s = emarks[l];
    }
    f32x4 acc[2][4] = {};

    for (int k0 = 0; k0 < 768; k0 += 32) {
        if (t < 128) {
            if (k0 < 384) {
                int fb = (k0 < 192 ? k0 : k0 - 192) + q_s * 8;
                const __half* gs = fb < 64 ? gx1 : (fb < 128 ? gx2 : gx3);
                int off = fb & 63;
                half8 va = *(const half8*)&gs[(size_t)e_s * 64 + off];
                half8 vb = *(const half8*)&gs[(size_t)(e_s + 1) * 64 + off];
                half8 rv;
                if (k0 < 192) {
#pragma unroll
                    for (int j = 0; j < 8; j++)
                        rv[j] = (_Float16)fminf((float)va[j], (float)vb[j]);
                } else {
#pragma unroll
                    for (int j = 0; j < 8; j++)
                        rv[j] = (_Float16)fmaxf((float)va[j], (float)vb[j]);
                }
                *(half8*)&Xs[r_s * LDK + q_s * 8] = rv;
            } else {
                int fb = (k0 - 384) + q_s * 8;
                const __half* hs = fb < 128 ? hx1 : (fb < 256 ? hx2 : hx3);
                int off = fb & 127;
                *(float4*)&Xs[r_s * LDK + q_s * 8] = *(const float4*)&hs[(size_t)m_s * 128 + off];
            }
        }
        for (int u = t; u < 1024; u += 256) {
            int r = u >> 2, q = u & 3;
            *(float4*)&Ws[r * LDK + q * 8] = *(const float4*)&W1t[(size_t)r * 768 + k0 + q * 8];
        }
        __syncthreads();
        half8 a[2], b[4];
#pragma unroll
        for (int fm = 0; fm < 2; fm++)
            a[fm] = *(const half8*)&Xs[(fm * 16 + lr) * LDK + g * 8];
#pragma unroll
        for (int fn = 0; fn < 4; fn++)
            b[fn] = *(const half8*)&Ws[(wave * 64 + fn * 16 + lr) * LDK + g * 8];
#pragma unroll
        for (int fm = 0; fm < 2; fm++)
#pragma unroll
            for (int fn = 0; fn < 4; fn++)
                acc[fm][fn] = __builtin_amdgcn_mfma_f32_16x16x32_f16(a[fm], b[fn], acc[fm][fn], 0, 0, 0);
        __syncthreads();
    }
    float b1c[4], w20[4], w21[4];
#pragma unroll
    for (int fn = 0; fn < 4; fn++) {
        int col = wave * 64 + fn * 16 + lr;
        b1c[fn] = b1[col];
        w20[fn] = W2[(size_t)col * 2 + 0];
        w21[fn] = W2[(size_t)col * 2 + 1];
    }
    float p0[2][4], p1[2][4];
#pragma unroll
    for (int fm = 0; fm < 2; fm++) {
#pragma unroll
        for (int reg = 0; reg < 4; reg++) {
            float s0 = 0.f, s1 = 0.f;
#pragma unroll
            for (int fn = 0; fn < 4; fn++) {
                float hh = fmaxf(acc[fm][fn][reg] + b1c[fn], 0.f);
                s0 = fmaf(hh, w20[fn], s0);
                s1 = fmaf(hh, w21[fn], s1);
            }
            p0[fm][reg] = s0; p1[fm][reg] = s1;
        }
    }
#pragma unroll
    for (int mask = 1; mask < 16; mask <<= 1) {
#pragma unroll
        for (int fm = 0; fm < 2; fm++)
#pragma unroll
            for (int reg = 0; reg < 4; reg++) {
                p0[fm][reg] += __shfl_xor(p0[fm][reg], mask);
                p1[fm][reg] += __shfl_xor(p1[fm][reg], mask);
            }
    }
    if (lr == 0) {
#pragma unroll
        for (int fm = 0; fm < 2; fm++)
#pragma unroll
            for (int reg = 0; reg < 4; reg++) {
                int row = fm * 16 + g * 4 + reg;
                part[wave][row][0] = p0[fm][reg];
                part[wave][row][1] = p1[fm][reg];
            }
    }
    __syncthreads();
    if (t < 32) {
        int l = bm0 + t;
        if (l < NL) {
            float l0 = part[0][t][0] + part[1][t][0] + part[2][t][0] + part[3][t][0] + b2[0];
            float l1 = part[0][t][1] + part[1][t][1] + part[2][t][1] + part[3][t][1] + b2[1];
            float mx = fmaxf(l0, l1);
            float lse = mx + logf(expf(l0 - mx) + expf(l1 - mx));
            out[(size_t)l * 2 + 0] = l0 - lse;
            out[(size_t)l * 2 + 1] = l1 - lse;
        }
    }
}

extern "C" void kernel_launch(void* const* d_in, const int* in_sizes, int n_in,
                              void* d_out, int out_size, void* d_ws, size_t ws_size,
                              hipStream_t stream) {
    const float* x      = (const float*)d_in[0];
    const float* ex     = (const float*)d_in[1];
    const int*   ei     = (const int*)d_in[2];
    const int*   marks  = (const int*)d_in[3];
    const int*   emarks = (const int*)d_in[4];
    const float* Wn[3] = {(const float*)d_in[5],  (const float*)d_in[9],  (const float*)d_in[13]};
    const float* bn[3] = {(const float*)d_in[6],  (const float*)d_in[10], (const float*)d_in[14]};
    const float* We[3] = {(const float*)d_in[7],  (const float*)d_in[11], (const float*)d_in[15]};
    const float* be[3] = {(const float*)d_in[8],  (const float*)d_in[12], (const float*)d_in[16]};
    const float* W1 = (const float*)d_in[17];
    const float* b1 = (const float*)d_in[18];
    const float* W2 = (const float*)d_in[19];
    const float* b2 = (const float*)d_in[20];

    // ---- workspace layout ----
    int*    off_n = (int*)d_ws;                // 50004
    int*    off_h = off_n + 50004;             // 50004
    int*    adj_n = off_h + 50004;             // 800000
    int*    adj_h = adj_n + 800000;            // 800000
    int*    cnt   = adj_h + 800000;            // 100000 (cnt_n, cnt_h)
    int*    cur   = cnt + 100000;              // 100000 (cur_n, cur_h)
    float*  invn  = (float*)(cur + 100000);    // 50000
    float*  invh  = invn + 50000;              // 50000
    __half* xh    = (__half*)(invh + 50000);   // 12.8M
    __half* exh   = xh + 12800000;             // 6.4M
    __half* xwb   = exh + 6400000;             // 6.4M
    __half* heb   = xwb + 6400000;             // 6.4M
    __half* h[3]  = {heb + 6400000, heb + 12800000, heb + 19200000};   // 6.4M each
    __half* g[3]  = {h[2] + 6400000, h[2] + 9600000, h[2] + 12800000}; // 3.2M each
    __half* Wnt[3] = {g[2] + 3200000, g[2] + 3232768, g[2] + 3249152};
    __half* Wet[3] = {g[2] + 3265536, g[2] + 3273728, g[2] + 3277824};
    __half* W1t    = g[2] + 3281920;

    int* cnt_n = cnt;
    int* cnt_h = cnt + 50000;
    int* cur_n = cur;
    int* cur_h = cur + 50000;

    // ---- prep: conversions + transposes + histogram (one kernel) ----
    hipMemsetAsync(cnt, 0, 200000 * sizeof(int), stream);   // counts + cursors
    k_prep<<<PB_H, 256, 0, stream>>>(x, xh, ex, exh,
                                     Wn[0], Wn[1], Wn[2], We[0], We[1], We[2], W1,
                                     Wnt[0], Wnt[1], Wnt[2], Wet[0], Wet[1], Wet[2], W1t,
                                     ei, cnt_n, cnt_h);
    k_scan2<<<2, 1024, 0, stream>>>(cnt_n, cnt_h, off_n, off_h, invn, invh);
    k_fill<<<(NI + 255) / 256, 256, 0, stream>>>(ei, off_n, off_h, cur_n, cur_h, adj_n, adj_h);

    // ---- node convs ----
    const __half* cur_x = xh;
    int k = 256;
    for (int i = 0; i < 3; i++) {
        k_gemm_mfma<64, 128, 4, 2><<<(NN + 63) / 64, 256, 0, stream>>>(cur_x, Wnt[i], xwb, NN, k);
        k_pull_h<128, false><<<(NH + 15) / 16, 256, 0, stream>>>(xwb, off_h, adj_h, invh, nullptr, heb, NH);
        k_pull_h<128, true><<<(NN + 15) / 16, 256, 0, stream>>>(heb, off_n, adj_n, invn, bn[i], h[i], NN);
        cur_x = h[i];
        k = 128;
    }

    // ---- edge convs (flipped) ----
    cur_x = exh;
    k = 128;
    for (int i = 0; i < 3; i++) {
        k_gemm_mfma<64, 64, 4, 1><<<(NH + 63) / 64, 256, 0, stream>>>(cur_x, Wet[i], xwb, NH, k);
        k_pull_h<64, false><<<(NN + 31) / 32, 256, 0, stream>>>(xwb, off_n, adj_n, invn, nullptr, heb, NN);
        k_pull_h<64, true><<<(NH + 31) / 32, 256, 0, stream>>>(heb, off_h, adj_h, invh, be[i], g[i], NH);
        cur_x = g[i];
        k = 64;
    }

    // ---- fused final MLP (MFMA) + head + log_softmax ----
    k_mlp_mfma<<<(NL + 31) / 32, 256, 0, stream>>>(h[0], h[1], h[2], g[0], g[1], g[2],
                                                   marks, emarks, W1t, b1, W2, b2, (float*)d_out);
}

// Round 9
// 600.691 us; speedup vs baseline: 6.5243x; 1.2235x over previous
//
#include <hip/hip_runtime.h>
#include <hip/hip_fp16.h>
#include <math.h>

#define NN 50000
#define NH 50000
#define NI 800000
#define NL 20000

using half8 = __attribute__((ext_vector_type(8))) _Float16;
using f32x4 = __attribute__((ext_vector_type(4))) float;

// ================= helpers =================
static __device__ __forceinline__ float2 pack_h4(float4 v) {
    float2 st;
    *(__half2*)&st.x = __float22half2_rn(make_float2(v.x, v.y));
    *(__half2*)&st.y = __float22half2_rn(make_float2(v.z, v.w));
    return st;
}
static __device__ __forceinline__ void acc_h8(float4& a, float4& b, float4 raw) {
    const __half2* hp = (const __half2*)&raw;
    float2 f0 = __half22float2(hp[0]);
    float2 f1 = __half22float2(hp[1]);
    float2 f2 = __half22float2(hp[2]);
    float2 f3 = __half22float2(hp[3]);
    a.x += f0.x; a.y += f0.y; a.z += f1.x; a.w += f1.y;
    b.x += f2.x; b.y += f2.y; b.z += f3.x; b.w += f3.y;
}
static __device__ __forceinline__ float4 pack_h8(float4 a, float4 b) {
    float4 st;
    ((__half2*)&st)[0] = __float22half2_rn(make_float2(a.x, a.y));
    ((__half2*)&st)[1] = __float22half2_rn(make_float2(a.z, a.w));
    ((__half2*)&st)[2] = __float22half2_rn(make_float2(b.x, b.y));
    ((__half2*)&st)[3] = __float22half2_rn(make_float2(b.z, b.w));
    return st;
}

// ================= fused prep: f2h(x), f2h(ex), 7 weight transposes, histogram ==
#define PB_X   12500
#define PB_EX  18750
#define PB_WT  19838
#define PB_H   22963
__global__ void k_prep(const float* __restrict__ x, __half* __restrict__ xh,
                       const float* __restrict__ ex, __half* __restrict__ exh,
                       const float* __restrict__ Wn0, const float* __restrict__ Wn1,
                       const float* __restrict__ Wn2, const float* __restrict__ We0,
                       const float* __restrict__ We1, const float* __restrict__ We2,
                       const float* __restrict__ W1,
                       __half* __restrict__ Wnt0, __half* __restrict__ Wnt1,
                       __half* __restrict__ Wnt2, __half* __restrict__ Wet0,
                       __half* __restrict__ Wet1, __half* __restrict__ Wet2,
                       __half* __restrict__ W1t,
                       const int* __restrict__ ei, int* __restrict__ cnt_n,
                       int* __restrict__ cnt_h) {
    int b = blockIdx.x, t = threadIdx.x;
    if (b < PB_X) {
        int i = b * 256 + t;
        float4 v = ((const float4*)x)[i];
        ((float2*)xh)[i] = pack_h4(v);
    } else if (b < PB_EX) {
        int i = (b - PB_X) * 256 + t;
        float4 v = ((const float4*)ex)[i];
        ((float2*)exh)[i] = pack_h4(v);
    } else if (b < PB_WT) {
        int u = (b - PB_EX) * 256 + t;
        if (u < 278528) {
            const float* S; __half* D; int K, N;
            if (u < 32768)      { S = Wn0; D = Wnt0; K = 256; N = 128; }
            else if (u < 49152) { S = Wn1; D = Wnt1; K = 128; N = 128; u -= 32768; }
            else if (u < 65536) { S = Wn2; D = Wnt2; K = 128; N = 128; u -= 49152; }
            else if (u < 73728) { S = We0; D = Wet0; K = 128; N = 64;  u -= 65536; }
            else if (u < 77824) { S = We1; D = Wet1; K = 64;  N = 64;  u -= 73728; }
            else if (u < 81920) { S = We2; D = Wet2; K = 64;  N = 64;  u -= 77824; }
            else                { S = W1;  D = W1t;  K = 768; N = 256; u -= 81920; }
            int n = u / K, k = u % K;
            D[(size_t)n * K + k] = __float2half(S[(size_t)k * N + n]);
        }
    } else {
        int e = (b - PB_WT) * 256 + t;
        if (e < NI) {
            atomicAdd(&cnt_n[ei[e]], 1);
            atomicAdd(&cnt_h[ei[e + NI]], 1);
        }
    }
}

// ================= 3-phase multi-block scan (both count arrays at once) ========
// parts layout: parts[0..195] = n-side block sums, parts[256..451] = h-side
__global__ void k_scanp1(const int* __restrict__ cnt_n, const int* __restrict__ cnt_h,
                         int* __restrict__ parts) {
    __shared__ int s[256];
    int arr = blockIdx.x / 196, blk = blockIdx.x % 196, t = threadIdx.x;
    const int* cnt = arr ? cnt_h : cnt_n;
    int i = blk * 256 + t;
    int v = (i < 50000) ? cnt[i] : 0;
    s[t] = v;
    __syncthreads();
#pragma unroll
    for (int d = 128; d > 0; d >>= 1) {
        if (t < d) s[t] += s[t + d];
        __syncthreads();
    }
    if (t == 0) parts[arr * 256 + blk] = s[0];
}

__global__ void k_scanp2(int* __restrict__ parts, int* __restrict__ off_n,
                         int* __restrict__ off_h) {
    __shared__ int s[256];
    int b = blockIdx.x, t = threadIdx.x;
    int* P = parts + b * 256;
    int v = (t < 196) ? P[t] : 0;
    s[t] = v;
    __syncthreads();
#pragma unroll
    for (int d = 1; d < 256; d <<= 1) {
        int u = (t >= d) ? s[t - d] : 0;
        __syncthreads();
        s[t] += u;
        __syncthreads();
    }
    if (t < 196) P[t] = s[t] - v;          // exclusive
    if (t == 0) {
        int* off = b ? off_h : off_n;
        off[50000] = s[255];
    }
}

__global__ void k_scanp3(const int* __restrict__ cnt_n, const int* __restrict__ cnt_h,
                         const int* __restrict__ parts, int* __restrict__ off_n,
                         int* __restrict__ off_h, float* __restrict__ invn,
                         float* __restrict__ invh) {
    __shared__ int s[256];
    int arr = blockIdx.x / 196, blk = blockIdx.x % 196, t = threadIdx.x;
    const int* cnt = arr ? cnt_h : cnt_n;
    int* off = arr ? off_h : off_n;
    float* inv = arr ? invh : invn;
    int i = blk * 256 + t;
    int c = (i < 50000) ? cnt[i] : 0;
    s[t] = c;
    __syncthreads();
#pragma unroll
    for (int d = 1; d < 256; d <<= 1) {
        int u = (t >= d) ? s[t - d] : 0;
        __syncthreads();
        s[t] += u;
        __syncthreads();
    }
    if (i < 50000) {
        off[i] = parts[arr * 256 + blk] + s[t] - c;
        inv[i] = c > 0 ? 1.0f / (float)c : 0.0f;
    }
}

// ================= fill both CSRs in one pass =================
__global__ void k_fill(const int* __restrict__ ei, const int* __restrict__ off_n,
                       const int* __restrict__ off_h, int* __restrict__ cur_n,
                       int* __restrict__ cur_h, int* __restrict__ adj_n,
                       int* __restrict__ adj_h) {
    int e = blockIdx.x * blockDim.x + threadIdx.x;
    if (e >= NI) return;
    int s = ei[e], d = ei[e + NI];
    int p = atomicAdd(&cur_h[d], 1);
    adj_h[off_h[d] + p] = s;
    int q = atomicAdd(&cur_n[s], 1);
    adj_n[off_n[s] + q] = d;
}

// ================= MFMA GEMM body =================
template <int BM, int BN, int FM, int FN>
static __device__ __forceinline__ void gemm_body(const __half* __restrict__ X,
                                                 const __half* __restrict__ Wt,
                                                 __half* __restrict__ Y, int M, int K,
                                                 int blk, __half* smem) {
    constexpr int LDK = 56;
    constexpr int WN = BN / 4;
    __half* Xs = smem;
    __half* Ws = smem + BM * LDK;
    int t = threadIdx.x;
    int wave = t >> 6, lane = t & 63;
    int g = lane >> 4, lr = lane & 15;
    int bm0 = blk * BM;
    f32x4 acc[FM][FN] = {};

    for (int k0 = 0; k0 < K; k0 += 32) {
        for (int u = t; u < BM * 4; u += 256) {
            int r = u >> 2, q = u & 3;
            int rg = bm0 + r; if (rg >= M) rg = M - 1;
            *(float4*)&Xs[r * LDK + q * 8] = *(const float4*)&X[(size_t)rg * K + k0 + q * 8];
        }
        for (int u = t; u < BN * 4; u += 256) {
            int r = u >> 2, q = u & 3;
            *(float4*)&Ws[r * LDK + q * 8] = *(const float4*)&Wt[(size_t)r * K + k0 + q * 8];
        }
        __syncthreads();
        half8 a[FM], b[FN];
#pragma unroll
        for (int fm = 0; fm < FM; fm++)
            a[fm] = *(const half8*)&Xs[(fm * 16 + lr) * LDK + g * 8];
#pragma unroll
        for (int fn = 0; fn < FN; fn++)
            b[fn] = *(const half8*)&Ws[(wave * WN + fn * 16 + lr) * LDK + g * 8];
#pragma unroll
        for (int fm = 0; fm < FM; fm++)
#pragma unroll
            for (int fn = 0; fn < FN; fn++)
                acc[fm][fn] = __builtin_amdgcn_mfma_f32_16x16x32_f16(a[fm], b[fn], acc[fm][fn], 0, 0, 0);
        __syncthreads();
    }
#pragma unroll
    for (int fm = 0; fm < FM; fm++) {
#pragma unroll
        for (int fn = 0; fn < FN; fn++) {
            int cg = wave * WN + fn * 16 + lr;
#pragma unroll
            for (int reg = 0; reg < 4; reg++) {
                int rg = bm0 + fm * 16 + g * 4 + reg;
                if (rg < M) Y[(size_t)rg * BN + cg] = __float2half(acc[fm][fn][reg]);
            }
        }
    }
}

// combined node (64x128) + edge (64x64) GEMM; blocks [0,782) node, [782,1564) edge
__global__ void __launch_bounds__(256)
k_gemm2(const __half* __restrict__ Xn, const __half* __restrict__ Wtn,
        __half* __restrict__ Yn, int Kn,
        const __half* __restrict__ Xe, const __half* __restrict__ Wte,
        __half* __restrict__ Ye, int Ke) {
    __shared__ __align__(16) __half smem[(64 + 128) * 56];
    if (blockIdx.x < 782)
        gemm_body<64, 128, 4, 2>(Xn, Wtn, Yn, NN, Kn, blockIdx.x, smem);
    else
        gemm_body<64, 64, 4, 1>(Xe, Wte, Ye, NH, Ke, blockIdx.x - 782, smem);
}

// ================= pull body: 16B gathers, 8-way unrolled ========
template <int F, bool RELU>
static __device__ __forceinline__ void pull_body(const __half* __restrict__ in,
                                                 const int* __restrict__ off,
                                                 const int* __restrict__ adj,
                                                 const float* __restrict__ scale,
                                                 const float* __restrict__ bias,
                                                 __half* __restrict__ out,
                                                 int nrows, int blk) {
    constexpr int TPR = F / 8;
    constexpr int RPB = 256 / TPR;
    int r = blk * RPB + (int)threadIdx.x / TPR;
    int lane = threadIdx.x % TPR;
    if (r >= nrows) return;
    int lo = off[r], hi = off[r + 1];
    const float4* in4 = (const float4*)in;
    float4 a0 = {0,0,0,0}, b0 = {0,0,0,0}, a1 = {0,0,0,0}, b1v = {0,0,0,0};
    float4 a2 = {0,0,0,0}, b2v = {0,0,0,0}, a3 = {0,0,0,0}, b3 = {0,0,0,0};
    int j = lo;
    for (; j + 7 < hi; j += 8) {
        int c0 = adj[j], c1 = adj[j + 1], c2 = adj[j + 2], c3 = adj[j + 3];
        int c4 = adj[j + 4], c5 = adj[j + 5], c6 = adj[j + 6], c7 = adj[j + 7];
        float4 v0 = in4[(size_t)c0 * TPR + lane];
        float4 v1 = in4[(size_t)c1 * TPR + lane];
        float4 v2 = in4[(size_t)c2 * TPR + lane];
        float4 v3 = in4[(size_t)c3 * TPR + lane];
        float4 v4 = in4[(size_t)c4 * TPR + lane];
        float4 v5 = in4[(size_t)c5 * TPR + lane];
        float4 v6 = in4[(size_t)c6 * TPR + lane];
        float4 v7 = in4[(size_t)c7 * TPR + lane];
        acc_h8(a0, b0, v0); acc_h8(a1, b1v, v1); acc_h8(a2, b2v, v2); acc_h8(a3, b3, v3);
        acc_h8(a0, b0, v4); acc_h8(a1, b1v, v5); acc_h8(a2, b2v, v6); acc_h8(a3, b3, v7);
    }
    for (; j + 1 < hi; j += 2) {
        int c0 = adj[j], c1 = adj[j + 1];
        float4 v0 = in4[(size_t)c0 * TPR + lane];
        float4 v1 = in4[(size_t)c1 * TPR + lane];
        acc_h8(a0, b0, v0); acc_h8(a1, b1v, v1);
    }
    if (j < hi) {
        float4 v0 = in4[(size_t)adj[j] * TPR + lane];
        acc_h8(a0, b0, v0);
    }
    a0.x += a1.x + a2.x + a3.x; a0.y += a1.y + a2.y + a3.y;
    a0.z += a1.z + a2.z + a3.z; a0.w += a1.w + a2.w + a3.w;
    b0.x += b1v.x + b2v.x + b3.x; b0.y += b1v.y + b2v.y + b3.y;
    b0.z += b1v.z + b2v.z + b3.z; b0.w += b1v.w + b2v.w + b3.w;
    float sc = scale[r];
    if (RELU) {
        float4 ba = ((const float4*)bias)[lane * 2];
        float4 bb = ((const float4*)bias)[lane * 2 + 1];
        a0.x = fmaxf(fmaf(a0.x, sc, ba.x), 0.f);
        a0.y = fmaxf(fmaf(a0.y, sc, ba.y), 0.f);
        a0.z = fmaxf(fmaf(a0.z, sc, ba.z), 0.f);
        a0.w = fmaxf(fmaf(a0.w, sc, ba.w), 0.f);
        b0.x = fmaxf(fmaf(b0.x, sc, bb.x), 0.f);
        b0.y = fmaxf(fmaf(b0.y, sc, bb.y), 0.f);
        b0.z = fmaxf(fmaf(b0.z, sc, bb.z), 0.f);
        b0.w = fmaxf(fmaf(b0.w, sc, bb.w), 0.f);
    } else {
        a0.x *= sc; a0.y *= sc; a0.z *= sc; a0.w *= sc;
        b0.x *= sc; b0.y *= sc; b0.z *= sc; b0.w *= sc;
    }
    ((float4*)out)[(size_t)r * TPR + lane] = pack_h8(a0, b0);
}

// combined pull: blocks [0,3125) = F=128 side, [3125,4688) = F=64 side
template <bool RELU>
__global__ void k_pull2(const __half* __restrict__ inA, const int* __restrict__ offA,
                        const int* __restrict__ adjA, const float* __restrict__ scA,
                        const float* __restrict__ biA, __half* __restrict__ outA, int rowsA,
                        const __half* __restrict__ inB, const int* __restrict__ offB,
                        const int* __restrict__ adjB, const float* __restrict__ scB,
                        const float* __restrict__ biB, __half* __restrict__ outB, int rowsB) {
    if (blockIdx.x < 3125)
        pull_body<128, RELU>(inA, offA, adjA, scA, biA, outA, rowsA, blockIdx.x);
    else
        pull_body<64, RELU>(inB, offB, adjB, scB, biB, outB, rowsB, blockIdx.x - 3125);
}

// ================= fused final MLP via MFMA ==================================
__global__ void __launch_bounds__(256)
k_mlp_mfma(const __half* __restrict__ hx1, const __half* __restrict__ hx2,
           const __half* __restrict__ hx3, const __half* __restrict__ gx1,
           const __half* __restrict__ gx2, const __half* __restrict__ gx3,
           const int* __restrict__ marks, const int* __restrict__ emarks,
           const __half* __restrict__ W1t, const float* __restrict__ b1,
           const float* __restrict__ W2, const float* __restrict__ b2,
           float* __restrict__ out) {
    constexpr int LDK = 56;
    __shared__ __align__(16) __half Xs[32 * LDK];
    __shared__ __align__(16) __half Ws[256 * LDK];
    __shared__ float part[4][32][2];
    int t = threadIdx.x;
    int wave = t >> 6, lane = t & 63;
    int g = lane >> 4, lr = lane & 15;
    int bm0 = blockIdx.x * 32;
    int r_s = t >> 2, q_s = t & 3;
    int m_s = 0, e_s = 0;
    if (t < 128) {
        int l = bm0 + r_s; if (l >= NL) l = NL - 1;
        m_s = marks[l]; e_s = emarks[l];
    }
    f32x4 acc[2][4] = {};

    for (int k0 = 0; k0 < 768; k0 += 32) {
        if (t < 128) {
            if (k0 < 384) {
                int fb = (k0 < 192 ? k0 : k0 - 192) + q_s * 8;
                const __half* gs = fb < 64 ? gx1 : (fb < 128 ? gx2 : gx3);
                int off = fb & 63;
                half8 va = *(const half8*)&gs[(size_t)e_s * 64 + off];
                half8 vb = *(const half8*)&gs[(size_t)(e_s + 1) * 64 + off];
                half8 rv;
                if (k0 < 192) {
#pragma unroll
                    for (int j = 0; j < 8; j++)
                        rv[j] = (_Float16)fminf((float)va[j], (float)vb[j]);
                } else {
#pragma unroll
                    for (int j = 0; j < 8; j++)
                        rv[j] = (_Float16)fmaxf((float)va[j], (float)vb[j]);
                }
                *(half8*)&Xs[r_s * LDK + q_s * 8] = rv;
            } else {
                int fb = (k0 - 384) + q_s * 8;
                const __half* hs = fb < 128 ? hx1 : (fb < 256 ? hx2 : hx3);
                int off = fb & 127;
                *(float4*)&Xs[r_s * LDK + q_s * 8] = *(const float4*)&hs[(size_t)m_s * 128 + off];
            }
        }
        for (int u = t; u < 1024; u += 256) {
            int r = u >> 2, q = u & 3;
            *(float4*)&Ws[r * LDK + q * 8] = *(const float4*)&W1t[(size_t)r * 768 + k0 + q * 8];
        }
        __syncthreads();
        half8 a[2], b[4];
#pragma unroll
        for (int fm = 0; fm < 2; fm++)
            a[fm] = *(const half8*)&Xs[(fm * 16 + lr) * LDK + g * 8];
#pragma unroll
        for (int fn = 0; fn < 4; fn++)
            b[fn] = *(const half8*)&Ws[(wave * 64 + fn * 16 + lr) * LDK + g * 8];
#pragma unroll
        for (int fm = 0; fm < 2; fm++)
#pragma unroll
            for (int fn = 0; fn < 4; fn++)
                acc[fm][fn] = __builtin_amdgcn_mfma_f32_16x16x32_f16(a[fm], b[fn], acc[fm][fn], 0, 0, 0);
        __syncthreads();
    }
    float b1c[4], w20[4], w21[4];
#pragma unroll
    for (int fn = 0; fn < 4; fn++) {
        int col = wave * 64 + fn * 16 + lr;
        b1c[fn] = b1[col];
        w20[fn] = W2[(size_t)col * 2 + 0];
        w21[fn] = W2[(size_t)col * 2 + 1];
    }
    float p0[2][4], p1[2][4];
#pragma unroll
    for (int fm = 0; fm < 2; fm++) {
#pragma unroll
        for (int reg = 0; reg < 4; reg++) {
            float s0 = 0.f, s1 = 0.f;
#pragma unroll
            for (int fn = 0; fn < 4; fn++) {
                float hh = fmaxf(acc[fm][fn][reg] + b1c[fn], 0.f);
                s0 = fmaf(hh, w20[fn], s0);
                s1 = fmaf(hh, w21[fn], s1);
            }
            p0[fm][reg] = s0; p1[fm][reg] = s1;
        }
    }
#pragma unroll
    for (int mask = 1; mask < 16; mask <<= 1) {
#pragma unroll
        for (int fm = 0; fm < 2; fm++)
#pragma unroll
            for (int reg = 0; reg < 4; reg++) {
                p0[fm][reg] += __shfl_xor(p0[fm][reg], mask);
                p1[fm][reg] += __shfl_xor(p1[fm][reg], mask);
            }
    }
    if (lr == 0) {
#pragma unroll
        for (int fm = 0; fm < 2; fm++)
#pragma unroll
            for (int reg = 0; reg < 4; reg++) {
                int row = fm * 16 + g * 4 + reg;
                part[wave][row][0] = p0[fm][reg];
                part[wave][row][1] = p1[fm][reg];
            }
    }
    __syncthreads();
    if (t < 32) {
        int l = bm0 + t;
        if (l < NL) {
            float l0 = part[0][t][0] + part[1][t][0] + part[2][t][0] + part[3][t][0] + b2[0];
            float l1 = part[0][t][1] + part[1][t][1] + part[2][t][1] + part[3][t][1] + b2[1];
            float mx = fmaxf(l0, l1);
            float lse = mx + logf(expf(l0 - mx) + expf(l1 - mx));
            out[(size_t)l * 2 + 0] = l0 - lse;
            out[(size_t)l * 2 + 1] = l1 - lse;
        }
    }
}

extern "C" void kernel_launch(void* const* d_in, const int* in_sizes, int n_in,
                              void* d_out, int out_size, void* d_ws, size_t ws_size,
                              hipStream_t stream) {
    const float* x      = (const float*)d_in[0];
    const float* ex     = (const float*)d_in[1];
    const int*   ei     = (const int*)d_in[2];
    const int*   marks  = (const int*)d_in[3];
    const int*   emarks = (const int*)d_in[4];
    const float* Wn[3] = {(const float*)d_in[5],  (const float*)d_in[9],  (const float*)d_in[13]};
    const float* bn[3] = {(const float*)d_in[6],  (const float*)d_in[10], (const float*)d_in[14]};
    const float* We[3] = {(const float*)d_in[7],  (const float*)d_in[11], (const float*)d_in[15]};
    const float* be[3] = {(const float*)d_in[8],  (const float*)d_in[12], (const float*)d_in[16]};
    const float* W1 = (const float*)d_in[17];
    const float* b1 = (const float*)d_in[18];
    const float* W2 = (const float*)d_in[19];
    const float* b2 = (const float*)d_in[20];

    // ---- workspace layout ----
    int*    off_n = (int*)d_ws;                // 50004
    int*    off_h = off_n + 50004;             // 50004
    int*    adj_n = off_h + 50004;             // 800000
    int*    adj_h = adj_n + 800000;            // 800000
    int*    cnt   = adj_h + 800000;            // 100000
    int*    cur   = cnt + 100000;              // 100000
    int*    parts = cur + 100000;              // 512
    float*  invn  = (float*)(parts + 512);     // 50000
    float*  invh  = invn + 50000;              // 50000
    __half* xh    = (__half*)(invh + 50000);   // 12.8M
    __half* exh   = xh + 12800000;             // 6.4M
    __half* xwb   = exh + 6400000;             // 6.4M
    __half* xwb2  = xwb + 6400000;             // 3.2M
    __half* heb   = xwb2 + 3200000;            // 6.4M
    __half* heb2  = heb + 6400000;             // 3.2M
    __half* h[3]  = {heb2 + 3200000, heb2 + 9600000, heb2 + 16000000};  // 6.4M each
    __half* g[3]  = {h[2] + 6400000, h[2] + 9600000, h[2] + 12800000};  // 3.2M each
    __half* Wnt[3] = {g[2] + 3200000, g[2] + 3232768, g[2] + 3249152};
    __half* Wet[3] = {g[2] + 3265536, g[2] + 3273728, g[2] + 3277824};
    __half* W1t    = g[2] + 3281920;

    int* cnt_n = cnt;
    int* cnt_h = cnt + 50000;
    int* cur_n = cur;
    int* cur_h = cur + 50000;

    // ---- prep + CSR build ----
    hipMemsetAsync(cnt, 0, 200000 * sizeof(int), stream);   // counts + cursors
    k_prep<<<PB_H, 256, 0, stream>>>(x, xh, ex, exh,
                                     Wn[0], Wn[1], Wn[2], We[0], We[1], We[2], W1,
                                     Wnt[0], Wnt[1], Wnt[2], Wet[0], Wet[1], Wet[2], W1t,
                                     ei, cnt_n, cnt_h);
    k_scanp1<<<392, 256, 0, stream>>>(cnt_n, cnt_h, parts);
    k_scanp2<<<2, 256, 0, stream>>>(parts, off_n, off_h);
    k_scanp3<<<392, 256, 0, stream>>>(cnt_n, cnt_h, parts, off_n, off_h, invn, invh);
    k_fill<<<(NI + 255) / 256, 256, 0, stream>>>(ei, off_n, off_h, cur_n, cur_h, adj_n, adj_h);

    // ---- fused node+edge conv chains (independent until final MLP) ----
    const __half* cn = xh;  int kn = 256;
    const __half* ce = exh; int ke = 128;
    for (int i = 0; i < 3; i++) {
        k_gemm2<<<1564, 256, 0, stream>>>(cn, Wnt[i], xwb, kn, ce, Wet[i], xwb2, ke);
        k_pull2<false><<<4688, 256, 0, stream>>>(xwb, off_h, adj_h, invh, nullptr, heb, NH,
                                                 xwb2, off_n, adj_n, invn, nullptr, heb2, NN);
        k_pull2<true><<<4688, 256, 0, stream>>>(heb, off_n, adj_n, invn, bn[i], h[i], NN,
                                                heb2, off_h, adj_h, invh, be[i], g[i], NH);
        cn = h[i]; kn = 128;
        ce = g[i]; ke = 64;
    }

    // ---- fused final MLP (MFMA) + head + log_softmax ----
    k_mlp_mfma<<<(NL + 31) / 32, 256, 0, stream>>>(h[0], h[1], h[2], g[0], g[1], g[2],
                                                   marks, emarks, W1t, b1, W2, b2, (float*)d_out);
}

// Round 10
// 582.887 us; speedup vs baseline: 6.7236x; 1.0305x over previous
//
#include <hip/hip_runtime.h>
#include <hip/hip_fp16.h>
#include <math.h>

#define NN 50000
#define NH 50000
#define NI 800000
#define NL 20000

using half8 = __attribute__((ext_vector_type(8))) _Float16;
using f32x4 = __attribute__((ext_vector_type(4))) float;

// ================= helpers =================
static __device__ __forceinline__ float2 pack_h4(float4 v) {
    float2 st;
    *(__half2*)&st.x = __float22half2_rn(make_float2(v.x, v.y));
    *(__half2*)&st.y = __float22half2_rn(make_float2(v.z, v.w));
    return st;
}
static __device__ __forceinline__ void acc_h8(float4& a, float4& b, float4 raw) {
    const __half2* hp = (const __half2*)&raw;
    float2 f0 = __half22float2(hp[0]);
    float2 f1 = __half22float2(hp[1]);
    float2 f2 = __half22float2(hp[2]);
    float2 f3 = __half22float2(hp[3]);
    a.x += f0.x; a.y += f0.y; a.z += f1.x; a.w += f1.y;
    b.x += f2.x; b.y += f2.y; b.z += f3.x; b.w += f3.y;
}
static __device__ __forceinline__ float4 pack_h8(float4 a, float4 b) {
    float4 st;
    ((__half2*)&st)[0] = __float22half2_rn(make_float2(a.x, a.y));
    ((__half2*)&st)[1] = __float22half2_rn(make_float2(a.z, a.w));
    ((__half2*)&st)[2] = __float22half2_rn(make_float2(b.x, b.y));
    ((__half2*)&st)[3] = __float22half2_rn(make_float2(b.z, b.w));
    return st;
}

// ================= fused prep: f2h(x), f2h(ex), 7 weight transposes, histogram ==
#define PB_X   12500
#define PB_EX  18750
#define PB_WT  19838
#define PB_H   22963
__global__ void k_prep(const float* __restrict__ x, __half* __restrict__ xh,
                       const float* __restrict__ ex, __half* __restrict__ exh,
                       const float* __restrict__ Wn0, const float* __restrict__ Wn1,
                       const float* __restrict__ Wn2, const float* __restrict__ We0,
                       const float* __restrict__ We1, const float* __restrict__ We2,
                       const float* __restrict__ W1,
                       __half* __restrict__ Wnt0, __half* __restrict__ Wnt1,
                       __half* __restrict__ Wnt2, __half* __restrict__ Wet0,
                       __half* __restrict__ Wet1, __half* __restrict__ Wet2,
                       __half* __restrict__ W1t,
                       const int* __restrict__ ei, int* __restrict__ cnt_n,
                       int* __restrict__ cnt_h) {
    int b = blockIdx.x, t = threadIdx.x;
    if (b < PB_X) {
        int i = b * 256 + t;
        float4 v = ((const float4*)x)[i];
        ((float2*)xh)[i] = pack_h4(v);
    } else if (b < PB_EX) {
        int i = (b - PB_X) * 256 + t;
        float4 v = ((const float4*)ex)[i];
        ((float2*)exh)[i] = pack_h4(v);
    } else if (b < PB_WT) {
        int u = (b - PB_EX) * 256 + t;
        if (u < 278528) {
            const float* S; __half* D; int K, N;
            if (u < 32768)      { S = Wn0; D = Wnt0; K = 256; N = 128; }
            else if (u < 49152) { S = Wn1; D = Wnt1; K = 128; N = 128; u -= 32768; }
            else if (u < 65536) { S = Wn2; D = Wnt2; K = 128; N = 128; u -= 49152; }
            else if (u < 73728) { S = We0; D = Wet0; K = 128; N = 64;  u -= 65536; }
            else if (u < 77824) { S = We1; D = Wet1; K = 64;  N = 64;  u -= 73728; }
            else if (u < 81920) { S = We2; D = Wet2; K = 64;  N = 64;  u -= 77824; }
            else                { S = W1;  D = W1t;  K = 768; N = 256; u -= 81920; }
            int n = u / K, k = u % K;
            D[(size_t)n * K + k] = __float2half(S[(size_t)k * N + n]);
        }
    } else {
        int e = (b - PB_WT) * 256 + t;
        if (e < NI) {
            atomicAdd(&cnt_n[ei[e]], 1);
            atomicAdd(&cnt_h[ei[e + NI]], 1);
        }
    }
}

// ================= 3-phase multi-block scan (both count arrays at once) ========
__global__ void k_scanp1(const int* __restrict__ cnt_n, const int* __restrict__ cnt_h,
                         int* __restrict__ parts) {
    __shared__ int s[256];
    int arr = blockIdx.x / 196, blk = blockIdx.x % 196, t = threadIdx.x;
    const int* cnt = arr ? cnt_h : cnt_n;
    int i = blk * 256 + t;
    int v = (i < 50000) ? cnt[i] : 0;
    s[t] = v;
    __syncthreads();
#pragma unroll
    for (int d = 128; d > 0; d >>= 1) {
        if (t < d) s[t] += s[t + d];
        __syncthreads();
    }
    if (t == 0) parts[arr * 256 + blk] = s[0];
}

__global__ void k_scanp2(int* __restrict__ parts, int* __restrict__ off_n,
                         int* __restrict__ off_h) {
    __shared__ int s[256];
    int b = blockIdx.x, t = threadIdx.x;
    int* P = parts + b * 256;
    int v = (t < 196) ? P[t] : 0;
    s[t] = v;
    __syncthreads();
#pragma unroll
    for (int d = 1; d < 256; d <<= 1) {
        int u = (t >= d) ? s[t - d] : 0;
        __syncthreads();
        s[t] += u;
        __syncthreads();
    }
    if (t < 196) P[t] = s[t] - v;          // exclusive
    if (t == 0) {
        int* off = b ? off_h : off_n;
        off[50000] = s[255];
    }
}

__global__ void k_scanp3(const int* __restrict__ cnt_n, const int* __restrict__ cnt_h,
                         const int* __restrict__ parts, int* __restrict__ off_n,
                         int* __restrict__ off_h, float* __restrict__ invn,
                         float* __restrict__ invh) {
    __shared__ int s[256];
    int arr = blockIdx.x / 196, blk = blockIdx.x % 196, t = threadIdx.x;
    const int* cnt = arr ? cnt_h : cnt_n;
    int* off = arr ? off_h : off_n;
    float* inv = arr ? invh : invn;
    int i = blk * 256 + t;
    int c = (i < 50000) ? cnt[i] : 0;
    s[t] = c;
    __syncthreads();
#pragma unroll
    for (int d = 1; d < 256; d <<= 1) {
        int u = (t >= d) ? s[t - d] : 0;
        __syncthreads();
        s[t] += u;
        __syncthreads();
    }
    if (i < 50000) {
        off[i] = parts[arr * 256 + blk] + s[t] - c;
        inv[i] = c > 0 ? 1.0f / (float)c : 0.0f;
    }
}

// ================= XCD-bucketed CSR fill =================
// Rows are split into 8 buckets (id/6250); bucket = blockIdx&7 so all blocks
// touching a given adj/cur line land on one XCD: lines accumulate in its L2
// and write back once (kills the 17x write amplification of the naive fill).
#define FILL_SEGS 98
#define FILL_PER  8164          // ceil(NI / FILL_SEGS)
__global__ void k_fill(const int* __restrict__ ei, const int* __restrict__ off_n,
                       const int* __restrict__ off_h, int* __restrict__ cur_n,
                       int* __restrict__ cur_h, int* __restrict__ adj_n,
                       int* __restrict__ adj_h) {
    int bucket = blockIdx.x & 7;
    int seg = blockIdx.x >> 3;
    int lo = seg * FILL_PER;
    int hi = min(lo + FILL_PER, NI);
    for (int e = lo + (int)threadIdx.x; e < hi; e += 256) {
        int s = ei[e], d = ei[e + NI];
        if (d / 6250 == bucket) {
            int p = atomicAdd(&cur_h[d], 1);
            adj_h[off_h[d] + p] = s;
        }
        if (s / 6250 == bucket) {
            int q = atomicAdd(&cur_n[s], 1);
            adj_n[off_n[s] + q] = d;
        }
    }
}

// ================= MFMA GEMM body =================
template <int BM, int BN, int FM, int FN>
static __device__ __forceinline__ void gemm_body(const __half* __restrict__ X,
                                                 const __half* __restrict__ Wt,
                                                 __half* __restrict__ Y, int M, int K,
                                                 int blk, __half* smem) {
    constexpr int LDK = 56;
    constexpr int WN = BN / 4;
    __half* Xs = smem;
    __half* Ws = smem + BM * LDK;
    int t = threadIdx.x;
    int wave = t >> 6, lane = t & 63;
    int g = lane >> 4, lr = lane & 15;
    int bm0 = blk * BM;
    f32x4 acc[FM][FN] = {};

    for (int k0 = 0; k0 < K; k0 += 32) {
        for (int u = t; u < BM * 4; u += 256) {
            int r = u >> 2, q = u & 3;
            int rg = bm0 + r; if (rg >= M) rg = M - 1;
            *(float4*)&Xs[r * LDK + q * 8] = *(const float4*)&X[(size_t)rg * K + k0 + q * 8];
        }
        for (int u = t; u < BN * 4; u += 256) {
            int r = u >> 2, q = u & 3;
            *(float4*)&Ws[r * LDK + q * 8] = *(const float4*)&Wt[(size_t)r * K + k0 + q * 8];
        }
        __syncthreads();
        half8 a[FM], b[FN];
#pragma unroll
        for (int fm = 0; fm < FM; fm++)
            a[fm] = *(const half8*)&Xs[(fm * 16 + lr) * LDK + g * 8];
#pragma unroll
        for (int fn = 0; fn < FN; fn++)
            b[fn] = *(const half8*)&Ws[(wave * WN + fn * 16 + lr) * LDK + g * 8];
#pragma unroll
        for (int fm = 0; fm < FM; fm++)
#pragma unroll
            for (int fn = 0; fn < FN; fn++)
                acc[fm][fn] = __builtin_amdgcn_mfma_f32_16x16x32_f16(a[fm], b[fn], acc[fm][fn], 0, 0, 0);
        __syncthreads();
    }
#pragma unroll
    for (int fm = 0; fm < FM; fm++) {
#pragma unroll
        for (int fn = 0; fn < FN; fn++) {
            int cg = wave * WN + fn * 16 + lr;
#pragma unroll
            for (int reg = 0; reg < 4; reg++) {
                int rg = bm0 + fm * 16 + g * 4 + reg;
                if (rg < M) Y[(size_t)rg * BN + cg] = __float2half(acc[fm][fn][reg]);
            }
        }
    }
}

// combined node (64x128) + edge (64x64) GEMM; blocks [0,782) node, [782,1564) edge
__global__ void __launch_bounds__(256)
k_gemm2(const __half* __restrict__ Xn, const __half* __restrict__ Wtn,
        __half* __restrict__ Yn, int Kn,
        const __half* __restrict__ Xe, const __half* __restrict__ Wte,
        __half* __restrict__ Ye, int Ke) {
    __shared__ __align__(16) __half smem[(64 + 128) * 56];
    if (blockIdx.x < 782)
        gemm_body<64, 128, 4, 2>(Xn, Wtn, Yn, NN, Kn, blockIdx.x, smem);
    else
        gemm_body<64, 64, 4, 1>(Xe, Wte, Ye, NH, Ke, blockIdx.x - 782, smem);
}

// ================= pull body: 16B gathers, 8-way unrolled ========
template <int F, bool RELU>
static __device__ __forceinline__ void pull_body(const __half* __restrict__ in,
                                                 const int* __restrict__ off,
                                                 const int* __restrict__ adj,
                                                 const float* __restrict__ scale,
                                                 const float* __restrict__ bias,
                                                 __half* __restrict__ out,
                                                 int nrows, int blk) {
    constexpr int TPR = F / 8;
    constexpr int RPB = 256 / TPR;
    int r = blk * RPB + (int)threadIdx.x / TPR;
    int lane = threadIdx.x % TPR;
    if (r >= nrows) return;
    int lo = off[r], hi = off[r + 1];
    const float4* in4 = (const float4*)in;
    float4 a0 = {0,0,0,0}, b0 = {0,0,0,0}, a1 = {0,0,0,0}, b1v = {0,0,0,0};
    float4 a2 = {0,0,0,0}, b2v = {0,0,0,0}, a3 = {0,0,0,0}, b3 = {0,0,0,0};
    int j = lo;
    for (; j + 7 < hi; j += 8) {
        int c0 = adj[j], c1 = adj[j + 1], c2 = adj[j + 2], c3 = adj[j + 3];
        int c4 = adj[j + 4], c5 = adj[j + 5], c6 = adj[j + 6], c7 = adj[j + 7];
        float4 v0 = in4[(size_t)c0 * TPR + lane];
        float4 v1 = in4[(size_t)c1 * TPR + lane];
        float4 v2 = in4[(size_t)c2 * TPR + lane];
        float4 v3 = in4[(size_t)c3 * TPR + lane];
        float4 v4 = in4[(size_t)c4 * TPR + lane];
        float4 v5 = in4[(size_t)c5 * TPR + lane];
        float4 v6 = in4[(size_t)c6 * TPR + lane];
        float4 v7 = in4[(size_t)c7 * TPR + lane];
        acc_h8(a0, b0, v0); acc_h8(a1, b1v, v1); acc_h8(a2, b2v, v2); acc_h8(a3, b3, v3);
        acc_h8(a0, b0, v4); acc_h8(a1, b1v, v5); acc_h8(a2, b2v, v6); acc_h8(a3, b3, v7);
    }
    for (; j + 1 < hi; j += 2) {
        int c0 = adj[j], c1 = adj[j + 1];
        float4 v0 = in4[(size_t)c0 * TPR + lane];
        float4 v1 = in4[(size_t)c1 * TPR + lane];
        acc_h8(a0, b0, v0); acc_h8(a1, b1v, v1);
    }
    if (j < hi) {
        float4 v0 = in4[(size_t)adj[j] * TPR + lane];
        acc_h8(a0, b0, v0);
    }
    a0.x += a1.x + a2.x + a3.x; a0.y += a1.y + a2.y + a3.y;
    a0.z += a1.z + a2.z + a3.z; a0.w += a1.w + a2.w + a3.w;
    b0.x += b1v.x + b2v.x + b3.x; b0.y += b1v.y + b2v.y + b3.y;
    b0.z += b1v.z + b2v.z + b3.z; b0.w += b1v.w + b2v.w + b3.w;
    float sc = scale[r];
    if (RELU) {
        float4 ba = ((const float4*)bias)[lane * 2];
        float4 bb = ((const float4*)bias)[lane * 2 + 1];
        a0.x = fmaxf(fmaf(a0.x, sc, ba.x), 0.f);
        a0.y = fmaxf(fmaf(a0.y, sc, ba.y), 0.f);
        a0.z = fmaxf(fmaf(a0.z, sc, ba.z), 0.f);
        a0.w = fmaxf(fmaf(a0.w, sc, ba.w), 0.f);
        b0.x = fmaxf(fmaf(b0.x, sc, bb.x), 0.f);
        b0.y = fmaxf(fmaf(b0.y, sc, bb.y), 0.f);
        b0.z = fmaxf(fmaf(b0.z, sc, bb.z), 0.f);
        b0.w = fmaxf(fmaf(b0.w, sc, bb.w), 0.f);
    } else {
        a0.x *= sc; a0.y *= sc; a0.z *= sc; a0.w *= sc;
        b0.x *= sc; b0.y *= sc; b0.z *= sc; b0.w *= sc;
    }
    ((float4*)out)[(size_t)r * TPR + lane] = pack_h8(a0, b0);
}

// combined pull: blocks [0,3125) = F=128 side, [3125,4688) = F=64 side
template <bool RELU>
__global__ void k_pull2(const __half* __restrict__ inA, const int* __restrict__ offA,
                        const int* __restrict__ adjA, const float* __restrict__ scA,
                        const float* __restrict__ biA, __half* __restrict__ outA, int rowsA,
                        const __half* __restrict__ inB, const int* __restrict__ offB,
                        const int* __restrict__ adjB, const float* __restrict__ scB,
                        const float* __restrict__ biB, __half* __restrict__ outB, int rowsB) {
    if (blockIdx.x < 3125)
        pull_body<128, RELU>(inA, offA, adjA, scA, biA, outA, rowsA, blockIdx.x);
    else
        pull_body<64, RELU>(inB, offB, adjB, scB, biB, outB, rowsB, blockIdx.x - 3125);
}

// ================= fused final MLP via MFMA ==================================
__global__ void __launch_bounds__(256)
k_mlp_mfma(const __half* __restrict__ hx1, const __half* __restrict__ hx2,
           const __half* __restrict__ hx3, const __half* __restrict__ gx1,
           const __half* __restrict__ gx2, const __half* __restrict__ gx3,
           const int* __restrict__ marks, const int* __restrict__ emarks,
           const __half* __restrict__ W1t, const float* __restrict__ b1,
           const float* __restrict__ W2, const float* __restrict__ b2,
           float* __restrict__ out) {
    constexpr int LDK = 56;
    __shared__ __align__(16) __half Xs[32 * LDK];
    __shared__ __align__(16) __half Ws[256 * LDK];
    __shared__ float part[4][32][2];
    int t = threadIdx.x;
    int wave = t >> 6, lane = t & 63;
    int g = lane >> 4, lr = lane & 15;
    int bm0 = blockIdx.x * 32;
    int r_s = t >> 2, q_s = t & 3;
    int m_s = 0, e_s = 0;
    if (t < 128) {
        int l = bm0 + r_s; if (l >= NL) l = NL - 1;
        m_s = marks[l]; e_s = emarks[l];
    }
    f32x4 acc[2][4] = {};

    for (int k0 = 0; k0 < 768; k0 += 32) {
        if (t < 128) {
            if (k0 < 384) {
                int fb = (k0 < 192 ? k0 : k0 - 192) + q_s * 8;
                const __half* gs = fb < 64 ? gx1 : (fb < 128 ? gx2 : gx3);
                int off = fb & 63;
                half8 va = *(const half8*)&gs[(size_t)e_s * 64 + off];
                half8 vb = *(const half8*)&gs[(size_t)(e_s + 1) * 64 + off];
                half8 rv;
                if (k0 < 192) {
#pragma unroll
                    for (int j = 0; j < 8; j++)
                        rv[j] = (_Float16)fminf((float)va[j], (float)vb[j]);
                } else {
#pragma unroll
                    for (int j = 0; j < 8; j++)
                        rv[j] = (_Float16)fmaxf((float)va[j], (float)vb[j]);
                }
                *(half8*)&Xs[r_s * LDK + q_s * 8] = rv;
            } else {
                int fb = (k0 - 384) + q_s * 8;
                const __half* hs = fb < 128 ? hx1 : (fb < 256 ? hx2 : hx3);
                int off = fb & 127;
                *(float4*)&Xs[r_s * LDK + q_s * 8] = *(const float4*)&hs[(size_t)m_s * 128 + off];
            }
        }
        for (int u = t; u < 1024; u += 256) {
            int r = u >> 2, q = u & 3;
            *(float4*)&Ws[r * LDK + q * 8] = *(const float4*)&W1t[(size_t)r * 768 + k0 + q * 8];
        }
        __syncthreads();
        half8 a[2], b[4];
#pragma unroll
        for (int fm = 0; fm < 2; fm++)
            a[fm] = *(const half8*)&Xs[(fm * 16 + lr) * LDK + g * 8];
#pragma unroll
        for (int fn = 0; fn < 4; fn++)
            b[fn] = *(const half8*)&Ws[(wave * 64 + fn * 16 + lr) * LDK + g * 8];
#pragma unroll
        for (int fm = 0; fm < 2; fm++)
#pragma unroll
            for (int fn = 0; fn < 4; fn++)
                acc[fm][fn] = __builtin_amdgcn_mfma_f32_16x16x32_f16(a[fm], b[fn], acc[fm][fn], 0, 0, 0);
        __syncthreads();
    }
    float b1c[4], w20[4], w21[4];
#pragma unroll
    for (int fn = 0; fn < 4; fn++) {
        int col = wave * 64 + fn * 16 + lr;
        b1c[fn] = b1[col];
        w20[fn] = W2[(size_t)col * 2 + 0];
        w21[fn] = W2[(size_t)col * 2 + 1];
    }
    float p0[2][4], p1[2][4];
#pragma unroll
    for (int fm = 0; fm < 2; fm++) {
#pragma unroll
        for (int reg = 0; reg < 4; reg++) {
            float s0 = 0.f, s1 = 0.f;
#pragma unroll
            for (int fn = 0; fn < 4; fn++) {
                float hh = fmaxf(acc[fm][fn][reg] + b1c[fn], 0.f);
                s0 = fmaf(hh, w20[fn], s0);
                s1 = fmaf(hh, w21[fn], s1);
            }
            p0[fm][reg] = s0; p1[fm][reg] = s1;
        }
    }
#pragma unroll
    for (int mask = 1; mask < 16; mask <<= 1) {
#pragma unroll
        for (int fm = 0; fm < 2; fm++)
#pragma unroll
            for (int reg = 0; reg < 4; reg++) {
                p0[fm][reg] += __shfl_xor(p0[fm][reg], mask);
                p1[fm][reg] += __shfl_xor(p1[fm][reg], mask);
            }
    }
    if (lr == 0) {
#pragma unroll
        for (int fm = 0; fm < 2; fm++)
#pragma unroll
            for (int reg = 0; reg < 4; reg++) {
                int row = fm * 16 + g * 4 + reg;
                part[wave][row][0] = p0[fm][reg];
                part[wave][row][1] = p1[fm][reg];
            }
    }
    __syncthreads();
    if (t < 32) {
        int l = bm0 + t;
        if (l < NL) {
            float l0 = part[0][t][0] + part[1][t][0] + part[2][t][0] + part[3][t][0] + b2[0];
            float l1 = part[0][t][1] + part[1][t][1] + part[2][t][1] + part[3][t][1] + b2[1];
            float mx = fmaxf(l0, l1);
            float lse = mx + logf(expf(l0 - mx) + expf(l1 - mx));
            out[(size_t)l * 2 + 0] = l0 - lse;
            out[(size_t)l * 2 + 1] = l1 - lse;
        }
    }
}

extern "C" void kernel_launch(void* const* d_in, const int* in_sizes, int n_in,
                              void* d_out, int out_size, void* d_ws, size_t ws_size,
                              hipStream_t stream) {
    const float* x      = (const float*)d_in[0];
    const float* ex     = (const float*)d_in[1];
    const int*   ei     = (const int*)d_in[2];
    const int*   marks  = (const int*)d_in[3];
    const int*   emarks = (const int*)d_in[4];
    const float* Wn[3] = {(const float*)d_in[5],  (const float*)d_in[9],  (const float*)d_in[13]};
    const float* bn[3] = {(const float*)d_in[6],  (const float*)d_in[10], (const float*)d_in[14]};
    const float* We[3] = {(const float*)d_in[7],  (const float*)d_in[11], (const float*)d_in[15]};
    const float* be[3] = {(const float*)d_in[8],  (const float*)d_in[12], (const float*)d_in[16]};
    const float* W1 = (const float*)d_in[17];
    const float* b1 = (const float*)d_in[18];
    const float* W2 = (const float*)d_in[19];
    const float* b2 = (const float*)d_in[20];

    // ---- workspace layout ----
    int*    off_n = (int*)d_ws;                // 50004
    int*    off_h = off_n + 50004;             // 50004
    int*    adj_n = off_h + 50004;             // 800000
    int*    adj_h = adj_n + 800000;            // 800000
    int*    cnt   = adj_h + 800000;            // 100000
    int*    cur   = cnt + 100000;              // 100000
    int*    parts = cur + 100000;              // 512
    float*  invn  = (float*)(parts + 512);     // 50000
    float*  invh  = invn + 50000;              // 50000
    __half* xh    = (__half*)(invh + 50000);   // 12.8M
    __half* exh   = xh + 12800000;             // 6.4M
    __half* xwb   = exh + 6400000;             // 6.4M
    __half* xwb2  = xwb + 6400000;             // 3.2M
    __half* heb   = xwb2 + 3200000;            // 6.4M
    __half* heb2  = heb + 6400000;             // 3.2M
    __half* h[3]  = {heb2 + 3200000, heb2 + 9600000, heb2 + 16000000};  // 6.4M each
    __half* g[3]  = {h[2] + 6400000, h[2] + 9600000, h[2] + 12800000};  // 3.2M each
    __half* Wnt[3] = {g[2] + 3200000, g[2] + 3232768, g[2] + 3249152};
    __half* Wet[3] = {g[2] + 3265536, g[2] + 3273728, g[2] + 3277824};
    __half* W1t    = g[2] + 3281920;

    int* cnt_n = cnt;
    int* cnt_h = cnt + 50000;
    int* cur_n = cur;
    int* cur_h = cur + 50000;

    // ---- prep + CSR build ----
    hipMemsetAsync(cnt, 0, 200000 * sizeof(int), stream);   // counts + cursors
    k_prep<<<PB_H, 256, 0, stream>>>(x, xh, ex, exh,
                                     Wn[0], Wn[1], Wn[2], We[0], We[1], We[2], W1,
                                     Wnt[0], Wnt[1], Wnt[2], Wet[0], Wet[1], Wet[2], W1t,
                                     ei, cnt_n, cnt_h);
    k_scanp1<<<392, 256, 0, stream>>>(cnt_n, cnt_h, parts);
    k_scanp2<<<2, 256, 0, stream>>>(parts, off_n, off_h);
    k_scanp3<<<392, 256, 0, stream>>>(cnt_n, cnt_h, parts, off_n, off_h, invn, invh);
    k_fill<<<FILL_SEGS * 8, 256, 0, stream>>>(ei, off_n, off_h, cur_n, cur_h, adj_n, adj_h);

    // ---- fused node+edge conv chains (independent until final MLP) ----
    const __half* cn = xh;  int kn = 256;
    const __half* ce = exh; int ke = 128;
    for (int i = 0; i < 3; i++) {
        k_gemm2<<<1564, 256, 0, stream>>>(cn, Wnt[i], xwb, kn, ce, Wet[i], xwb2, ke);
        k_pull2<false><<<4688, 256, 0, stream>>>(xwb, off_h, adj_h, invh, nullptr, heb, NH,
                                                 xwb2, off_n, adj_n, invn, nullptr, heb2, NN);
        k_pull2<true><<<4688, 256, 0, stream>>>(heb, off_n, adj_n, invn, bn[i], h[i], NN,
                                                heb2, off_h, adj_h, invh, be[i], g[i], NH);
        cn = h[i]; kn = 128;
        ce = g[i]; ke = 64;
    }

    // ---- fused final MLP (MFMA) + head + log_softmax ----
    k_mlp_mfma<<<(NL + 31) / 32, 256, 0, stream>>>(h[0], h[1], h[2], g[0], g[1], g[2],
                                                   marks, emarks, W1t, b1, W2, b2, (float*)d_out);
}

// Round 11
// 571.308 us; speedup vs baseline: 6.8599x; 1.0203x over previous
//
#include <hip/hip_runtime.h>
#include <hip/hip_fp16.h>
#include <math.h>

#define NN 50000
#define NH 50000
#define NI 800000
#define NL 20000

using half8 = __attribute__((ext_vector_type(8))) _Float16;
using f32x4 = __attribute__((ext_vector_type(4))) float;

// ================= helpers =================
static __device__ __forceinline__ float2 pack_h4(float4 v) {
    float2 st;
    *(__half2*)&st.x = __float22half2_rn(make_float2(v.x, v.y));
    *(__half2*)&st.y = __float22half2_rn(make_float2(v.z, v.w));
    return st;
}
static __device__ __forceinline__ void acc_h8(float4& a, float4& b, float4 raw) {
    const __half2* hp = (const __half2*)&raw;
    float2 f0 = __half22float2(hp[0]);
    float2 f1 = __half22float2(hp[1]);
    float2 f2 = __half22float2(hp[2]);
    float2 f3 = __half22float2(hp[3]);
    a.x += f0.x; a.y += f0.y; a.z += f1.x; a.w += f1.y;
    b.x += f2.x; b.y += f2.y; b.z += f3.x; b.w += f3.y;
}
static __device__ __forceinline__ float4 pack_h8(float4 a, float4 b) {
    float4 st;
    ((__half2*)&st)[0] = __float22half2_rn(make_float2(a.x, a.y));
    ((__half2*)&st)[1] = __float22half2_rn(make_float2(a.z, a.w));
    ((__half2*)&st)[2] = __float22half2_rn(make_float2(b.x, b.y));
    ((__half2*)&st)[3] = __float22half2_rn(make_float2(b.z, b.w));
    return st;
}

// ================= prep: 7 weight transposes + XCD-bucketed histogram ==========
// blocks [0,1088): weight transpose elements; [1088, 1088+784): histogram
// (98 segments x 8 buckets; counters id/6250 == bucket stay in one XCD's L2)
#define WT_BLKS 1088
#define HIST_SEGS 98
#define HIST_PER  8164
__global__ void k_prep(const float* __restrict__ Wn0, const float* __restrict__ Wn1,
                       const float* __restrict__ Wn2, const float* __restrict__ We0,
                       const float* __restrict__ We1, const float* __restrict__ We2,
                       const float* __restrict__ W1,
                       __half* __restrict__ Wnt0, __half* __restrict__ Wnt1,
                       __half* __restrict__ Wnt2, __half* __restrict__ Wet0,
                       __half* __restrict__ Wet1, __half* __restrict__ Wet2,
                       __half* __restrict__ W1t,
                       const int* __restrict__ ei, int* __restrict__ cnt_n,
                       int* __restrict__ cnt_h) {
    int b = blockIdx.x, t = threadIdx.x;
    if (b < WT_BLKS) {
        int u = b * 256 + t;
        if (u < 278528) {
            const float* S; __half* D; int K, N;
            if (u < 32768)      { S = Wn0; D = Wnt0; K = 256; N = 128; }
            else if (u < 49152) { S = Wn1; D = Wnt1; K = 128; N = 128; u -= 32768; }
            else if (u < 65536) { S = Wn2; D = Wnt2; K = 128; N = 128; u -= 49152; }
            else if (u < 73728) { S = We0; D = Wet0; K = 128; N = 64;  u -= 65536; }
            else if (u < 77824) { S = We1; D = Wet1; K = 64;  N = 64;  u -= 73728; }
            else if (u < 81920) { S = We2; D = Wet2; K = 64;  N = 64;  u -= 77824; }
            else                { S = W1;  D = W1t;  K = 768; N = 256; u -= 81920; }
            int n = u / K, k = u % K;
            D[(size_t)n * K + k] = __float2half(S[(size_t)k * N + n]);
        }
    } else {
        int hb = b - WT_BLKS;
        int bucket = hb & 7;
        int seg = hb >> 3;
        int lo = seg * HIST_PER;
        int hi = min(lo + HIST_PER, NI);
        for (int e = lo + t; e < hi; e += 256) {
            int s = ei[e], d = ei[e + NI];
            if (s / 6250 == bucket) atomicAdd(&cnt_n[s], 1);
            if (d / 6250 == bucket) atomicAdd(&cnt_h[d], 1);
        }
    }
}

// ================= 3-phase multi-block scan (both count arrays at once) ========
__global__ void k_scanp1(const int* __restrict__ cnt_n, const int* __restrict__ cnt_h,
                         int* __restrict__ parts) {
    __shared__ int s[256];
    int arr = blockIdx.x / 196, blk = blockIdx.x % 196, t = threadIdx.x;
    const int* cnt = arr ? cnt_h : cnt_n;
    int i = blk * 256 + t;
    int v = (i < 50000) ? cnt[i] : 0;
    s[t] = v;
    __syncthreads();
#pragma unroll
    for (int d = 128; d > 0; d >>= 1) {
        if (t < d) s[t] += s[t + d];
        __syncthreads();
    }
    if (t == 0) parts[arr * 256 + blk] = s[0];
}

__global__ void k_scanp2(int* __restrict__ parts, int* __restrict__ off_n,
                         int* __restrict__ off_h) {
    __shared__ int s[256];
    int b = blockIdx.x, t = threadIdx.x;
    int* P = parts + b * 256;
    int v = (t < 196) ? P[t] : 0;
    s[t] = v;
    __syncthreads();
#pragma unroll
    for (int d = 1; d < 256; d <<= 1) {
        int u = (t >= d) ? s[t - d] : 0;
        __syncthreads();
        s[t] += u;
        __syncthreads();
    }
    if (t < 196) P[t] = s[t] - v;          // exclusive
    if (t == 0) {
        int* off = b ? off_h : off_n;
        off[50000] = s[255];
    }
}

__global__ void k_scanp3(const int* __restrict__ cnt_n, const int* __restrict__ cnt_h,
                         const int* __restrict__ parts, int* __restrict__ off_n,
                         int* __restrict__ off_h, float* __restrict__ invn,
                         float* __restrict__ invh) {
    __shared__ int s[256];
    int arr = blockIdx.x / 196, blk = blockIdx.x % 196, t = threadIdx.x;
    const int* cnt = arr ? cnt_h : cnt_n;
    int* off = arr ? off_h : off_n;
    float* inv = arr ? invh : invn;
    int i = blk * 256 + t;
    int c = (i < 50000) ? cnt[i] : 0;
    s[t] = c;
    __syncthreads();
#pragma unroll
    for (int d = 1; d < 256; d <<= 1) {
        int u = (t >= d) ? s[t - d] : 0;
        __syncthreads();
        s[t] += u;
        __syncthreads();
    }
    if (i < 50000) {
        off[i] = parts[arr * 256 + blk] + s[t] - c;
        inv[i] = c > 0 ? 1.0f / (float)c : 0.0f;
    }
}

// ================= XCD-bucketed CSR fill =================
#define FILL_SEGS 98
#define FILL_PER  8164
__global__ void k_fill(const int* __restrict__ ei, const int* __restrict__ off_n,
                       const int* __restrict__ off_h, int* __restrict__ cur_n,
                       int* __restrict__ cur_h, int* __restrict__ adj_n,
                       int* __restrict__ adj_h) {
    int bucket = blockIdx.x & 7;
    int seg = blockIdx.x >> 3;
    int lo = seg * FILL_PER;
    int hi = min(lo + FILL_PER, NI);
    for (int e = lo + (int)threadIdx.x; e < hi; e += 256) {
        int s = ei[e], d = ei[e + NI];
        if (d / 6250 == bucket) {
            int p = atomicAdd(&cur_h[d], 1);
            adj_h[off_h[d] + p] = s;
        }
        if (s / 6250 == bucket) {
            int q = atomicAdd(&cur_n[s], 1);
            adj_n[off_n[s] + q] = d;
        }
    }
}

// ================= MFMA GEMM body (SrcT = float converts during staging) =======
template <typename SrcT, int BM, int BN, int FM, int FN>
static __device__ __forceinline__ void gemm_body(const SrcT* __restrict__ X,
                                                 const __half* __restrict__ Wt,
                                                 __half* __restrict__ Y, int M, int K,
                                                 int blk, __half* smem) {
    constexpr int LDK = 56;
    constexpr int WN = BN / 4;
    __half* Xs = smem;
    __half* Ws = smem + BM * LDK;
    int t = threadIdx.x;
    int wave = t >> 6, lane = t & 63;
    int g = lane >> 4, lr = lane & 15;
    int bm0 = blk * BM;
    f32x4 acc[FM][FN] = {};

    for (int k0 = 0; k0 < K; k0 += 32) {
        for (int u = t; u < BM * 4; u += 256) {
            int r = u >> 2, q = u & 3;
            int rg = bm0 + r; if (rg >= M) rg = M - 1;
            if constexpr (sizeof(SrcT) == 4) {
                const float* src = (const float*)X + (size_t)rg * K + k0 + q * 8;
                float4 v0 = *(const float4*)src;
                float4 v1 = *(const float4*)(src + 4);
                *(float2*)&Xs[r * LDK + q * 8]     = pack_h4(v0);
                *(float2*)&Xs[r * LDK + q * 8 + 4] = pack_h4(v1);
            } else {
                *(float4*)&Xs[r * LDK + q * 8] =
                    *(const float4*)((const __half*)X + (size_t)rg * K + k0 + q * 8);
            }
        }
        for (int u = t; u < BN * 4; u += 256) {
            int r = u >> 2, q = u & 3;
            *(float4*)&Ws[r * LDK + q * 8] = *(const float4*)&Wt[(size_t)r * K + k0 + q * 8];
        }
        __syncthreads();
        half8 a[FM], b[FN];
#pragma unroll
        for (int fm = 0; fm < FM; fm++)
            a[fm] = *(const half8*)&Xs[(fm * 16 + lr) * LDK + g * 8];
#pragma unroll
        for (int fn = 0; fn < FN; fn++)
            b[fn] = *(const half8*)&Ws[(wave * WN + fn * 16 + lr) * LDK + g * 8];
#pragma unroll
        for (int fm = 0; fm < FM; fm++)
#pragma unroll
            for (int fn = 0; fn < FN; fn++)
                acc[fm][fn] = __builtin_amdgcn_mfma_f32_16x16x32_f16(a[fm], b[fn], acc[fm][fn], 0, 0, 0);
        __syncthreads();
    }
#pragma unroll
    for (int fm = 0; fm < FM; fm++) {
#pragma unroll
        for (int fn = 0; fn < FN; fn++) {
            int cg = wave * WN + fn * 16 + lr;
#pragma unroll
            for (int reg = 0; reg < 4; reg++) {
                int rg = bm0 + fm * 16 + g * 4 + reg;
                if (rg < M) Y[(size_t)rg * BN + cg] = __float2half(acc[fm][fn][reg]);
            }
        }
    }
}

// combined node (64x128) + edge (64x64) GEMM; blocks [0,782) node, rest edge
template <typename SrcT>
__global__ void __launch_bounds__(256)
k_gemm2(const SrcT* __restrict__ Xn, const __half* __restrict__ Wtn,
        __half* __restrict__ Yn, int Kn,
        const SrcT* __restrict__ Xe, const __half* __restrict__ Wte,
        __half* __restrict__ Ye, int Ke) {
    __shared__ __align__(16) __half smem[(64 + 128) * 56];
    if (blockIdx.x < 782)
        gemm_body<SrcT, 64, 128, 4, 2>(Xn, Wtn, Yn, NN, Kn, blockIdx.x, smem);
    else
        gemm_body<SrcT, 64, 64, 4, 1>(Xe, Wte, Ye, NH, Ke, blockIdx.x - 782, smem);
}

// ================= pull body: 16B gathers, 8-way unrolled ========
template <int F, bool RELU>
static __device__ __forceinline__ void pull_body(const __half* __restrict__ in,
                                                 const int* __restrict__ off,
                                                 const int* __restrict__ adj,
                                                 const float* __restrict__ scale,
                                                 const float* __restrict__ bias,
                                                 __half* __restrict__ out,
                                                 int nrows, int blk) {
    constexpr int TPR = F / 8;
    constexpr int RPB = 256 / TPR;
    int r = blk * RPB + (int)threadIdx.x / TPR;
    int lane = threadIdx.x % TPR;
    if (r >= nrows) return;
    int lo = off[r], hi = off[r + 1];
    const float4* in4 = (const float4*)in;
    float4 a0 = {0,0,0,0}, b0 = {0,0,0,0}, a1 = {0,0,0,0}, b1v = {0,0,0,0};
    float4 a2 = {0,0,0,0}, b2v = {0,0,0,0}, a3 = {0,0,0,0}, b3 = {0,0,0,0};
    int j = lo;
    for (; j + 7 < hi; j += 8) {
        int c0 = adj[j], c1 = adj[j + 1], c2 = adj[j + 2], c3 = adj[j + 3];
        int c4 = adj[j + 4], c5 = adj[j + 5], c6 = adj[j + 6], c7 = adj[j + 7];
        float4 v0 = in4[(size_t)c0 * TPR + lane];
        float4 v1 = in4[(size_t)c1 * TPR + lane];
        float4 v2 = in4[(size_t)c2 * TPR + lane];
        float4 v3 = in4[(size_t)c3 * TPR + lane];
        float4 v4 = in4[(size_t)c4 * TPR + lane];
        float4 v5 = in4[(size_t)c5 * TPR + lane];
        float4 v6 = in4[(size_t)c6 * TPR + lane];
        float4 v7 = in4[(size_t)c7 * TPR + lane];
        acc_h8(a0, b0, v0); acc_h8(a1, b1v, v1); acc_h8(a2, b2v, v2); acc_h8(a3, b3, v3);
        acc_h8(a0, b0, v4); acc_h8(a1, b1v, v5); acc_h8(a2, b2v, v6); acc_h8(a3, b3, v7);
    }
    for (; j + 1 < hi; j += 2) {
        int c0 = adj[j], c1 = adj[j + 1];
        float4 v0 = in4[(size_t)c0 * TPR + lane];
        float4 v1 = in4[(size_t)c1 * TPR + lane];
        acc_h8(a0, b0, v0); acc_h8(a1, b1v, v1);
    }
    if (j < hi) {
        float4 v0 = in4[(size_t)adj[j] * TPR + lane];
        acc_h8(a0, b0, v0);
    }
    a0.x += a1.x + a2.x + a3.x; a0.y += a1.y + a2.y + a3.y;
    a0.z += a1.z + a2.z + a3.z; a0.w += a1.w + a2.w + a3.w;
    b0.x += b1v.x + b2v.x + b3.x; b0.y += b1v.y + b2v.y + b3.y;
    b0.z += b1v.z + b2v.z + b3.z; b0.w += b1v.w + b2v.w + b3.w;
    float sc = scale[r];
    if (RELU) {
        float4 ba = ((const float4*)bias)[lane * 2];
        float4 bb = ((const float4*)bias)[lane * 2 + 1];
        a0.x = fmaxf(fmaf(a0.x, sc, ba.x), 0.f);
        a0.y = fmaxf(fmaf(a0.y, sc, ba.y), 0.f);
        a0.z = fmaxf(fmaf(a0.z, sc, ba.z), 0.f);
        a0.w = fmaxf(fmaf(a0.w, sc, ba.w), 0.f);
        b0.x = fmaxf(fmaf(b0.x, sc, bb.x), 0.f);
        b0.y = fmaxf(fmaf(b0.y, sc, bb.y), 0.f);
        b0.z = fmaxf(fmaf(b0.z, sc, bb.z), 0.f);
        b0.w = fmaxf(fmaf(b0.w, sc, bb.w), 0.f);
    } else {
        a0.x *= sc; a0.y *= sc; a0.z *= sc; a0.w *= sc;
        b0.x *= sc; b0.y *= sc; b0.z *= sc; b0.w *= sc;
    }
    ((float4*)out)[(size_t)r * TPR + lane] = pack_h8(a0, b0);
}

// combined pull: blocks [0,3125) = F=128 side, [3125,4688) = F=64 side
template <bool RELU>
__global__ void k_pull2(const __half* __restrict__ inA, const int* __restrict__ offA,
                        const int* __restrict__ adjA, const float* __restrict__ scA,
                        const float* __restrict__ biA, __half* __restrict__ outA, int rowsA,
                        const __half* __restrict__ inB, const int* __restrict__ offB,
                        const int* __restrict__ adjB, const float* __restrict__ scB,
                        const float* __restrict__ biB, __half* __restrict__ outB, int rowsB) {
    if (blockIdx.x < 3125)
        pull_body<128, RELU>(inA, offA, adjA, scA, biA, outA, rowsA, blockIdx.x);
    else
        pull_body<64, RELU>(inB, offB, adjB, scB, biB, outB, rowsB, blockIdx.x - 3125);
}

// ================= fused final MLP via MFMA ==================================
__global__ void __launch_bounds__(256)
k_mlp_mfma(const __half* __restrict__ hx1, const __half* __restrict__ hx2,
           const __half* __restrict__ hx3, const __half* __restrict__ gx1,
           const __half* __restrict__ gx2, const __half* __restrict__ gx3,
           const int* __restrict__ marks, const int* __restrict__ emarks,
           const __half* __restrict__ W1t, const float* __restrict__ b1,
           const float* __restrict__ W2, const float* __restrict__ b2,
           float* __restrict__ out) {
    constexpr int LDK = 56;
    __shared__ __align__(16) __half Xs[32 * LDK];
    __shared__ __align__(16) __half Ws[256 * LDK];
    __shared__ float part[4][32][2];
    int t = threadIdx.x;
    int wave = t >> 6, lane = t & 63;
    int g = lane >> 4, lr = lane & 15;
    int bm0 = blockIdx.x * 32;
    int r_s = t >> 2, q_s = t & 3;
    int m_s = 0, e_s = 0;
    if (t < 128) {
        int l = bm0 + r_s; if (l >= NL) l = NL - 1;
        m_s = marks[l]; e_s = emarks[l];
    }
    f32x4 acc[2][4] = {};

    for (int k0 = 0; k0 < 768; k0 += 32) {
        if (t < 128) {
            if (k0 < 384) {
                int fb = (k0 < 192 ? k0 : k0 - 192) + q_s * 8;
                const __half* gs = fb < 64 ? gx1 : (fb < 128 ? gx2 : gx3);
                int off = fb & 63;
                half8 va = *(const half8*)&gs[(size_t)e_s * 64 + off];
                half8 vb = *(const half8*)&gs[(size_t)(e_s + 1) * 64 + off];
                half8 rv;
                if (k0 < 192) {
#pragma unroll
                    for (int j = 0; j < 8; j++)
                        rv[j] = (_Float16)fminf((float)va[j], (float)vb[j]);
                } else {
#pragma unroll
                    for (int j = 0; j < 8; j++)
                        rv[j] = (_Float16)fmaxf((float)va[j], (float)vb[j]);
                }
                *(half8*)&Xs[r_s * LDK + q_s * 8] = rv;
            } else {
                int fb = (k0 - 384) + q_s * 8;
                const __half* hs = fb < 128 ? hx1 : (fb < 256 ? hx2 : hx3);
                int off = fb & 127;
                *(float4*)&Xs[r_s * LDK + q_s * 8] = *(const float4*)&hs[(size_t)m_s * 128 + off];
            }
        }
        for (int u = t; u < 1024; u += 256) {
            int r = u >> 2, q = u & 3;
            *(float4*)&Ws[r * LDK + q * 8] = *(const float4*)&W1t[(size_t)r * 768 + k0 + q * 8];
        }
        __syncthreads();
        half8 a[2], b[4];
#pragma unroll
        for (int fm = 0; fm < 2; fm++)
            a[fm] = *(const half8*)&Xs[(fm * 16 + lr) * LDK + g * 8];
#pragma unroll
        for (int fn = 0; fn < 4; fn++)
            b[fn] = *(const half8*)&Ws[(wave * 64 + fn * 16 + lr) * LDK + g * 8];
#pragma unroll
        for (int fm = 0; fm < 2; fm++)
#pragma unroll
            for (int fn = 0; fn < 4; fn++)
                acc[fm][fn] = __builtin_amdgcn_mfma_f32_16x16x32_f16(a[fm], b[fn], acc[fm][fn], 0, 0, 0);
        __syncthreads();
    }
    float b1c[4], w20[4], w21[4];
#pragma unroll
    for (int fn = 0; fn < 4; fn++) {
        int col = wave * 64 + fn * 16 + lr;
        b1c[fn] = b1[col];
        w20[fn] = W2[(size_t)col * 2 + 0];
        w21[fn] = W2[(size_t)col * 2 + 1];
    }
    float p0[2][4], p1[2][4];
#pragma unroll
    for (int fm = 0; fm < 2; fm++) {
#pragma unroll
        for (int reg = 0; reg < 4; reg++) {
            float s0 = 0.f, s1 = 0.f;
#pragma unroll
            for (int fn = 0; fn < 4; fn++) {
                float hh = fmaxf(acc[fm][fn][reg] + b1c[fn], 0.f);
                s0 = fmaf(hh, w20[fn], s0);
                s1 = fmaf(hh, w21[fn], s1);
            }
            p0[fm][reg] = s0; p1[fm][reg] = s1;
        }
    }
#pragma unroll
    for (int mask = 1; mask < 16; mask <<= 1) {
#pragma unroll
        for (int fm = 0; fm < 2; fm++)
#pragma unroll
            for (int reg = 0; reg < 4; reg++) {
                p0[fm][reg] += __shfl_xor(p0[fm][reg], mask);
                p1[fm][reg] += __shfl_xor(p1[fm][reg], mask);
            }
    }
    if (lr == 0) {
#pragma unroll
        for (int fm = 0; fm < 2; fm++)
#pragma unroll
            for (int reg = 0; reg < 4; reg++) {
                int row = fm * 16 + g * 4 + reg;
                part[wave][row][0] = p0[fm][reg];
                part[wave][row][1] = p1[fm][reg];
            }
    }
    __syncthreads();
    if (t < 32) {
        int l = bm0 + t;
        if (l < NL) {
            float l0 = part[0][t][0] + part[1][t][0] + part[2][t][0] + part[3][t][0] + b2[0];
            float l1 = part[0][t][1] + part[1][t][1] + part[2][t][1] + part[3][t][1] + b2[1];
            float mx = fmaxf(l0, l1);
            float lse = mx + logf(expf(l0 - mx) + expf(l1 - mx));
            out[(size_t)l * 2 + 0] = l0 - lse;
            out[(size_t)l * 2 + 1] = l1 - lse;
        }
    }
}

extern "C" void kernel_launch(void* const* d_in, const int* in_sizes, int n_in,
                              void* d_out, int out_size, void* d_ws, size_t ws_size,
                              hipStream_t stream) {
    const float* x      = (const float*)d_in[0];
    const float* ex     = (const float*)d_in[1];
    const int*   ei     = (const int*)d_in[2];
    const int*   marks  = (const int*)d_in[3];
    const int*   emarks = (const int*)d_in[4];
    const float* Wn[3] = {(const float*)d_in[5],  (const float*)d_in[9],  (const float*)d_in[13]};
    const float* bn[3] = {(const float*)d_in[6],  (const float*)d_in[10], (const float*)d_in[14]};
    const float* We[3] = {(const float*)d_in[7],  (const float*)d_in[11], (const float*)d_in[15]};
    const float* be[3] = {(const float*)d_in[8],  (const float*)d_in[12], (const float*)d_in[16]};
    const float* W1 = (const float*)d_in[17];
    const float* b1 = (const float*)d_in[18];
    const float* W2 = (const float*)d_in[19];
    const float* b2 = (const float*)d_in[20];

    // ---- workspace layout ----
    int*    off_n = (int*)d_ws;                // 50004
    int*    off_h = off_n + 50004;             // 50004
    int*    adj_n = off_h + 50004;             // 800000
    int*    adj_h = adj_n + 800000;            // 800000
    int*    cnt   = adj_h + 800000;            // 100000
    int*    cur   = cnt + 100000;              // 100000
    int*    parts = cur + 100000;              // 512
    float*  invn  = (float*)(parts + 512);     // 50000
    float*  invh  = invn + 50000;              // 50000
    __half* xwb   = (__half*)(invh + 50000);   // 6.4M
    __half* xwb2  = xwb + 6400000;             // 3.2M
    __half* heb   = xwb2 + 3200000;            // 6.4M
    __half* heb2  = heb + 6400000;             // 3.2M
    __half* h[3]  = {heb2 + 3200000, heb2 + 9600000, heb2 + 16000000};  // 6.4M each
    __half* g[3]  = {h[2] + 6400000, h[2] + 9600000, h[2] + 12800000};  // 3.2M each
    __half* Wnt[3] = {g[2] + 3200000, g[2] + 3232768, g[2] + 3249152};
    __half* Wet[3] = {g[2] + 3265536, g[2] + 3273728, g[2] + 3277824};
    __half* W1t    = g[2] + 3281920;

    int* cnt_n = cnt;
    int* cnt_h = cnt + 50000;
    int* cur_n = cur;
    int* cur_h = cur + 50000;

    // ---- prep + CSR build ----
    hipMemsetAsync(cnt, 0, 200000 * sizeof(int), stream);   // counts + cursors
    k_prep<<<WT_BLKS + HIST_SEGS * 8, 256, 0, stream>>>(
        Wn[0], Wn[1], Wn[2], We[0], We[1], We[2], W1,
        Wnt[0], Wnt[1], Wnt[2], Wet[0], Wet[1], Wet[2], W1t,
        ei, cnt_n, cnt_h);
    k_scanp1<<<392, 256, 0, stream>>>(cnt_n, cnt_h, parts);
    k_scanp2<<<2, 256, 0, stream>>>(parts, off_n, off_h);
    k_scanp3<<<392, 256, 0, stream>>>(cnt_n, cnt_h, parts, off_n, off_h, invn, invh);
    k_fill<<<FILL_SEGS * 8, 256, 0, stream>>>(ei, off_n, off_h, cur_n, cur_h, adj_n, adj_h);

    // ---- fused node+edge conv chains ----
    // layer 0: fp32 inputs converted during GEMM staging
    k_gemm2<float><<<1564, 256, 0, stream>>>(x, Wnt[0], xwb, 256, ex, Wet[0], xwb2, 128);
    k_pull2<false><<<4688, 256, 0, stream>>>(xwb, off_h, adj_h, invh, nullptr, heb, NH,
                                             xwb2, off_n, adj_n, invn, nullptr, heb2, NN);
    k_pull2<true><<<4688, 256, 0, stream>>>(heb, off_n, adj_n, invn, bn[0], h[0], NN,
                                            heb2, off_h, adj_h, invh, be[0], g[0], NH);
    for (int i = 1; i < 3; i++) {
        k_gemm2<__half><<<1564, 256, 0, stream>>>(h[i - 1], Wnt[i], xwb, 128,
                                                  g[i - 1], Wet[i], xwb2, 64);
        k_pull2<false><<<4688, 256, 0, stream>>>(xwb, off_h, adj_h, invh, nullptr, heb, NH,
                                                 xwb2, off_n, adj_n, invn, nullptr, heb2, NN);
        k_pull2<true><<<4688, 256, 0, stream>>>(heb, off_n, adj_n, invn, bn[i], h[i], NN,
                                                heb2, off_h, adj_h, invh, be[i], g[i], NH);
    }

    // ---- fused final MLP (MFMA) + head + log_softmax ----
    k_mlp_mfma<<<(NL + 31) / 32, 256, 0, stream>>>(h[0], h[1], h[2], g[0], g[1], g[2],
                                                   marks, emarks, W1t, b1, W2, b2, (float*)d_out);
}